// Round 8
// baseline (7402.095 us; speedup 1.0000x reference)
//
#include <hip/hip_runtime.h>
#include <math.h>

#define B_ 512
#define C_ 200
#define D_ 512
#define E_ 256
#define V_ 8192
#define G_ 2048
#define L_ 16
#define NBLK_ 512u

typedef __attribute__((ext_vector_type(8))) short short8;
typedef __attribute__((ext_vector_type(4))) float f32x4;

__device__ __forceinline__ float sigm(float x) { return 1.0f / (1.0f + expf(-x)); }

__device__ __forceinline__ unsigned short bf16_rn(float x) {
    unsigned int u = __float_as_uint(x);
    return (unsigned short)((u + 0x7FFFu + ((u >> 16) & 1u)) >> 16);
}
__device__ __forceinline__ float bf16f(unsigned short h) {
    return __uint_as_float(((unsigned int)h) << 16);
}

// ---------------------------------------------------------------------------
// LDS union for the mono-kernel phases
// ---------------------------------------------------------------------------
union SharedU {
    struct { float accw[4][512]; float mw[4]; float sw[4]; } attn;
    struct { short As[8 * 512]; short Bs[4 * 512]; int toks[64]; } gates;
    struct { short As[8 * 512]; short Bs[16 * 512]; float pvS[64][2]; int piS[64][2]; } mega;
};

// ---------------------------------------------------------------------------
// device-scope grid barrier (sense-reversing; all 512 blocks co-resident)
// ---------------------------------------------------------------------------
__device__ __forceinline__ void gridbar(unsigned* bar) {
    __syncthreads();
    if (threadIdx.x == 0) {
        __threadfence();   // release prior writes to device scope
        unsigned gen = __hip_atomic_load(bar + 1, __ATOMIC_RELAXED, __HIP_MEMORY_SCOPE_AGENT);
        unsigned arr = __hip_atomic_fetch_add(bar, 1u, __ATOMIC_ACQ_REL, __HIP_MEMORY_SCOPE_AGENT);
        if (arr == NBLK_ - 1u) {
            __hip_atomic_store(bar, 0u, __ATOMIC_RELAXED, __HIP_MEMORY_SCOPE_AGENT);
            __hip_atomic_fetch_add(bar + 1, 1u, __ATOMIC_RELEASE, __HIP_MEMORY_SCOPE_AGENT);
        } else {
            while (__hip_atomic_load(bar + 1, __ATOMIC_ACQUIRE, __HIP_MEMORY_SCOPE_AGENT) == gen)
                __builtin_amdgcn_s_sleep(2);
        }
        __threadfence();   // acquire
    }
    __syncthreads();
}

// ---------------------------------------------------------------------------
// merged setup (block ranges):
//   [0,4096) W_proj  [4096,6144) emb  [6144,8704) Wg  [8704,8960) W_attn
//   [8960,9472) init h0=c0=mean, tok0=1; block 0 also zeroes bar counter
// ---------------------------------------------------------------------------
__global__ __launch_bounds__(256) void k_setup(const float* __restrict__ W_proj,
                                               const float* __restrict__ emb,
                                               const float* __restrict__ W_ih,
                                               const float* __restrict__ W_hh,
                                               const float* __restrict__ W_attn,
                                               const float* __restrict__ ctx,
                                               const int* __restrict__ counts,
                                               unsigned short* __restrict__ Wp_hi,
                                               unsigned short* __restrict__ Wp_lo,
                                               unsigned short* __restrict__ Eb_hi,
                                               unsigned short* __restrict__ Eb_lo,
                                               unsigned short* __restrict__ Wg_hi,
                                               unsigned short* __restrict__ Wg_lo,
                                               unsigned short* __restrict__ Wa_hi,
                                               unsigned short* __restrict__ Wa_lo,
                                               unsigned short* __restrict__ h_hi,
                                               unsigned short* __restrict__ h_lo,
                                               float* __restrict__ c,
                                               int* __restrict__ tok,
                                               unsigned* __restrict__ bar) {
    int bb = blockIdx.x;
    int t = threadIdx.x;
    if (bb == 0 && t == 0) bar[0] = 0u;
    if (bb < 4096) {
        int i = bb * 256 + t;
        float4 v = ((const float4*)W_proj)[i];
        ushort4 h, l;
        h.x = bf16_rn(v.x); l.x = bf16_rn(v.x - bf16f(h.x));
        h.y = bf16_rn(v.y); l.y = bf16_rn(v.y - bf16f(h.y));
        h.z = bf16_rn(v.z); l.z = bf16_rn(v.z - bf16f(h.z));
        h.w = bf16_rn(v.w); l.w = bf16_rn(v.w - bf16f(h.w));
        ((ushort4*)Wp_hi)[i] = h;
        ((ushort4*)Wp_lo)[i] = l;
    } else if (bb < 6144) {
        int i = (bb - 4096) * 256 + t;
        float4 v = ((const float4*)emb)[i];
        ushort4 h, l;
        h.x = bf16_rn(v.x); l.x = bf16_rn(v.x - bf16f(h.x));
        h.y = bf16_rn(v.y); l.y = bf16_rn(v.y - bf16f(h.y));
        h.z = bf16_rn(v.z); l.z = bf16_rn(v.z - bf16f(h.z));
        h.w = bf16_rn(v.w); l.w = bf16_rn(v.w - bf16f(h.w));
        ((ushort4*)Eb_hi)[i] = h;
        ((ushort4*)Eb_lo)[i] = l;
    } else if (bb < 8704) {
        int idx = (bb - 6144) * 256 + t;
        int r = idx / 320;
        int k = (idx - r * 320) * 4;
        int go = ((r & 3) << 9) + (r >> 2);
        float4 v = (k < 768) ? *(const float4*)&W_ih[(size_t)go * 768 + k]
                             : *(const float4*)&W_hh[(size_t)go * 512 + (k - 768)];
        ushort4 h, l;
        h.x = bf16_rn(v.x); l.x = bf16_rn(v.x - bf16f(h.x));
        h.y = bf16_rn(v.y); l.y = bf16_rn(v.y - bf16f(h.y));
        h.z = bf16_rn(v.z); l.z = bf16_rn(v.z - bf16f(h.z));
        h.w = bf16_rn(v.w); l.w = bf16_rn(v.w - bf16f(h.w));
        *(ushort4*)&Wg_hi[(size_t)r * 1280 + k] = h;
        *(ushort4*)&Wg_lo[(size_t)r * 1280 + k] = l;
    } else if (bb < 8960) {
        int i = (bb - 8704) * 256 + t;
        float4 v = ((const float4*)W_attn)[i];
        ushort4 h, l;
        h.x = bf16_rn(v.x); l.x = bf16_rn(v.x - bf16f(h.x));
        h.y = bf16_rn(v.y); l.y = bf16_rn(v.y - bf16f(h.y));
        h.z = bf16_rn(v.z); l.z = bf16_rn(v.z - bf16f(h.z));
        h.w = bf16_rn(v.w); l.w = bf16_rn(v.w - bf16f(h.w));
        ((ushort4*)Wa_hi)[i] = h;
        ((ushort4*)Wa_lo)[i] = l;
    } else {
        int b = bb - 8960;
        int cnt = counts[b];
        const float* base = ctx + (size_t)b * C_ * D_;
        float s0 = 0.f, s1 = 0.f;
        for (int cc = 0; cc < cnt; ++cc) {
            s0 += base[(size_t)cc * D_ + t];
            s1 += base[(size_t)cc * D_ + t + 256];
        }
        float inv = 1.0f / (float)cnt;
        float v0 = s0 * inv, v1 = s1 * inv;
        c[b * D_ + t] = v0;       c[b * D_ + t + 256] = v1;
        unsigned short p0 = bf16_rn(v0), p1 = bf16_rn(v1);
        h_hi[b * D_ + t] = p0;    h_hi[b * D_ + t + 256] = p1;
        h_lo[b * D_ + t] = bf16_rn(v0 - bf16f(p0));
        h_lo[b * D_ + t + 256] = bf16_rn(v1 - bf16f(p1));
        if (t == 0) tok[b] = 1;
    }
}

// ---------------------------------------------------------------------------
// Shared split-bf16 GEMM body: C[64m x 128n] tile, K=512, 4 waves.
// PART=1: +bias + per-block argmax partials. PART=0: plain store.
// ---------------------------------------------------------------------------
template<int PART>
__device__ __forceinline__ void gemm_body(int nb, int mb,
                                          const unsigned short* __restrict__ Ah,
                                          const unsigned short* __restrict__ Al,
                                          const unsigned short* __restrict__ Bh,
                                          const unsigned short* __restrict__ Bl,
                                          const float* __restrict__ bias,
                                          float* __restrict__ C, int ldc,
                                          float* __restrict__ pvO,
                                          int* __restrict__ piO,
                                          short* As, short* Bs,
                                          float (*pvS)[2], int (*piS)[2]) {
    int t = threadIdx.x;
    int l = t & 63;
    int w = t >> 6;
    int m0 = mb * 64;
    int n0 = nb * 128;
    int srow = l & 15;
    int koct = 8 * (l >> 4);
    int pl = w & 1;
    int mtA = w >> 1;
    const unsigned short* Apl = pl ? Al : Ah;
    const unsigned short* Bpl = pl ? Bl : Bh;
    const unsigned short* ApA = Apl + (size_t)(m0 + mtA * 16 + srow) * 512 + koct;
    const unsigned short* ApB = ApA + 32 * 512;
    const unsigned short* Bp0 = Bpl + (size_t)(n0 + (w >> 1) * 16 + srow) * 512 + koct;

    short8 rA0, rA1, rB0, rB1, rB2, rB3;
    rA0 = *(const short8*)(ApA);
    rA1 = *(const short8*)(ApB);
    rB0 = *(const short8*)(Bp0);
    rB1 = *(const short8*)(Bp0 + 32 * 512);
    rB2 = *(const short8*)(Bp0 + 64 * 512);
    rB3 = *(const short8*)(Bp0 + 96 * 512);

    f32x4 z = {0.f, 0.f, 0.f, 0.f};
    f32x4 acc[2][4];
#pragma unroll
    for (int i = 0; i < 2; ++i)
#pragma unroll
        for (int j = 0; j < 4; ++j) acc[i][j] = z;

    int wm = w >> 1, wn = w & 1;
    for (int kt = 0; kt < 512; kt += 32) {
        __syncthreads();
        *(short8*)&As[(w)*512 + l * 8] = rA0;
        *(short8*)&As[(w + 4) * 512 + l * 8] = rA1;
        *(short8*)&Bs[(w)*512 + l * 8] = rB0;
        *(short8*)&Bs[(w + 4) * 512 + l * 8] = rB1;
        *(short8*)&Bs[(w + 8) * 512 + l * 8] = rB2;
        *(short8*)&Bs[(w + 12) * 512 + l * 8] = rB3;
        __syncthreads();
        if (kt + 32 < 512) {
            rA0 = *(const short8*)(ApA + kt + 32);
            rA1 = *(const short8*)(ApB + kt + 32);
            rB0 = *(const short8*)(Bp0 + kt + 32);
            rB1 = *(const short8*)(Bp0 + 32 * 512 + kt + 32);
            rB2 = *(const short8*)(Bp0 + 64 * 512 + kt + 32);
            rB3 = *(const short8*)(Bp0 + 96 * 512 + kt + 32);
        }
        short8 ah[2], al2[2], bh[4], bl2[4];
#pragma unroll
        for (int i = 0; i < 2; ++i) {
            ah[i] = *(short8*)&As[((wm * 2 + i) * 2 + 0) * 512 + l * 8];
            al2[i] = *(short8*)&As[((wm * 2 + i) * 2 + 1) * 512 + l * 8];
        }
#pragma unroll
        for (int j = 0; j < 4; ++j) {
            bh[j] = *(short8*)&Bs[((wn * 4 + j) * 2 + 0) * 512 + l * 8];
            bl2[j] = *(short8*)&Bs[((wn * 4 + j) * 2 + 1) * 512 + l * 8];
        }
#pragma unroll
        for (int i = 0; i < 2; ++i)
#pragma unroll
            for (int j = 0; j < 4; ++j) {
                acc[i][j] = __builtin_amdgcn_mfma_f32_16x16x32_bf16(ah[i], bh[j], acc[i][j], 0, 0, 0);
                acc[i][j] = __builtin_amdgcn_mfma_f32_16x16x32_bf16(ah[i], bl2[j], acc[i][j], 0, 0, 0);
                acc[i][j] = __builtin_amdgcn_mfma_f32_16x16x32_bf16(al2[i], bh[j], acc[i][j], 0, 0, 0);
            }
    }
    int r0 = (l >> 4) * 4;
    int cl = l & 15;
    if (PART) {
        float bj_[4];
#pragma unroll
        for (int j = 0; j < 4; ++j) bj_[j] = bias[n0 + wn * 64 + j * 16 + cl];
#pragma unroll
        for (int i = 0; i < 2; ++i) {
#pragma unroll
            for (int r = 0; r < 4; ++r) {
                int row = m0 + wm * 32 + i * 16 + r0 + r;
                float bv = -INFINITY;
                int bidx = 0x7fffffff;
#pragma unroll
                for (int j = 0; j < 4; ++j) {
                    int col = n0 + wn * 64 + j * 16 + cl;
                    float v = acc[i][j][r] + bj_[j];
                    C[(size_t)row * ldc + col] = v;
                    if (v > bv) { bv = v; bidx = col; }
                }
#pragma unroll
                for (int off = 1; off < 16; off <<= 1) {
                    float ov = __shfl_xor(bv, off);
                    int oi = __shfl_xor(bidx, off);
                    if (ov > bv || (ov == bv && oi < bidx)) { bv = ov; bidx = oi; }
                }
                if (cl == 0) {
                    pvS[wm * 32 + i * 16 + r0 + r][wn] = bv;
                    piS[wm * 32 + i * 16 + r0 + r][wn] = bidx;
                }
            }
        }
        __syncthreads();
        if (t < 64) {
            float v0 = pvS[t][0], v1 = pvS[t][1];
            int i0 = piS[t][0], i1 = piS[t][1];
            bool take1 = (v1 > v0);
            pvO[(size_t)(m0 + t) * 64 + nb] = take1 ? v1 : v0;
            piO[(size_t)(m0 + t) * 64 + nb] = take1 ? i1 : i0;
        }
    } else {
#pragma unroll
        for (int i = 0; i < 2; ++i)
#pragma unroll
            for (int j = 0; j < 4; ++j) {
                int col = n0 + wn * 64 + j * 16 + cl;
                int rowb = m0 + wm * 32 + i * 16 + r0;
#pragma unroll
                for (int r = 0; r < 4; ++r)
                    C[(size_t)(rowb + r) * ldc + col] = acc[i][j][r];
            }
    }
}

// standalone qproj for the first step (h0)
__global__ __launch_bounds__(256, 2) void k_qproj(const unsigned short* __restrict__ Ah,
                                                  const unsigned short* __restrict__ Al,
                                                  const unsigned short* __restrict__ Wah,
                                                  const unsigned short* __restrict__ Wal,
                                                  float* __restrict__ qbuf) {
    __shared__ SharedU sh;
    int nb = blockIdx.x & 3, mb = blockIdx.x >> 2;
    gemm_body<0>(nb, mb, Ah, Al, Wah, Wal, nullptr, qbuf, D_, nullptr, nullptr,
                 sh.mega.As, sh.mega.Bs, sh.mega.pvS, sh.mega.piS);
}

// ---------------------------------------------------------------------------
// attention phase body (block b): single-pass online softmax
// ---------------------------------------------------------------------------
__device__ void attn_phase(int b, const float* __restrict__ ctx,
                           const int* __restrict__ counts,
                           const float* __restrict__ q,
                           unsigned short* __restrict__ cv_hi,
                           unsigned short* __restrict__ cv_lo,
                           SharedU& sh) {
    int t = threadIdx.x;
    int lane = t & 63;
    int wv = t >> 6;
    int cnt = counts[b];
    const float* cb = ctx + (size_t)b * C_ * D_;

    float4 q0 = *(const float4*)&q[(size_t)b * D_ + lane * 4];
    float4 q1 = *(const float4*)&q[(size_t)b * D_ + lane * 4 + 256];

    float m_w = -INFINITY, s_w = 0.f;
    float4 a0 = make_float4(0.f, 0.f, 0.f, 0.f);
    float4 a1 = make_float4(0.f, 0.f, 0.f, 0.f);

#define ATT_DOT(x0, x1) (x0.x * q0.x + x0.y * q0.y + x0.z * q0.z + x0.w * q0.w + \
                         x1.x * q1.x + x1.y * q1.y + x1.z * q1.z + x1.w * q1.w)
#define ATT_UPD(s, x0, x1)                                                     \
    {                                                                          \
        float e;                                                               \
        if (s > m_w) {                                                         \
            float sc = expf(m_w - s);                                          \
            s_w = s_w * sc + 1.f;                                              \
            a0.x *= sc; a0.y *= sc; a0.z *= sc; a0.w *= sc;                    \
            a1.x *= sc; a1.y *= sc; a1.z *= sc; a1.w *= sc;                    \
            m_w = s; e = 1.f;                                                  \
        } else {                                                               \
            e = expf(s - m_w);                                                 \
            s_w += e;                                                          \
        }                                                                      \
        a0.x += e * x0.x; a0.y += e * x0.y; a0.z += e * x0.z; a0.w += e * x0.w;\
        a1.x += e * x1.x; a1.y += e * x1.y; a1.z += e * x1.z; a1.w += e * x1.w;\
    }

    int cc = wv;
    for (; cc + 4 < cnt; cc += 8) {
        const float* rA = cb + (size_t)cc * D_;
        const float* rB = cb + (size_t)(cc + 4) * D_;
        float4 xa0 = *(const float4*)&rA[lane * 4];
        float4 xa1 = *(const float4*)&rA[lane * 4 + 256];
        float4 xb0 = *(const float4*)&rB[lane * 4];
        float4 xb1 = *(const float4*)&rB[lane * 4 + 256];
        float sa = ATT_DOT(xa0, xa1);
        float sb = ATT_DOT(xb0, xb1);
#pragma unroll
        for (int off = 32; off; off >>= 1) {
            sa += __shfl_xor(sa, off);
            sb += __shfl_xor(sb, off);
        }
        ATT_UPD(sa, xa0, xa1);
        ATT_UPD(sb, xb0, xb1);
    }
    if (cc < cnt) {
        const float* rA = cb + (size_t)cc * D_;
        float4 xa0 = *(const float4*)&rA[lane * 4];
        float4 xa1 = *(const float4*)&rA[lane * 4 + 256];
        float sa = ATT_DOT(xa0, xa1);
#pragma unroll
        for (int off = 32; off; off >>= 1) sa += __shfl_xor(sa, off);
        ATT_UPD(sa, xa0, xa1);
    }

    sh.attn.accw[wv][lane * 4 + 0] = a0.x; sh.attn.accw[wv][lane * 4 + 1] = a0.y;
    sh.attn.accw[wv][lane * 4 + 2] = a0.z; sh.attn.accw[wv][lane * 4 + 3] = a0.w;
    sh.attn.accw[wv][256 + lane * 4 + 0] = a1.x; sh.attn.accw[wv][256 + lane * 4 + 1] = a1.y;
    sh.attn.accw[wv][256 + lane * 4 + 2] = a1.z; sh.attn.accw[wv][256 + lane * 4 + 3] = a1.w;
    if (lane == 0) { sh.attn.mw[wv] = m_w; sh.attn.sw[wv] = s_w; }
    __syncthreads();

    float m_g = fmaxf(fmaxf(sh.attn.mw[0], sh.attn.mw[1]), fmaxf(sh.attn.mw[2], sh.attn.mw[3]));
    float e0 = expf(sh.attn.mw[0] - m_g), e1 = expf(sh.attn.mw[1] - m_g);
    float e2 = expf(sh.attn.mw[2] - m_g), e3 = expf(sh.attn.mw[3] - m_g);
    float inv = 1.0f / (sh.attn.sw[0] * e0 + sh.attn.sw[1] * e1 +
                        sh.attn.sw[2] * e2 + sh.attn.sw[3] * e3);
    float v0 = (sh.attn.accw[0][t] * e0 + sh.attn.accw[1][t] * e1 +
                sh.attn.accw[2][t] * e2 + sh.attn.accw[3][t] * e3) * inv;
    float v1 = (sh.attn.accw[0][t + 256] * e0 + sh.attn.accw[1][t + 256] * e1 +
                sh.attn.accw[2][t + 256] * e2 + sh.attn.accw[3][t + 256] * e3) * inv;
    unsigned short p0 = bf16_rn(v0), p1 = bf16_rn(v1);
    cv_hi[(size_t)b * D_ + t] = p0;
    cv_hi[(size_t)b * D_ + t + 256] = p1;
    cv_lo[(size_t)b * D_ + t] = bf16_rn(v0 - bf16f(p0));
    cv_lo[(size_t)b * D_ + t + 256] = bf16_rn(v1 - bf16f(p1));
}

// ---------------------------------------------------------------------------
// gates phase body: 64m x 32n tile, 512 tiles, XCD swizzle, LSTM epilogue
// ---------------------------------------------------------------------------
__device__ void gates_phase(int bid, bool first,
                            const int* __restrict__ tok,
                            const float* __restrict__ pvO,
                            const int* __restrict__ piO,
                            const unsigned short* __restrict__ Eh,
                            const unsigned short* __restrict__ El,
                            const unsigned short* __restrict__ Ch,
                            const unsigned short* __restrict__ Cl,
                            const unsigned short* __restrict__ Hh,
                            const unsigned short* __restrict__ Hl,
                            const unsigned short* __restrict__ Wh,
                            const unsigned short* __restrict__ Wl,
                            const float* __restrict__ b_ih,
                            const float* __restrict__ b_hh,
                            float* __restrict__ cbuf,
                            unsigned short* __restrict__ Hoh,
                            unsigned short* __restrict__ Hol,
                            SharedU& sh) {
    short* As = sh.gates.As;
    short* Bs = sh.gates.Bs;
    int* toks = sh.gates.toks;
    int t = threadIdx.x;
    int l = t & 63;
    int w = t >> 6;
    int xcd = bid & 7, lid = bid >> 3;
    int nb = xcd * 8 + (lid & 7);        // 0..63
    int mb = lid >> 3;                   // 0..7
    int m0 = mb * 64;
    int n0 = nb * 32;
    int srow = l & 15;
    int koct = 8 * (l >> 4);
    int pl = w & 1;
    int mtA = w >> 1;
    int locA = mtA * 16 + srow;          // 0..31
    int rowA = m0 + locA;
    int rowB = rowA + 32;

    if (!first) {
        int ri = t >> 2, qq = t & 3;
        const float* pv = pvO + (size_t)(m0 + ri) * 64 + qq * 16;
        const int* pi = piO + (size_t)(m0 + ri) * 64 + qq * 16;
        float bv = -INFINITY;
        int bix = 0x7fffffff;
#pragma unroll
        for (int j = 0; j < 16; ++j) {
            float v = pv[j];
            int ii = pi[j];
            if (v > bv || (v == bv && ii < bix)) { bv = v; bix = ii; }
        }
#pragma unroll
        for (int off = 1; off < 4; off <<= 1) {
            float ov = __shfl_xor(bv, off);
            int oi = __shfl_xor(bix, off);
            if (ov > bv || (ov == bv && oi < bix)) { bv = ov; bix = oi; }
        }
        if (qq == 0) toks[ri] = bix;
        __syncthreads();
    }

    int tokA = first ? tok[rowA] : toks[locA];
    int tokB = first ? tok[rowB] : toks[locA + 32];

    const unsigned short* Ep = pl ? El : Eh;
    const unsigned short* Cp = pl ? Cl : Ch;
    const unsigned short* Hp = pl ? Hl : Hh;
    const unsigned short* Wp = pl ? Wl : Wh;
    const unsigned short* Wp0 = Wp + (size_t)(n0 + (w >> 1) * 16 + srow) * 1280 + koct;

    f32x4 z = {0.f, 0.f, 0.f, 0.f};
    f32x4 acc[2];
    acc[0] = z; acc[1] = z;

    int wm = w >> 1, wn = w & 1;
    short8 rA0, rA1, rB0;

#define GATES_LOADA(dst, row, tk, kk)                                          \
    {                                                                          \
        int kx = (kk);                                                         \
        if (kx < 256)      dst = *(const short8*)&Ep[(size_t)(tk)*256 + kx];   \
        else if (kx < 768) dst = *(const short8*)&Cp[(size_t)(row)*512 + (kx - 256)]; \
        else               dst = *(const short8*)&Hp[(size_t)(row)*512 + (kx - 768)]; \
    }

    GATES_LOADA(rA0, rowA, tokA, koct);
    GATES_LOADA(rA1, rowB, tokB, koct);
    rB0 = *(const short8*)(Wp0);

    for (int kt = 0; kt < 1280; kt += 32) {
        __syncthreads();
        *(short8*)&As[(w)*512 + l * 8] = rA0;
        *(short8*)&As[(w + 4) * 512 + l * 8] = rA1;
        *(short8*)&Bs[(w)*512 + l * 8] = rB0;
        __syncthreads();
        if (kt + 32 < 1280) {
            GATES_LOADA(rA0, rowA, tokA, kt + 32 + koct);
            GATES_LOADA(rA1, rowB, tokB, kt + 32 + koct);
            rB0 = *(const short8*)(Wp0 + kt + 32);
        }
        short8 ah[2], al2[2], bh, bl2;
#pragma unroll
        for (int i = 0; i < 2; ++i) {
            ah[i] = *(short8*)&As[((wm * 2 + i) * 2 + 0) * 512 + l * 8];
            al2[i] = *(short8*)&As[((wm * 2 + i) * 2 + 1) * 512 + l * 8];
        }
        bh = *(short8*)&Bs[(wn * 2 + 0) * 512 + l * 8];
        bl2 = *(short8*)&Bs[(wn * 2 + 1) * 512 + l * 8];
#pragma unroll
        for (int i = 0; i < 2; ++i) {
            acc[i] = __builtin_amdgcn_mfma_f32_16x16x32_bf16(ah[i], bh, acc[i], 0, 0, 0);
            acc[i] = __builtin_amdgcn_mfma_f32_16x16x32_bf16(ah[i], bl2, acc[i], 0, 0, 0);
            acc[i] = __builtin_amdgcn_mfma_f32_16x16x32_bf16(al2[i], bh, acc[i], 0, 0, 0);
        }
    }

    int r0 = (l >> 4) * 4;
    int cl = l & 15;
    bool act = (cl & 3) == 0;
    int gc = n0 + wn * 16 + cl;
    int d = gc >> 2;
    float bi_ = b_ih[d] + b_hh[d];
    float bf_ = b_ih[512 + d] + b_hh[512 + d];
    float bg_ = b_ih[1024 + d] + b_hh[1024 + d];
    float bo_ = b_ih[1536 + d] + b_hh[1536 + d];
#pragma unroll
    for (int i = 0; i < 2; ++i) {
#pragma unroll
        for (int r = 0; r < 4; ++r) {
            float x = acc[i][r];
            float x1 = __shfl_xor(x, 1);
            float x2 = __shfl_xor(x, 2);
            float x3 = __shfl_xor(x, 3);
            if (act) {
                int row = m0 + wm * 32 + i * 16 + r0 + r;
                float ig = sigm(x + bi_);
                float fg = sigm(x1 + bf_);
                float gg = tanhf(x2 + bg_);
                float og = sigm(x3 + bo_);
                float cn = fg * cbuf[(size_t)row * D_ + d] + ig * gg;
                cbuf[(size_t)row * D_ + d] = cn;
                float hv = og * tanhf(cn);
                unsigned short hh = bf16_rn(hv);
                Hoh[(size_t)row * D_ + d] = hh;
                Hol[(size_t)row * D_ + d] = bf16_rn(hv - bf16f(hh));
            }
        }
    }
}

// ---------------------------------------------------------------------------
// mono-kernel: 15 decode steps, 3 phases per step, manual grid barriers
// ---------------------------------------------------------------------------
__global__ __launch_bounds__(256, 2) void k_mono(const float* __restrict__ ctx,
                                                 const int* __restrict__ counts,
                                                 const unsigned short* __restrict__ Eh,
                                                 const unsigned short* __restrict__ El,
                                                 const unsigned short* __restrict__ Wgh,
                                                 const unsigned short* __restrict__ Wgl,
                                                 const unsigned short* __restrict__ Wph,
                                                 const unsigned short* __restrict__ Wpl,
                                                 const unsigned short* __restrict__ Wah,
                                                 const unsigned short* __restrict__ Wal,
                                                 const float* __restrict__ b_ih,
                                                 const float* __restrict__ b_hh,
                                                 const float* __restrict__ b_proj,
                                                 float* __restrict__ out,
                                                 float* __restrict__ qbuf,
                                                 float* __restrict__ cbuf,
                                                 unsigned short* __restrict__ hA_hi,
                                                 unsigned short* __restrict__ hA_lo,
                                                 unsigned short* __restrict__ hB_hi,
                                                 unsigned short* __restrict__ hB_lo,
                                                 unsigned short* __restrict__ cv_hi,
                                                 unsigned short* __restrict__ cv_lo,
                                                 const int* __restrict__ tok,
                                                 float* __restrict__ pvO,
                                                 int* __restrict__ piO,
                                                 unsigned* __restrict__ bar) {
    __shared__ SharedU sh;
    int bid = blockIdx.x;

    const unsigned short *hin_hi = hA_hi, *hin_lo = hA_lo;
    unsigned short *hout_hi = hB_hi, *hout_lo = hB_lo;

    for (int t = 1; t < L_; ++t) {
        // phase 1: attention (q from previous phase 3 / initial qproj)
        attn_phase(bid, ctx, counts, qbuf, cv_hi, cv_lo, sh);
        gridbar(bar);

        // phase 2: gates + LSTM
        gates_phase(bid, t == 1, tok, pvO, piO, Eh, El, cv_hi, cv_lo,
                    hin_hi, hin_lo, Wgh, Wgl, b_ih, b_hh, cbuf,
                    hout_hi, hout_lo, sh);
        gridbar(bar);

        // phase 3: logits (+ argmax partials) and qproj for next step
        {
            float* slab = out + (size_t)t * B_ * V_;
            int xcd = bid & 7, lid = bid >> 3;
            int nb = xcd * 8 + (lid & 7);
            int mb = lid >> 3;
            gemm_body<1>(nb, mb, hout_hi, hout_lo, Wph, Wpl, b_proj, slab, V_,
                         pvO, piO, sh.mega.As, sh.mega.Bs, sh.mega.pvS, sh.mega.piS);
            if (bid < 32) {
                gemm_body<0>(bid & 3, bid >> 2, hout_hi, hout_lo, Wah, Wal,
                             nullptr, qbuf, D_, nullptr, nullptr,
                             sh.mega.As, sh.mega.Bs, sh.mega.pvS, sh.mega.piS);
            }
        }
        gridbar(bar);

        // swap h ping-pong
        const unsigned short* th;
        th = hin_hi; hin_hi = hout_hi; hout_hi = (unsigned short*)th;
        th = hin_lo; hin_lo = hout_lo; hout_lo = (unsigned short*)th;
    }
}

// ---------------------------------------------------------------------------
extern "C" void kernel_launch(void* const* d_in, const int* in_sizes, int n_in,
                              void* d_out, int out_size, void* d_ws, size_t ws_size,
                              hipStream_t stream) {
    const float* ctx    = (const float*)d_in[0];
    const int*   counts = (const int*)d_in[1];
    const float* emb    = (const float*)d_in[3];
    const float* W_attn = (const float*)d_in[4];
    const float* W_ih   = (const float*)d_in[5];
    const float* b_ih   = (const float*)d_in[6];
    const float* W_hh   = (const float*)d_in[7];
    const float* b_hh   = (const float*)d_in[8];
    const float* W_proj = (const float*)d_in[9];
    const float* b_proj = (const float*)d_in[10];
    float* out = (float*)d_out;

    float* qbuf = (float*)d_ws;                 // [512][512]
    float* cbuf = qbuf + B_ * D_;               // [512][512]
    unsigned short* p = (unsigned short*)(cbuf + B_ * D_);
    unsigned short* Wa_hi = p; p += D_ * D_;
    unsigned short* Wa_lo = p; p += D_ * D_;
    unsigned short* Wp_hi = p; p += (size_t)V_ * D_;
    unsigned short* Wp_lo = p; p += (size_t)V_ * D_;
    unsigned short* Eb_hi = p; p += (size_t)V_ * E_;
    unsigned short* Eb_lo = p; p += (size_t)V_ * E_;
    unsigned short* Wg_hi = p; p += (size_t)G_ * 1280;
    unsigned short* Wg_lo = p; p += (size_t)G_ * 1280;
    unsigned short* hA_hi = p; p += B_ * D_;
    unsigned short* hA_lo = p; p += B_ * D_;
    unsigned short* hB_hi = p; p += B_ * D_;
    unsigned short* hB_lo = p; p += B_ * D_;
    unsigned short* cv_hi = p; p += B_ * D_;
    unsigned short* cv_lo = p; p += B_ * D_;
    int* tok = (int*)p;                         // [512]
    float* pvO = (float*)(tok + B_);            // [512][64]
    int* piO = (int*)(pvO + B_ * 64);           // [512][64]
    unsigned* bar = (unsigned*)(piO + B_ * 64); // [2]

    k_setup<<<9472, 256, 0, stream>>>(W_proj, emb, W_ih, W_hh, W_attn, ctx, counts,
                                      Wp_hi, Wp_lo, Eb_hi, Eb_lo, Wg_hi, Wg_lo,
                                      Wa_hi, Wa_lo, hA_hi, hA_lo, cbuf, tok, bar);

    hipMemsetAsync(out, 0, (size_t)B_ * V_ * sizeof(float), stream);

    // q for step 1 from h0
    k_qproj<<<32, 256, 0, stream>>>(hA_hi, hA_lo, Wa_hi, Wa_lo, qbuf);

    // whole decode loop in one persistent launch
    k_mono<<<NBLK_, 256, 0, stream>>>(ctx, counts, Eb_hi, Eb_lo, Wg_hi, Wg_lo,
                                      Wp_hi, Wp_lo, Wa_hi, Wa_lo,
                                      b_ih, b_hh, b_proj, out,
                                      qbuf, cbuf, hA_hi, hA_lo, hB_hi, hB_lo,
                                      cv_hi, cv_lo, tok, pvO, piO, bar);
}

// Round 9
// 1677.693 us; speedup vs baseline: 4.4121x; 4.4121x over previous
//
#include <hip/hip_runtime.h>
#include <math.h>

#define B_ 512
#define C_ 200
#define D_ 512
#define E_ 256
#define V_ 8192
#define G_ 2048
#define L_ 16

typedef __attribute__((ext_vector_type(8))) short short8;
typedef __attribute__((ext_vector_type(4))) float f32x4;

__device__ __forceinline__ float sigm(float x) { return 1.0f / (1.0f + expf(-x)); }

__device__ __forceinline__ unsigned short bf16_rn(float x) {
    unsigned int u = __float_as_uint(x);
    return (unsigned short)((u + 0x7FFFu + ((u >> 16) & 1u)) >> 16);
}
__device__ __forceinline__ float bf16f(unsigned short h) {
    return __uint_as_float(((unsigned int)h) << 16);
}

// ---------------------------------------------------------------------------
// merged setup (block ranges):
//   [0,4096) W_proj  [4096,6144) emb  [6144,8704) Wg  [8704,8960) W_attn
//   [8960,9472) init h0=c0=mean, tok0=1
// ---------------------------------------------------------------------------
__global__ __launch_bounds__(256) void k_setup(const float* __restrict__ W_proj,
                                               const float* __restrict__ emb,
                                               const float* __restrict__ W_ih,
                                               const float* __restrict__ W_hh,
                                               const float* __restrict__ W_attn,
                                               const float* __restrict__ ctx,
                                               const int* __restrict__ counts,
                                               unsigned short* __restrict__ Wp_hi,
                                               unsigned short* __restrict__ Wp_lo,
                                               unsigned short* __restrict__ Eb_hi,
                                               unsigned short* __restrict__ Eb_lo,
                                               unsigned short* __restrict__ Wg_hi,
                                               unsigned short* __restrict__ Wg_lo,
                                               unsigned short* __restrict__ Wa_hi,
                                               unsigned short* __restrict__ Wa_lo,
                                               unsigned short* __restrict__ h_hi,
                                               unsigned short* __restrict__ h_lo,
                                               float* __restrict__ c,
                                               int* __restrict__ tok) {
    int bb = blockIdx.x;
    int t = threadIdx.x;
    if (bb < 4096) {
        int i = bb * 256 + t;
        float4 v = ((const float4*)W_proj)[i];
        ushort4 h, l;
        h.x = bf16_rn(v.x); l.x = bf16_rn(v.x - bf16f(h.x));
        h.y = bf16_rn(v.y); l.y = bf16_rn(v.y - bf16f(h.y));
        h.z = bf16_rn(v.z); l.z = bf16_rn(v.z - bf16f(h.z));
        h.w = bf16_rn(v.w); l.w = bf16_rn(v.w - bf16f(h.w));
        ((ushort4*)Wp_hi)[i] = h;
        ((ushort4*)Wp_lo)[i] = l;
    } else if (bb < 6144) {
        int i = (bb - 4096) * 256 + t;
        float4 v = ((const float4*)emb)[i];
        ushort4 h, l;
        h.x = bf16_rn(v.x); l.x = bf16_rn(v.x - bf16f(h.x));
        h.y = bf16_rn(v.y); l.y = bf16_rn(v.y - bf16f(h.y));
        h.z = bf16_rn(v.z); l.z = bf16_rn(v.z - bf16f(h.z));
        h.w = bf16_rn(v.w); l.w = bf16_rn(v.w - bf16f(h.w));
        ((ushort4*)Eb_hi)[i] = h;
        ((ushort4*)Eb_lo)[i] = l;
    } else if (bb < 8704) {
        int idx = (bb - 6144) * 256 + t;
        int r = idx / 320;
        int k = (idx - r * 320) * 4;
        int go = ((r & 3) << 9) + (r >> 2);
        float4 v = (k < 768) ? *(const float4*)&W_ih[(size_t)go * 768 + k]
                             : *(const float4*)&W_hh[(size_t)go * 512 + (k - 768)];
        ushort4 h, l;
        h.x = bf16_rn(v.x); l.x = bf16_rn(v.x - bf16f(h.x));
        h.y = bf16_rn(v.y); l.y = bf16_rn(v.y - bf16f(h.y));
        h.z = bf16_rn(v.z); l.z = bf16_rn(v.z - bf16f(h.z));
        h.w = bf16_rn(v.w); l.w = bf16_rn(v.w - bf16f(h.w));
        *(ushort4*)&Wg_hi[(size_t)r * 1280 + k] = h;
        *(ushort4*)&Wg_lo[(size_t)r * 1280 + k] = l;
    } else if (bb < 8960) {
        int i = (bb - 8704) * 256 + t;
        float4 v = ((const float4*)W_attn)[i];
        ushort4 h, l;
        h.x = bf16_rn(v.x); l.x = bf16_rn(v.x - bf16f(h.x));
        h.y = bf16_rn(v.y); l.y = bf16_rn(v.y - bf16f(h.y));
        h.z = bf16_rn(v.z); l.z = bf16_rn(v.z - bf16f(h.z));
        h.w = bf16_rn(v.w); l.w = bf16_rn(v.w - bf16f(h.w));
        ((ushort4*)Wa_hi)[i] = h;
        ((ushort4*)Wa_lo)[i] = l;
    } else {
        int b = bb - 8960;
        int cnt = counts[b];
        const float* base = ctx + (size_t)b * C_ * D_;
        float s0 = 0.f, s1 = 0.f;
        for (int cc = 0; cc < cnt; ++cc) {
            s0 += base[(size_t)cc * D_ + t];
            s1 += base[(size_t)cc * D_ + t + 256];
        }
        float inv = 1.0f / (float)cnt;
        float v0 = s0 * inv, v1 = s1 * inv;
        c[b * D_ + t] = v0;       c[b * D_ + t + 256] = v1;
        unsigned short p0 = bf16_rn(v0), p1 = bf16_rn(v1);
        h_hi[b * D_ + t] = p0;    h_hi[b * D_ + t + 256] = p1;
        h_lo[b * D_ + t] = bf16_rn(v0 - bf16f(p0));
        h_lo[b * D_ + t + 256] = bf16_rn(v1 - bf16f(p1));
        if (t == 0) tok[b] = 1;
    }
}

// ---------------------------------------------------------------------------
// Shared split-bf16 GEMM body: C[64m x 128n] tile, K=512, 4 waves.
// PART=1: +bias + per-block argmax partials. PART=0: plain store.
// ---------------------------------------------------------------------------
template<int PART>
__device__ __forceinline__ void gemm_body(int nb, int mb,
                                          const unsigned short* __restrict__ Ah,
                                          const unsigned short* __restrict__ Al,
                                          const unsigned short* __restrict__ Bh,
                                          const unsigned short* __restrict__ Bl,
                                          const float* __restrict__ bias,
                                          float* __restrict__ C, int ldc,
                                          float* __restrict__ pvO,
                                          int* __restrict__ piO,
                                          short* As, short* Bs,
                                          float (*pvS)[2], int (*piS)[2]) {
    int t = threadIdx.x;
    int l = t & 63;
    int w = t >> 6;
    int m0 = mb * 64;
    int n0 = nb * 128;
    int srow = l & 15;
    int koct = 8 * (l >> 4);
    int pl = w & 1;
    int mtA = w >> 1;
    const unsigned short* Apl = pl ? Al : Ah;
    const unsigned short* Bpl = pl ? Bl : Bh;
    const unsigned short* ApA = Apl + (size_t)(m0 + mtA * 16 + srow) * 512 + koct;
    const unsigned short* ApB = ApA + 32 * 512;
    const unsigned short* Bp0 = Bpl + (size_t)(n0 + (w >> 1) * 16 + srow) * 512 + koct;

    short8 rA0, rA1, rB0, rB1, rB2, rB3;
    rA0 = *(const short8*)(ApA);
    rA1 = *(const short8*)(ApB);
    rB0 = *(const short8*)(Bp0);
    rB1 = *(const short8*)(Bp0 + 32 * 512);
    rB2 = *(const short8*)(Bp0 + 64 * 512);
    rB3 = *(const short8*)(Bp0 + 96 * 512);

    f32x4 z = {0.f, 0.f, 0.f, 0.f};
    f32x4 acc[2][4];
#pragma unroll
    for (int i = 0; i < 2; ++i)
#pragma unroll
        for (int j = 0; j < 4; ++j) acc[i][j] = z;

    int wm = w >> 1, wn = w & 1;
    for (int kt = 0; kt < 512; kt += 32) {
        __syncthreads();
        *(short8*)&As[(w)*512 + l * 8] = rA0;
        *(short8*)&As[(w + 4) * 512 + l * 8] = rA1;
        *(short8*)&Bs[(w)*512 + l * 8] = rB0;
        *(short8*)&Bs[(w + 4) * 512 + l * 8] = rB1;
        *(short8*)&Bs[(w + 8) * 512 + l * 8] = rB2;
        *(short8*)&Bs[(w + 12) * 512 + l * 8] = rB3;
        __syncthreads();
        if (kt + 32 < 512) {
            rA0 = *(const short8*)(ApA + kt + 32);
            rA1 = *(const short8*)(ApB + kt + 32);
            rB0 = *(const short8*)(Bp0 + kt + 32);
            rB1 = *(const short8*)(Bp0 + 32 * 512 + kt + 32);
            rB2 = *(const short8*)(Bp0 + 64 * 512 + kt + 32);
            rB3 = *(const short8*)(Bp0 + 96 * 512 + kt + 32);
        }
        short8 ah[2], al2[2], bh[4], bl2[4];
#pragma unroll
        for (int i = 0; i < 2; ++i) {
            ah[i] = *(short8*)&As[((wm * 2 + i) * 2 + 0) * 512 + l * 8];
            al2[i] = *(short8*)&As[((wm * 2 + i) * 2 + 1) * 512 + l * 8];
        }
#pragma unroll
        for (int j = 0; j < 4; ++j) {
            bh[j] = *(short8*)&Bs[((wn * 4 + j) * 2 + 0) * 512 + l * 8];
            bl2[j] = *(short8*)&Bs[((wn * 4 + j) * 2 + 1) * 512 + l * 8];
        }
#pragma unroll
        for (int i = 0; i < 2; ++i)
#pragma unroll
            for (int j = 0; j < 4; ++j) {
                acc[i][j] = __builtin_amdgcn_mfma_f32_16x16x32_bf16(ah[i], bh[j], acc[i][j], 0, 0, 0);
                acc[i][j] = __builtin_amdgcn_mfma_f32_16x16x32_bf16(ah[i], bl2[j], acc[i][j], 0, 0, 0);
                acc[i][j] = __builtin_amdgcn_mfma_f32_16x16x32_bf16(al2[i], bh[j], acc[i][j], 0, 0, 0);
            }
    }
    int r0 = (l >> 4) * 4;
    int cl = l & 15;
    if (PART) {
        float bj_[4];
#pragma unroll
        for (int j = 0; j < 4; ++j) bj_[j] = bias[n0 + wn * 64 + j * 16 + cl];
#pragma unroll
        for (int i = 0; i < 2; ++i) {
#pragma unroll
            for (int r = 0; r < 4; ++r) {
                int row = m0 + wm * 32 + i * 16 + r0 + r;
                float bv = -INFINITY;
                int bidx = 0x7fffffff;
#pragma unroll
                for (int j = 0; j < 4; ++j) {
                    int col = n0 + wn * 64 + j * 16 + cl;
                    float v = acc[i][j][r] + bj_[j];
                    C[(size_t)row * ldc + col] = v;
                    if (v > bv) { bv = v; bidx = col; }
                }
#pragma unroll
                for (int off = 1; off < 16; off <<= 1) {
                    float ov = __shfl_xor(bv, off);
                    int oi = __shfl_xor(bidx, off);
                    if (ov > bv || (ov == bv && oi < bidx)) { bv = ov; bidx = oi; }
                }
                if (cl == 0) {
                    pvS[wm * 32 + i * 16 + r0 + r][wn] = bv;
                    piS[wm * 32 + i * 16 + r0 + r][wn] = bidx;
                }
            }
        }
        __syncthreads();
        if (t < 64) {
            float v0 = pvS[t][0], v1 = pvS[t][1];
            int i0 = piS[t][0], i1 = piS[t][1];
            bool take1 = (v1 > v0);
            pvO[(size_t)(m0 + t) * 64 + nb] = take1 ? v1 : v0;
            piO[(size_t)(m0 + t) * 64 + nb] = take1 ? i1 : i0;
        }
    } else {
#pragma unroll
        for (int i = 0; i < 2; ++i)
#pragma unroll
            for (int j = 0; j < 4; ++j) {
                int col = n0 + wn * 64 + j * 16 + cl;
                int rowb = m0 + wm * 32 + i * 16 + r0;
#pragma unroll
                for (int r = 0; r < 4; ++r)
                    C[(size_t)(rowb + r) * ldc + col] = acc[i][j][r];
            }
    }
}

// ---------------------------------------------------------------------------
// mega: blocks [0,512) = logits(h) w/ XCD swizzle + argmax partials;
//       blocks [512,544) = qproj(h) -> qbuf (next step's q).
// ---------------------------------------------------------------------------
__global__ __launch_bounds__(256, 2) void k_mega(const unsigned short* __restrict__ Ah,
                                                 const unsigned short* __restrict__ Al,
                                                 const unsigned short* __restrict__ Wph,
                                                 const unsigned short* __restrict__ Wpl,
                                                 const float* __restrict__ bias,
                                                 float* __restrict__ Cl_,
                                                 float* __restrict__ pvO,
                                                 int* __restrict__ piO,
                                                 const unsigned short* __restrict__ Wah,
                                                 const unsigned short* __restrict__ Wal,
                                                 float* __restrict__ qbuf) {
    __shared__ short As[8 * 512];
    __shared__ short Bs[16 * 512];
    __shared__ float pvS[64][2];
    __shared__ int piS[64][2];
    int bb = blockIdx.x;
    if (bb < 512) {
        int xcd = bb & 7, lid = bb >> 3;
        int nb = xcd * 8 + (lid & 7);
        int mb = lid >> 3;
        gemm_body<1>(nb, mb, Ah, Al, Wph, Wpl, bias, Cl_, V_, pvO, piO,
                     As, Bs, pvS, piS);
    } else {
        int idx = bb - 512;
        int nb = idx & 3, mb = idx >> 2;
        gemm_body<0>(nb, mb, Ah, Al, Wah, Wal, nullptr, qbuf, D_, nullptr, nullptr,
                     As, Bs, pvS, piS);
    }
}

// standalone qproj for the first step (h0)
__global__ __launch_bounds__(256, 2) void k_qproj(const unsigned short* __restrict__ Ah,
                                                  const unsigned short* __restrict__ Al,
                                                  const unsigned short* __restrict__ Wah,
                                                  const unsigned short* __restrict__ Wal,
                                                  float* __restrict__ qbuf) {
    __shared__ short As[8 * 512];
    __shared__ short Bs[16 * 512];
    __shared__ float pvS[64][2];
    __shared__ int piS[64][2];
    int nb = blockIdx.x & 3, mb = blockIdx.x >> 2;
    gemm_body<0>(nb, mb, Ah, Al, Wah, Wal, nullptr, qbuf, D_, nullptr, nullptr,
                 As, Bs, pvS, piS);
}

// ---------------------------------------------------------------------------
// attention: single-pass online softmax. One block per batch row, 4 waves.
// ---------------------------------------------------------------------------
__global__ __launch_bounds__(256) void k_attn(const float* __restrict__ ctx,
                                              const int* __restrict__ counts,
                                              const float* __restrict__ q,
                                              unsigned short* __restrict__ cv_hi,
                                              unsigned short* __restrict__ cv_lo) {
    __shared__ float accw[4][512];
    __shared__ float mw_s[4], sw_s[4];
    int b = blockIdx.x;
    int t = threadIdx.x;
    int lane = t & 63;
    int wv = t >> 6;
    int cnt = counts[b];
    const float* cb = ctx + (size_t)b * C_ * D_;

    float4 q0 = *(const float4*)&q[(size_t)b * D_ + lane * 4];
    float4 q1 = *(const float4*)&q[(size_t)b * D_ + lane * 4 + 256];

    float m_w = -INFINITY, s_w = 0.f;
    float4 a0 = make_float4(0.f, 0.f, 0.f, 0.f);
    float4 a1 = make_float4(0.f, 0.f, 0.f, 0.f);

#define ATT_DOT(x0, x1) (x0.x * q0.x + x0.y * q0.y + x0.z * q0.z + x0.w * q0.w + \
                         x1.x * q1.x + x1.y * q1.y + x1.z * q1.z + x1.w * q1.w)
#define ATT_UPD(s, x0, x1)                                                     \
    {                                                                          \
        float e;                                                               \
        if (s > m_w) {                                                         \
            float sc = expf(m_w - s);                                          \
            s_w = s_w * sc + 1.f;                                              \
            a0.x *= sc; a0.y *= sc; a0.z *= sc; a0.w *= sc;                    \
            a1.x *= sc; a1.y *= sc; a1.z *= sc; a1.w *= sc;                    \
            m_w = s; e = 1.f;                                                  \
        } else {                                                               \
            e = expf(s - m_w);                                                 \
            s_w += e;                                                          \
        }                                                                      \
        a0.x += e * x0.x; a0.y += e * x0.y; a0.z += e * x0.z; a0.w += e * x0.w;\
        a1.x += e * x1.x; a1.y += e * x1.y; a1.z += e * x1.z; a1.w += e * x1.w;\
    }

    int cc = wv;
    for (; cc + 4 < cnt; cc += 8) {
        const float* rA = cb + (size_t)cc * D_;
        const float* rB = cb + (size_t)(cc + 4) * D_;
        float4 xa0 = *(const float4*)&rA[lane * 4];
        float4 xa1 = *(const float4*)&rA[lane * 4 + 256];
        float4 xb0 = *(const float4*)&rB[lane * 4];
        float4 xb1 = *(const float4*)&rB[lane * 4 + 256];
        float sa = ATT_DOT(xa0, xa1);
        float sb = ATT_DOT(xb0, xb1);
#pragma unroll
        for (int off = 32; off; off >>= 1) {
            sa += __shfl_xor(sa, off);
            sb += __shfl_xor(sb, off);
        }
        ATT_UPD(sa, xa0, xa1);
        ATT_UPD(sb, xb0, xb1);
    }
    if (cc < cnt) {
        const float* rA = cb + (size_t)cc * D_;
        float4 xa0 = *(const float4*)&rA[lane * 4];
        float4 xa1 = *(const float4*)&rA[lane * 4 + 256];
        float sa = ATT_DOT(xa0, xa1);
#pragma unroll
        for (int off = 32; off; off >>= 1) sa += __shfl_xor(sa, off);
        ATT_UPD(sa, xa0, xa1);
    }

    accw[wv][lane * 4 + 0] = a0.x; accw[wv][lane * 4 + 1] = a0.y;
    accw[wv][lane * 4 + 2] = a0.z; accw[wv][lane * 4 + 3] = a0.w;
    accw[wv][256 + lane * 4 + 0] = a1.x; accw[wv][256 + lane * 4 + 1] = a1.y;
    accw[wv][256 + lane * 4 + 2] = a1.z; accw[wv][256 + lane * 4 + 3] = a1.w;
    if (lane == 0) { mw_s[wv] = m_w; sw_s[wv] = s_w; }
    __syncthreads();

    float m_g = fmaxf(fmaxf(mw_s[0], mw_s[1]), fmaxf(mw_s[2], mw_s[3]));
    float e0 = expf(mw_s[0] - m_g), e1 = expf(mw_s[1] - m_g);
    float e2 = expf(mw_s[2] - m_g), e3 = expf(mw_s[3] - m_g);
    float inv = 1.0f / (sw_s[0] * e0 + sw_s[1] * e1 + sw_s[2] * e2 + sw_s[3] * e3);
    float v0 = (accw[0][t] * e0 + accw[1][t] * e1 + accw[2][t] * e2 + accw[3][t] * e3) * inv;
    float v1 = (accw[0][t + 256] * e0 + accw[1][t + 256] * e1 +
                accw[2][t + 256] * e2 + accw[3][t + 256] * e3) * inv;
    unsigned short p0 = bf16_rn(v0), p1 = bf16_rn(v1);
    cv_hi[(size_t)b * D_ + t] = p0;
    cv_hi[(size_t)b * D_ + t + 256] = p1;
    cv_lo[(size_t)b * D_ + t] = bf16_rn(v0 - bf16f(p0));
    cv_lo[(size_t)b * D_ + t + 256] = bf16_rn(v1 - bf16f(p1));
}

// ---------------------------------------------------------------------------
// gates GEMM (split-bf16 MFMA, K=1280) + fused LSTM epilogue.
// 64m x 32n tiles, 512 blocks (2/CU), XCD swizzle: nb = xcd*8+(lid&7).
// RED=1: prologue reduces argmax partials for this block's 64 rows -> toks.
// ---------------------------------------------------------------------------
template<int RED>
__global__ __launch_bounds__(256, 2) void k_gatesm(const int* __restrict__ tok,
                                                   const float* __restrict__ pvO,
                                                   const int* __restrict__ piO,
                                                   const unsigned short* __restrict__ Eh,
                                                   const unsigned short* __restrict__ El,
                                                   const unsigned short* __restrict__ Ch,
                                                   const unsigned short* __restrict__ Cl,
                                                   const unsigned short* __restrict__ Hh,
                                                   const unsigned short* __restrict__ Hl,
                                                   const unsigned short* __restrict__ Wh,
                                                   const unsigned short* __restrict__ Wl,
                                                   const float* __restrict__ b_ih,
                                                   const float* __restrict__ b_hh,
                                                   float* __restrict__ cbuf,
                                                   unsigned short* __restrict__ Hoh,
                                                   unsigned short* __restrict__ Hol) {
    __shared__ short As[8 * 512];
    __shared__ short Bs[4 * 512];
    __shared__ int toks[64];
    int bid = blockIdx.x;
    int t = threadIdx.x;
    int l = t & 63;
    int w = t >> 6;
    int xcd = bid & 7, lid = bid >> 3;
    int nb = xcd * 8 + (lid & 7);        // 0..63
    int mb = lid >> 3;                   // 0..7
    int m0 = mb * 64;
    int n0 = nb * 32;
    int srow = l & 15;
    int koct = 8 * (l >> 4);
    int pl = w & 1;
    int mtA = w >> 1;
    int locA = mtA * 16 + srow;          // 0..31
    int rowA = m0 + locA;
    int rowB = rowA + 32;

    if (RED) {
        int ri = t >> 2, qq = t & 3;
        const float* pv = pvO + (size_t)(m0 + ri) * 64 + qq * 16;
        const int* pi = piO + (size_t)(m0 + ri) * 64 + qq * 16;
        float bv = -INFINITY;
        int bix = 0x7fffffff;
#pragma unroll
        for (int j = 0; j < 16; ++j) {
            float v = pv[j];
            int ii = pi[j];
            if (v > bv || (v == bv && ii < bix)) { bv = v; bix = ii; }
        }
#pragma unroll
        for (int off = 1; off < 4; off <<= 1) {
            float ov = __shfl_xor(bv, off);
            int oi = __shfl_xor(bix, off);
            if (ov > bv || (ov == bv && oi < bix)) { bv = ov; bix = oi; }
        }
        if (qq == 0) toks[ri] = bix;
        __syncthreads();
    }

    int tokA = RED ? toks[locA] : tok[rowA];
    int tokB = RED ? toks[locA + 32] : tok[rowB];

    const unsigned short* Ep = pl ? El : Eh;
    const unsigned short* Cp = pl ? Cl : Ch;
    const unsigned short* Hp = pl ? Hl : Hh;
    const unsigned short* Wp = pl ? Wl : Wh;
    const unsigned short* Wp0 = Wp + (size_t)(n0 + (w >> 1) * 16 + srow) * 1280 + koct;

    f32x4 z = {0.f, 0.f, 0.f, 0.f};
    f32x4 acc[2];
    acc[0] = z; acc[1] = z;

    int wm = w >> 1, wn = w & 1;
    short8 rA0, rA1, rB0;

#define GATES_LOADA(dst, row, tk, kk)                                          \
    {                                                                          \
        int kx = (kk);                                                         \
        if (kx < 256)      dst = *(const short8*)&Ep[(size_t)(tk)*256 + kx];   \
        else if (kx < 768) dst = *(const short8*)&Cp[(size_t)(row)*512 + (kx - 256)]; \
        else               dst = *(const short8*)&Hp[(size_t)(row)*512 + (kx - 768)]; \
    }

    GATES_LOADA(rA0, rowA, tokA, koct);
    GATES_LOADA(rA1, rowB, tokB, koct);
    rB0 = *(const short8*)(Wp0);

    for (int kt = 0; kt < 1280; kt += 32) {
        __syncthreads();
        *(short8*)&As[(w)*512 + l * 8] = rA0;
        *(short8*)&As[(w + 4) * 512 + l * 8] = rA1;
        *(short8*)&Bs[(w)*512 + l * 8] = rB0;
        __syncthreads();
        if (kt + 32 < 1280) {
            GATES_LOADA(rA0, rowA, tokA, kt + 32 + koct);
            GATES_LOADA(rA1, rowB, tokB, kt + 32 + koct);
            rB0 = *(const short8*)(Wp0 + kt + 32);
        }
        short8 ah[2], al2[2], bh, bl2;
#pragma unroll
        for (int i = 0; i < 2; ++i) {
            ah[i] = *(short8*)&As[((wm * 2 + i) * 2 + 0) * 512 + l * 8];
            al2[i] = *(short8*)&As[((wm * 2 + i) * 2 + 1) * 512 + l * 8];
        }
        bh = *(short8*)&Bs[(wn * 2 + 0) * 512 + l * 8];
        bl2 = *(short8*)&Bs[(wn * 2 + 1) * 512 + l * 8];
#pragma unroll
        for (int i = 0; i < 2; ++i) {
            acc[i] = __builtin_amdgcn_mfma_f32_16x16x32_bf16(ah[i], bh, acc[i], 0, 0, 0);
            acc[i] = __builtin_amdgcn_mfma_f32_16x16x32_bf16(ah[i], bl2, acc[i], 0, 0, 0);
            acc[i] = __builtin_amdgcn_mfma_f32_16x16x32_bf16(al2[i], bh, acc[i], 0, 0, 0);
        }
    }

    int r0 = (l >> 4) * 4;
    int cl = l & 15;
    bool act = (cl & 3) == 0;
    int gc = n0 + wn * 16 + cl;
    int d = gc >> 2;
    float bi_ = b_ih[d] + b_hh[d];
    float bf_ = b_ih[512 + d] + b_hh[512 + d];
    float bg_ = b_ih[1024 + d] + b_hh[1024 + d];
    float bo_ = b_ih[1536 + d] + b_hh[1536 + d];
#pragma unroll
    for (int i = 0; i < 2; ++i) {
#pragma unroll
        for (int r = 0; r < 4; ++r) {
            float x = acc[i][r];
            float x1 = __shfl_xor(x, 1);
            float x2 = __shfl_xor(x, 2);
            float x3 = __shfl_xor(x, 3);
            if (act) {
                int row = m0 + wm * 32 + i * 16 + r0 + r;
                float ig = sigm(x + bi_);
                float fg = sigm(x1 + bf_);
                float gg = tanhf(x2 + bg_);
                float og = sigm(x3 + bo_);
                float cn = fg * cbuf[(size_t)row * D_ + d] + ig * gg;
                cbuf[(size_t)row * D_ + d] = cn;
                float hv = og * tanhf(cn);
                unsigned short hh = bf16_rn(hv);
                Hoh[(size_t)row * D_ + d] = hh;
                Hol[(size_t)row * D_ + d] = bf16_rn(hv - bf16f(hh));
            }
        }
    }
}

// ---------------------------------------------------------------------------
extern "C" void kernel_launch(void* const* d_in, const int* in_sizes, int n_in,
                              void* d_out, int out_size, void* d_ws, size_t ws_size,
                              hipStream_t stream) {
    const float* ctx    = (const float*)d_in[0];
    const int*   counts = (const int*)d_in[1];
    const float* emb    = (const float*)d_in[3];
    const float* W_attn = (const float*)d_in[4];
    const float* W_ih   = (const float*)d_in[5];
    const float* b_ih   = (const float*)d_in[6];
    const float* W_hh   = (const float*)d_in[7];
    const float* b_hh   = (const float*)d_in[8];
    const float* W_proj = (const float*)d_in[9];
    const float* b_proj = (const float*)d_in[10];
    float* out = (float*)d_out;

    float* qbuf = (float*)d_ws;                 // [512][512]
    float* cbuf = qbuf + B_ * D_;               // [512][512]
    unsigned short* p = (unsigned short*)(cbuf + B_ * D_);
    unsigned short* Wa_hi = p; p += D_ * D_;
    unsigned short* Wa_lo = p; p += D_ * D_;
    unsigned short* Wp_hi = p; p += (size_t)V_ * D_;
    unsigned short* Wp_lo = p; p += (size_t)V_ * D_;
    unsigned short* Eb_hi = p; p += (size_t)V_ * E_;
    unsigned short* Eb_lo = p; p += (size_t)V_ * E_;
    unsigned short* Wg_hi = p; p += (size_t)G_ * 1280;
    unsigned short* Wg_lo = p; p += (size_t)G_ * 1280;
    unsigned short* hA_hi = p; p += B_ * D_;
    unsigned short* hA_lo = p; p += B_ * D_;
    unsigned short* hB_hi = p; p += B_ * D_;
    unsigned short* hB_lo = p; p += B_ * D_;
    unsigned short* cv_hi = p; p += B_ * D_;
    unsigned short* cv_lo = p; p += B_ * D_;
    int* tok = (int*)p;                         // [512]
    float* pvO = (float*)(tok + B_);            // [512][64]
    int* piO = (int*)(pvO + B_ * 64);           // [512][64]

    k_setup<<<9472, 256, 0, stream>>>(W_proj, emb, W_ih, W_hh, W_attn, ctx, counts,
                                      Wp_hi, Wp_lo, Eb_hi, Eb_lo, Wg_hi, Wg_lo,
                                      Wa_hi, Wa_lo, hA_hi, hA_lo, cbuf, tok);

    hipMemsetAsync(out, 0, (size_t)B_ * V_ * sizeof(float), stream);

    // q for step 1 from h0
    k_qproj<<<32, 256, 0, stream>>>(hA_hi, hA_lo, Wa_hi, Wa_lo, qbuf);

    unsigned short *hin_hi = hA_hi, *hin_lo = hA_lo;
    unsigned short *hout_hi = hB_hi, *hout_lo = hB_lo;
    for (int t = 1; t < L_; ++t) {
        k_attn<<<B_, 256, 0, stream>>>(ctx, counts, qbuf, cv_hi, cv_lo);
        if (t == 1) {
            k_gatesm<0><<<512, 256, 0, stream>>>(
                tok, pvO, piO, Eb_hi, Eb_lo, cv_hi, cv_lo, hin_hi, hin_lo,
                Wg_hi, Wg_lo, b_ih, b_hh, cbuf, hout_hi, hout_lo);
        } else {
            k_gatesm<1><<<512, 256, 0, stream>>>(
                tok, pvO, piO, Eb_hi, Eb_lo, cv_hi, cv_lo, hin_hi, hin_lo,
                Wg_hi, Wg_lo, b_ih, b_hh, cbuf, hout_hi, hout_lo);
        }
        float* slab = out + (size_t)t * B_ * V_;
        k_mega<<<544, 256, 0, stream>>>(hout_hi, hout_lo, Wp_hi, Wp_lo, b_proj,
                                        slab, pvO, piO, Wa_hi, Wa_lo, qbuf);
        unsigned short* tmp;
        tmp = hin_hi; hin_hi = hout_hi; hout_hi = tmp;
        tmp = hin_lo; hin_lo = hout_lo; hout_lo = tmp;
    }
}

// Round 10
// 1479.763 us; speedup vs baseline: 5.0022x; 1.1338x over previous
//
#include <hip/hip_runtime.h>
#include <math.h>

#define B_ 512
#define C_ 200
#define D_ 512
#define E_ 256
#define V_ 8192
#define G_ 2048
#define L_ 16

typedef __attribute__((ext_vector_type(8))) short short8;
typedef __attribute__((ext_vector_type(4))) float f32x4;

__device__ __forceinline__ float sigm(float x) { return 1.0f / (1.0f + expf(-x)); }

__device__ __forceinline__ unsigned short bf16_rn(float x) {
    unsigned int u = __float_as_uint(x);
    return (unsigned short)((u + 0x7FFFu + ((u >> 16) & 1u)) >> 16);
}
__device__ __forceinline__ float bf16f(unsigned short h) {
    return __uint_as_float(((unsigned int)h) << 16);
}

// Canonical fragment layout for MFMA B-operands (16x16x32):
//   canon[((nt*NKT + kt)*64 + lane)*8 + e] = W[nt*16 + (lane&15)][kt*32 + (lane>>4)*8 + e]
// -> a wave's B-fragment load is one contiguous 1KB short8 load.

// ---------------------------------------------------------------------------
// merged setup (block ranges):
//   [0,2048)      : W_proj -> canonical hi/lo   (8192 rows x 512 k)
//   [2048,4096)   : emb    -> linear hi/lo planes
//   [4096,5376)   : Wg (gate-interleaved) -> canonical hi/lo (2048 x 1280)
//   [5376,5504)   : W_attn -> canonical hi/lo   (512 x 512)
//   [5504,6016)   : init h0=c0=mean, tok0=1
// ---------------------------------------------------------------------------
__global__ __launch_bounds__(256) void k_setup(const float* __restrict__ W_proj,
                                               const float* __restrict__ emb,
                                               const float* __restrict__ W_ih,
                                               const float* __restrict__ W_hh,
                                               const float* __restrict__ W_attn,
                                               const float* __restrict__ ctx,
                                               const int* __restrict__ counts,
                                               unsigned short* __restrict__ WpC_hi,
                                               unsigned short* __restrict__ WpC_lo,
                                               unsigned short* __restrict__ Eb_hi,
                                               unsigned short* __restrict__ Eb_lo,
                                               unsigned short* __restrict__ WgC_hi,
                                               unsigned short* __restrict__ WgC_lo,
                                               unsigned short* __restrict__ WaC_hi,
                                               unsigned short* __restrict__ WaC_lo,
                                               unsigned short* __restrict__ h_hi,
                                               unsigned short* __restrict__ h_lo,
                                               float* __restrict__ c,
                                               int* __restrict__ tok) {
    int bb = blockIdx.x;
    int t = threadIdx.x;
    if (bb < 2048) {
        // W_proj canonical: thread -> (n, koff), 8 k-elements
        int i = bb * 256 + t;                    // 0..524287
        int n = i >> 6;
        int koff = (i & 63) * 8;
        float4 v0 = *(const float4*)&W_proj[(size_t)n * 512 + koff];
        float4 v1 = *(const float4*)&W_proj[(size_t)n * 512 + koff + 4];
        float vv[8] = {v0.x, v0.y, v0.z, v0.w, v1.x, v1.y, v1.z, v1.w};
        short8 h8, l8;
#pragma unroll
        for (int e = 0; e < 8; ++e) {
            unsigned short hh = bf16_rn(vv[e]);
            h8[e] = (short)hh;
            l8[e] = (short)bf16_rn(vv[e] - bf16f(hh));
        }
        int nt = n >> 4, srow = n & 15, ktile = koff >> 5, oct = (koff >> 3) & 3;
        size_t off = (((size_t)nt * 16 + ktile) * 64 + (srow + (oct << 4))) * 8;
        *(short8*)&WpC_hi[off] = h8;
        *(short8*)&WpC_lo[off] = l8;
    } else if (bb < 4096) {
        int i = (bb - 2048) * 256 + t;           // V_*E_/4 = 524288
        float4 v = ((const float4*)emb)[i];
        ushort4 h, l;
        h.x = bf16_rn(v.x); l.x = bf16_rn(v.x - bf16f(h.x));
        h.y = bf16_rn(v.y); l.y = bf16_rn(v.y - bf16f(h.y));
        h.z = bf16_rn(v.z); l.z = bf16_rn(v.z - bf16f(h.z));
        h.w = bf16_rn(v.w); l.w = bf16_rn(v.w - bf16f(h.w));
        ((ushort4*)Eb_hi)[i] = h;
        ((ushort4*)Eb_lo)[i] = l;
    } else if (bb < 5376) {
        // Wg canonical: row r (gate-interleaved), K=1280
        int i = (bb - 4096) * 256 + t;           // 0..327679
        if (i < 327680) {
            int r = i / 160;
            int koff = (i - r * 160) * 8;
            int go = ((r & 3) << 9) + (r >> 2);
            float4 v0, v1;
            if (koff < 768) {
                v0 = *(const float4*)&W_ih[(size_t)go * 768 + koff];
                v1 = *(const float4*)&W_ih[(size_t)go * 768 + koff + 4];
            } else {
                v0 = *(const float4*)&W_hh[(size_t)go * 512 + (koff - 768)];
                v1 = *(const float4*)&W_hh[(size_t)go * 512 + (koff - 768) + 4];
            }
            float vv[8] = {v0.x, v0.y, v0.z, v0.w, v1.x, v1.y, v1.z, v1.w};
            short8 h8, l8;
#pragma unroll
            for (int e = 0; e < 8; ++e) {
                unsigned short hh = bf16_rn(vv[e]);
                h8[e] = (short)hh;
                l8[e] = (short)bf16_rn(vv[e] - bf16f(hh));
            }
            int nt = r >> 4, srow = r & 15, ktile = koff >> 5, oct = (koff >> 3) & 3;
            size_t off = (((size_t)nt * 40 + ktile) * 64 + (srow + (oct << 4))) * 8;
            *(short8*)&WgC_hi[off] = h8;
            *(short8*)&WgC_lo[off] = l8;
        }
    } else if (bb < 5504) {
        // W_attn canonical (512 x 512)
        int i = (bb - 5376) * 256 + t;           // 0..32767
        int n = i >> 6;
        int koff = (i & 63) * 8;
        float4 v0 = *(const float4*)&W_attn[(size_t)n * 512 + koff];
        float4 v1 = *(const float4*)&W_attn[(size_t)n * 512 + koff + 4];
        float vv[8] = {v0.x, v0.y, v0.z, v0.w, v1.x, v1.y, v1.z, v1.w};
        short8 h8, l8;
#pragma unroll
        for (int e = 0; e < 8; ++e) {
            unsigned short hh = bf16_rn(vv[e]);
            h8[e] = (short)hh;
            l8[e] = (short)bf16_rn(vv[e] - bf16f(hh));
        }
        int nt = n >> 4, srow = n & 15, ktile = koff >> 5, oct = (koff >> 3) & 3;
        size_t off = (((size_t)nt * 16 + ktile) * 64 + (srow + (oct << 4))) * 8;
        *(short8*)&WaC_hi[off] = h8;
        *(short8*)&WaC_lo[off] = l8;
    } else {
        int b = bb - 5504;
        int cnt = counts[b];
        const float* base = ctx + (size_t)b * C_ * D_;
        float s0 = 0.f, s1 = 0.f;
        for (int cc = 0; cc < cnt; ++cc) {
            s0 += base[(size_t)cc * D_ + t];
            s1 += base[(size_t)cc * D_ + t + 256];
        }
        float inv = 1.0f / (float)cnt;
        float v0 = s0 * inv, v1 = s1 * inv;
        c[b * D_ + t] = v0;       c[b * D_ + t + 256] = v1;
        unsigned short p0 = bf16_rn(v0), p1 = bf16_rn(v1);
        h_hi[b * D_ + t] = p0;    h_hi[b * D_ + t + 256] = p1;
        h_lo[b * D_ + t] = bf16_rn(v0 - bf16f(p0));
        h_lo[b * D_ + t + 256] = bf16_rn(v1 - bf16f(p1));
        if (t == 0) tok[b] = 1;
    }
}

// ---------------------------------------------------------------------------
// Split-bf16 GEMM body: C[64m x 128n], K=512 (16 ktiles), 4 waves.
// A: LDS-staged (row gather). B: direct canonical loads from L2, no LDS.
// PART=1: +bias + per-block argmax partials. PART=0: plain store.
// ---------------------------------------------------------------------------
template<int PART>
__device__ __forceinline__ void gemm_body(int nb, int mb,
                                          const unsigned short* __restrict__ Ah,
                                          const unsigned short* __restrict__ Al,
                                          const unsigned short* __restrict__ BhC,
                                          const unsigned short* __restrict__ BlC,
                                          const float* __restrict__ bias,
                                          float* __restrict__ C, int ldc,
                                          float* __restrict__ pvO,
                                          int* __restrict__ piO,
                                          short* As,
                                          float (*pvS)[2], int (*piS)[2]) {
    int t = threadIdx.x;
    int l = t & 63;
    int w = t >> 6;
    int m0 = mb * 64;
    int n0 = nb * 128;
    int srow = l & 15;
    int koct = 8 * (l >> 4);
    int pl = w & 1;
    int mtA = w >> 1;
    int wm = w >> 1, wn = w & 1;
    const unsigned short* Apl = pl ? Al : Ah;
    const unsigned short* ApA = Apl + (size_t)(m0 + mtA * 16 + srow) * 512 + koct;
    const unsigned short* ApB = ApA + 32 * 512;
    int ntbase = nb * 8 + wn * 4;
    const unsigned short* Bh0 = BhC + ((size_t)ntbase * 16) * 512 + l * 8;
    const unsigned short* Bl0 = BlC + ((size_t)ntbase * 16) * 512 + l * 8;

    short8 rA0 = *(const short8*)(ApA);
    short8 rA1 = *(const short8*)(ApB);

    f32x4 z = {0.f, 0.f, 0.f, 0.f};
    f32x4 acc[2][4];
#pragma unroll
    for (int i = 0; i < 2; ++i)
#pragma unroll
        for (int j = 0; j < 4; ++j) acc[i][j] = z;

    for (int kt = 0; kt < 16; ++kt) {
        // B fragments: contiguous canonical loads (L2), issued before barriers
        short8 bh[4], bl[4];
#pragma unroll
        for (int j = 0; j < 4; ++j) {
            bh[j] = *(const short8*)(Bh0 + ((size_t)j * 16 + kt) * 512);
            bl[j] = *(const short8*)(Bl0 + ((size_t)j * 16 + kt) * 512);
        }
        __syncthreads();
        *(short8*)&As[(w)*512 + l * 8] = rA0;
        *(short8*)&As[(w + 4) * 512 + l * 8] = rA1;
        __syncthreads();
        if (kt + 1 < 16) {
            int ke = kt * 32;
            rA0 = *(const short8*)(ApA + ke + 32);
            rA1 = *(const short8*)(ApB + ke + 32);
        }
        short8 ah[2], al2[2];
#pragma unroll
        for (int i = 0; i < 2; ++i) {
            ah[i] = *(short8*)&As[((wm * 2 + i) * 2 + 0) * 512 + l * 8];
            al2[i] = *(short8*)&As[((wm * 2 + i) * 2 + 1) * 512 + l * 8];
        }
#pragma unroll
        for (int i = 0; i < 2; ++i)
#pragma unroll
            for (int j = 0; j < 4; ++j) {
                acc[i][j] = __builtin_amdgcn_mfma_f32_16x16x32_bf16(ah[i], bh[j], acc[i][j], 0, 0, 0);
                acc[i][j] = __builtin_amdgcn_mfma_f32_16x16x32_bf16(ah[i], bl[j], acc[i][j], 0, 0, 0);
                acc[i][j] = __builtin_amdgcn_mfma_f32_16x16x32_bf16(al2[i], bh[j], acc[i][j], 0, 0, 0);
            }
    }
    int r0 = (l >> 4) * 4;
    int cl = l & 15;
    if (PART) {
        float bj_[4];
#pragma unroll
        for (int j = 0; j < 4; ++j) bj_[j] = bias[n0 + wn * 64 + j * 16 + cl];
#pragma unroll
        for (int i = 0; i < 2; ++i) {
#pragma unroll
            for (int r = 0; r < 4; ++r) {
                int row = m0 + wm * 32 + i * 16 + r0 + r;
                float bv = -INFINITY;
                int bidx = 0x7fffffff;
#pragma unroll
                for (int j = 0; j < 4; ++j) {
                    int col = n0 + wn * 64 + j * 16 + cl;
                    float v = acc[i][j][r] + bj_[j];
                    C[(size_t)row * ldc + col] = v;
                    if (v > bv) { bv = v; bidx = col; }
                }
#pragma unroll
                for (int off = 1; off < 16; off <<= 1) {
                    float ov = __shfl_xor(bv, off);
                    int oi = __shfl_xor(bidx, off);
                    if (ov > bv || (ov == bv && oi < bidx)) { bv = ov; bidx = oi; }
                }
                if (cl == 0) {
                    pvS[wm * 32 + i * 16 + r0 + r][wn] = bv;
                    piS[wm * 32 + i * 16 + r0 + r][wn] = bidx;
                }
            }
        }
        __syncthreads();
        if (t < 64) {
            float v0 = pvS[t][0], v1 = pvS[t][1];
            int i0 = piS[t][0], i1 = piS[t][1];
            bool take1 = (v1 > v0);
            pvO[(size_t)(m0 + t) * 64 + nb] = take1 ? v1 : v0;
            piO[(size_t)(m0 + t) * 64 + nb] = take1 ? i1 : i0;
        }
    } else {
#pragma unroll
        for (int i = 0; i < 2; ++i)
#pragma unroll
            for (int j = 0; j < 4; ++j) {
                int col = n0 + wn * 64 + j * 16 + cl;
                int rowb = m0 + wm * 32 + i * 16 + r0;
#pragma unroll
                for (int r = 0; r < 4; ++r)
                    C[(size_t)(rowb + r) * ldc + col] = acc[i][j][r];
            }
    }
}

// ---------------------------------------------------------------------------
// mega: blocks [0,512) = logits (XCD swizzle, argmax partials);
//       blocks [512,544) = qproj -> qbuf (next step's q).
// ---------------------------------------------------------------------------
__global__ __launch_bounds__(256, 2) void k_mega(const unsigned short* __restrict__ Ah,
                                                 const unsigned short* __restrict__ Al,
                                                 const unsigned short* __restrict__ WpCh,
                                                 const unsigned short* __restrict__ WpCl,
                                                 const float* __restrict__ bias,
                                                 float* __restrict__ Cl_,
                                                 float* __restrict__ pvO,
                                                 int* __restrict__ piO,
                                                 const unsigned short* __restrict__ WaCh,
                                                 const unsigned short* __restrict__ WaCl,
                                                 float* __restrict__ qbuf) {
    __shared__ short As[8 * 512];
    __shared__ float pvS[64][2];
    __shared__ int piS[64][2];
    int bb = blockIdx.x;
    if (bb < 512) {
        int xcd = bb & 7, lid = bb >> 3;
        int nb = xcd * 8 + (lid & 7);
        int mb = lid >> 3;
        gemm_body<1>(nb, mb, Ah, Al, WpCh, WpCl, bias, Cl_, V_, pvO, piO,
                     As, pvS, piS);
    } else {
        int idx = bb - 512;
        int nb = idx & 3, mb = idx >> 2;
        gemm_body<0>(nb, mb, Ah, Al, WaCh, WaCl, nullptr, qbuf, D_, nullptr, nullptr,
                     As, pvS, piS);
    }
}

// standalone qproj for the first step (h0)
__global__ __launch_bounds__(256, 2) void k_qproj(const unsigned short* __restrict__ Ah,
                                                  const unsigned short* __restrict__ Al,
                                                  const unsigned short* __restrict__ WaCh,
                                                  const unsigned short* __restrict__ WaCl,
                                                  float* __restrict__ qbuf) {
    __shared__ short As[8 * 512];
    __shared__ float pvS[64][2];
    __shared__ int piS[64][2];
    int nb = blockIdx.x & 3, mb = blockIdx.x >> 2;
    gemm_body<0>(nb, mb, Ah, Al, WaCh, WaCl, nullptr, qbuf, D_, nullptr, nullptr,
                 As, pvS, piS);
}

// ---------------------------------------------------------------------------
// attention: single-pass online softmax. One block per batch row, 4 waves.
// ---------------------------------------------------------------------------
__global__ __launch_bounds__(256) void k_attn(const float* __restrict__ ctx,
                                              const int* __restrict__ counts,
                                              const float* __restrict__ q,
                                              unsigned short* __restrict__ cv_hi,
                                              unsigned short* __restrict__ cv_lo) {
    __shared__ float accw[4][512];
    __shared__ float mw_s[4], sw_s[4];
    int b = blockIdx.x;
    int t = threadIdx.x;
    int lane = t & 63;
    int wv = t >> 6;
    int cnt = counts[b];
    const float* cb = ctx + (size_t)b * C_ * D_;

    float4 q0 = *(const float4*)&q[(size_t)b * D_ + lane * 4];
    float4 q1 = *(const float4*)&q[(size_t)b * D_ + lane * 4 + 256];

    float m_w = -INFINITY, s_w = 0.f;
    float4 a0 = make_float4(0.f, 0.f, 0.f, 0.f);
    float4 a1 = make_float4(0.f, 0.f, 0.f, 0.f);

#define ATT_DOT(x0, x1) (x0.x * q0.x + x0.y * q0.y + x0.z * q0.z + x0.w * q0.w + \
                         x1.x * q1.x + x1.y * q1.y + x1.z * q1.z + x1.w * q1.w)
#define ATT_UPD(s, x0, x1)                                                     \
    {                                                                          \
        float e;                                                               \
        if (s > m_w) {                                                         \
            float sc = expf(m_w - s);                                          \
            s_w = s_w * sc + 1.f;                                              \
            a0.x *= sc; a0.y *= sc; a0.z *= sc; a0.w *= sc;                    \
            a1.x *= sc; a1.y *= sc; a1.z *= sc; a1.w *= sc;                    \
            m_w = s; e = 1.f;                                                  \
        } else {                                                               \
            e = expf(s - m_w);                                                 \
            s_w += e;                                                          \
        }                                                                      \
        a0.x += e * x0.x; a0.y += e * x0.y; a0.z += e * x0.z; a0.w += e * x0.w;\
        a1.x += e * x1.x; a1.y += e * x1.y; a1.z += e * x1.z; a1.w += e * x1.w;\
    }

    int cc = wv;
    for (; cc + 4 < cnt; cc += 8) {
        const float* rA = cb + (size_t)cc * D_;
        const float* rB = cb + (size_t)(cc + 4) * D_;
        float4 xa0 = *(const float4*)&rA[lane * 4];
        float4 xa1 = *(const float4*)&rA[lane * 4 + 256];
        float4 xb0 = *(const float4*)&rB[lane * 4];
        float4 xb1 = *(const float4*)&rB[lane * 4 + 256];
        float sa = ATT_DOT(xa0, xa1);
        float sb = ATT_DOT(xb0, xb1);
#pragma unroll
        for (int off = 32; off; off >>= 1) {
            sa += __shfl_xor(sa, off);
            sb += __shfl_xor(sb, off);
        }
        ATT_UPD(sa, xa0, xa1);
        ATT_UPD(sb, xb0, xb1);
    }
    if (cc < cnt) {
        const float* rA = cb + (size_t)cc * D_;
        float4 xa0 = *(const float4*)&rA[lane * 4];
        float4 xa1 = *(const float4*)&rA[lane * 4 + 256];
        float sa = ATT_DOT(xa0, xa1);
#pragma unroll
        for (int off = 32; off; off >>= 1) sa += __shfl_xor(sa, off);
        ATT_UPD(sa, xa0, xa1);
    }

    accw[wv][lane * 4 + 0] = a0.x; accw[wv][lane * 4 + 1] = a0.y;
    accw[wv][lane * 4 + 2] = a0.z; accw[wv][lane * 4 + 3] = a0.w;
    accw[wv][256 + lane * 4 + 0] = a1.x; accw[wv][256 + lane * 4 + 1] = a1.y;
    accw[wv][256 + lane * 4 + 2] = a1.z; accw[wv][256 + lane * 4 + 3] = a1.w;
    if (lane == 0) { mw_s[wv] = m_w; sw_s[wv] = s_w; }
    __syncthreads();

    float m_g = fmaxf(fmaxf(mw_s[0], mw_s[1]), fmaxf(mw_s[2], mw_s[3]));
    float e0 = expf(mw_s[0] - m_g), e1 = expf(mw_s[1] - m_g);
    float e2 = expf(mw_s[2] - m_g), e3 = expf(mw_s[3] - m_g);
    float inv = 1.0f / (sw_s[0] * e0 + sw_s[1] * e1 + sw_s[2] * e2 + sw_s[3] * e3);
    float v0 = (accw[0][t] * e0 + accw[1][t] * e1 + accw[2][t] * e2 + accw[3][t] * e3) * inv;
    float v1 = (accw[0][t + 256] * e0 + accw[1][t + 256] * e1 +
                accw[2][t + 256] * e2 + accw[3][t + 256] * e3) * inv;
    unsigned short p0 = bf16_rn(v0), p1 = bf16_rn(v1);
    cv_hi[(size_t)b * D_ + t] = p0;
    cv_hi[(size_t)b * D_ + t + 256] = p1;
    cv_lo[(size_t)b * D_ + t] = bf16_rn(v0 - bf16f(p0));
    cv_lo[(size_t)b * D_ + t + 256] = bf16_rn(v1 - bf16f(p1));
}

// ---------------------------------------------------------------------------
// gates GEMM (split-bf16 MFMA, K=1280, 40 ktiles) + fused LSTM epilogue.
// 64m x 32n tiles, 512 blocks (2/CU), XCD swizzle. B: direct canonical loads.
// RED=1: prologue reduces argmax partials for this block's 64 rows -> toks.
// ---------------------------------------------------------------------------
template<int RED>
__global__ __launch_bounds__(256, 2) void k_gatesm(const int* __restrict__ tok,
                                                   const float* __restrict__ pvO,
                                                   const int* __restrict__ piO,
                                                   const unsigned short* __restrict__ Eh,
                                                   const unsigned short* __restrict__ El,
                                                   const unsigned short* __restrict__ Ch,
                                                   const unsigned short* __restrict__ Cl,
                                                   const unsigned short* __restrict__ Hh,
                                                   const unsigned short* __restrict__ Hl,
                                                   const unsigned short* __restrict__ WgCh,
                                                   const unsigned short* __restrict__ WgCl,
                                                   const float* __restrict__ b_ih,
                                                   const float* __restrict__ b_hh,
                                                   float* __restrict__ cbuf,
                                                   unsigned short* __restrict__ Hoh,
                                                   unsigned short* __restrict__ Hol) {
    __shared__ short As[8 * 512];
    __shared__ int toks[64];
    int bid = blockIdx.x;
    int t = threadIdx.x;
    int l = t & 63;
    int w = t >> 6;
    int xcd = bid & 7, lid = bid >> 3;
    int nb = xcd * 8 + (lid & 7);        // 0..63
    int mb = lid >> 3;                   // 0..7
    int m0 = mb * 64;
    int n0 = nb * 32;
    int srow = l & 15;
    int koct = 8 * (l >> 4);
    int pl = w & 1;
    int mtA = w >> 1;
    int locA = mtA * 16 + srow;          // 0..31
    int rowA = m0 + locA;
    int rowB = rowA + 32;

    if (RED) {
        int ri = t >> 2, qq = t & 3;
        const float* pv = pvO + (size_t)(m0 + ri) * 64 + qq * 16;
        const int* pi = piO + (size_t)(m0 + ri) * 64 + qq * 16;
        float bv = -INFINITY;
        int bix = 0x7fffffff;
#pragma unroll
        for (int j = 0; j < 16; ++j) {
            float v = pv[j];
            int ii = pi[j];
            if (v > bv || (v == bv && ii < bix)) { bv = v; bix = ii; }
        }
#pragma unroll
        for (int off = 1; off < 4; off <<= 1) {
            float ov = __shfl_xor(bv, off);
            int oi = __shfl_xor(bix, off);
            if (ov > bv || (ov == bv && oi < bix)) { bv = ov; bix = oi; }
        }
        if (qq == 0) toks[ri] = bix;
        __syncthreads();
    }

    int tokA = RED ? toks[locA] : tok[rowA];
    int tokB = RED ? toks[locA + 32] : tok[rowB];

    const unsigned short* Ep = pl ? El : Eh;
    const unsigned short* Cp = pl ? Cl : Ch;
    const unsigned short* Hp = pl ? Hl : Hh;
    int wm = w >> 1, wn = w & 1;
    int ntg = nb * 2 + wn;
    const unsigned short* Bh0 = WgCh + ((size_t)ntg * 40) * 512 + l * 8;
    const unsigned short* Bl0 = WgCl + ((size_t)ntg * 40) * 512 + l * 8;

    f32x4 z = {0.f, 0.f, 0.f, 0.f};
    f32x4 acc[2];
    acc[0] = z; acc[1] = z;

    short8 rA0, rA1;

#define GATES_LOADA(dst, row, tk, kk)                                          \
    {                                                                          \
        int kx = (kk);                                                         \
        if (kx < 256)      dst = *(const short8*)&Ep[(size_t)(tk)*256 + kx];   \
        else if (kx < 768) dst = *(const short8*)&Cp[(size_t)(row)*512 + (kx - 256)]; \
        else               dst = *(const short8*)&Hp[(size_t)(row)*512 + (kx - 768)]; \
    }

    GATES_LOADA(rA0, rowA, tokA, koct);
    GATES_LOADA(rA1, rowB, tokB, koct);

    for (int kt = 0; kt < 40; ++kt) {
        short8 bh = *(const short8*)(Bh0 + (size_t)kt * 512);
        short8 bl = *(const short8*)(Bl0 + (size_t)kt * 512);
        __syncthreads();
        *(short8*)&As[(w)*512 + l * 8] = rA0;
        *(short8*)&As[(w + 4) * 512 + l * 8] = rA1;
        __syncthreads();
        if (kt + 1 < 40) {
            int ke = kt * 32;
            GATES_LOADA(rA0, rowA, tokA, ke + 32 + koct);
            GATES_LOADA(rA1, rowB, tokB, ke + 32 + koct);
        }
        short8 ah[2], al2[2];
#pragma unroll
        for (int i = 0; i < 2; ++i) {
            ah[i] = *(short8*)&As[((wm * 2 + i) * 2 + 0) * 512 + l * 8];
            al2[i] = *(short8*)&As[((wm * 2 + i) * 2 + 1) * 512 + l * 8];
        }
#pragma unroll
        for (int i = 0; i < 2; ++i) {
            acc[i] = __builtin_amdgcn_mfma_f32_16x16x32_bf16(ah[i], bh, acc[i], 0, 0, 0);
            acc[i] = __builtin_amdgcn_mfma_f32_16x16x32_bf16(ah[i], bl, acc[i], 0, 0, 0);
            acc[i] = __builtin_amdgcn_mfma_f32_16x16x32_bf16(al2[i], bh, acc[i], 0, 0, 0);
        }
    }

    int r0 = (l >> 4) * 4;
    int cl = l & 15;
    bool act = (cl & 3) == 0;
    int gc = n0 + wn * 16 + cl;
    int d = gc >> 2;
    float bi_ = b_ih[d] + b_hh[d];
    float bf_ = b_ih[512 + d] + b_hh[512 + d];
    float bg_ = b_ih[1024 + d] + b_hh[1024 + d];
    float bo_ = b_ih[1536 + d] + b_hh[1536 + d];
#pragma unroll
    for (int i = 0; i < 2; ++i) {
#pragma unroll
        for (int r = 0; r < 4; ++r) {
            float x = acc[i][r];
            float x1 = __shfl_xor(x, 1);
            float x2 = __shfl_xor(x, 2);
            float x3 = __shfl_xor(x, 3);
            if (act) {
                int row = m0 + wm * 32 + i * 16 + r0 + r;
                float ig = sigm(x + bi_);
                float fg = sigm(x1 + bf_);
                float gg = tanhf(x2 + bg_);
                float og = sigm(x3 + bo_);
                float cn = fg * cbuf[(size_t)row * D_ + d] + ig * gg;
                cbuf[(size_t)row * D_ + d] = cn;
                float hv = og * tanhf(cn);
                unsigned short hh = bf16_rn(hv);
                Hoh[(size_t)row * D_ + d] = hh;
                Hol[(size_t)row * D_ + d] = bf16_rn(hv - bf16f(hh));
            }
        }
    }
}

// ---------------------------------------------------------------------------
extern "C" void kernel_launch(void* const* d_in, const int* in_sizes, int n_in,
                              void* d_out, int out_size, void* d_ws, size_t ws_size,
                              hipStream_t stream) {
    const float* ctx    = (const float*)d_in[0];
    const int*   counts = (const int*)d_in[1];
    const float* emb    = (const float*)d_in[3];
    const float* W_attn = (const float*)d_in[4];
    const float* W_ih   = (const float*)d_in[5];
    const float* b_ih   = (const float*)d_in[6];
    const float* W_hh   = (const float*)d_in[7];
    const float* b_hh   = (const float*)d_in[8];
    const float* W_proj = (const float*)d_in[9];
    const float* b_proj = (const float*)d_in[10];
    float* out = (float*)d_out;

    float* qbuf = (float*)d_ws;                 // [512][512]
    float* cbuf = qbuf + B_ * D_;               // [512][512]
    unsigned short* p = (unsigned short*)(cbuf + B_ * D_);
    unsigned short* Wa_hi = p; p += D_ * D_;
    unsigned short* Wa_lo = p; p += D_ * D_;
    unsigned short* Wp_hi = p; p += (size_t)V_ * D_;
    unsigned short* Wp_lo = p; p += (size_t)V_ * D_;
    unsigned short* Eb_hi = p; p += (size_t)V_ * E_;
    unsigned short* Eb_lo = p; p += (size_t)V_ * E_;
    unsigned short* Wg_hi = p; p += (size_t)G_ * 1280;
    unsigned short* Wg_lo = p; p += (size_t)G_ * 1280;
    unsigned short* hA_hi = p; p += B_ * D_;
    unsigned short* hA_lo = p; p += B_ * D_;
    unsigned short* hB_hi = p; p += B_ * D_;
    unsigned short* hB_lo = p; p += B_ * D_;
    unsigned short* cv_hi = p; p += B_ * D_;
    unsigned short* cv_lo = p; p += B_ * D_;
    int* tok = (int*)p;                         // [512]
    float* pvO = (float*)(tok + B_);            // [512][64]
    int* piO = (int*)(pvO + B_ * 64);           // [512][64]

    k_setup<<<6016, 256, 0, stream>>>(W_proj, emb, W_ih, W_hh, W_attn, ctx, counts,
                                      Wp_hi, Wp_lo, Eb_hi, Eb_lo, Wg_hi, Wg_lo,
                                      Wa_hi, Wa_lo, hA_hi, hA_lo, cbuf, tok);

    hipMemsetAsync(out, 0, (size_t)B_ * V_ * sizeof(float), stream);

    // q for step 1 from h0
    k_qproj<<<32, 256, 0, stream>>>(hA_hi, hA_lo, Wa_hi, Wa_lo, qbuf);

    unsigned short *hin_hi = hA_hi, *hin_lo = hA_lo;
    unsigned short *hout_hi = hB_hi, *hout_lo = hB_lo;
    for (int t = 1; t < L_; ++t) {
        k_attn<<<B_, 256, 0, stream>>>(ctx, counts, qbuf, cv_hi, cv_lo);
        if (t == 1) {
            k_gatesm<0><<<512, 256, 0, stream>>>(
                tok, pvO, piO, Eb_hi, Eb_lo, cv_hi, cv_lo, hin_hi, hin_lo,
                Wg_hi, Wg_lo, b_ih, b_hh, cbuf, hout_hi, hout_lo);
        } else {
            k_gatesm<1><<<512, 256, 0, stream>>>(
                tok, pvO, piO, Eb_hi, Eb_lo, cv_hi, cv_lo, hin_hi, hin_lo,
                Wg_hi, Wg_lo, b_ih, b_hh, cbuf, hout_hi, hout_lo);
        }
        float* slab = out + (size_t)t * B_ * V_;
        k_mega<<<544, 256, 0, stream>>>(hout_hi, hout_lo, Wp_hi, Wp_lo, b_proj,
                                        slab, pvO, piO, Wa_hi, Wa_lo, qbuf);
        unsigned short* tmp;
        tmp = hin_hi; hin_hi = hout_hi; hout_hi = tmp;
        tmp = hin_lo; hin_lo = hout_lo; hout_lo = tmp;
    }
}

// Round 11
// 1462.708 us; speedup vs baseline: 5.0605x; 1.0117x over previous
//
#include <hip/hip_runtime.h>
#include <math.h>

#define B_ 512
#define C_ 200
#define D_ 512
#define E_ 256
#define V_ 8192
#define G_ 2048
#define L_ 16

typedef __attribute__((ext_vector_type(8))) short short8;
typedef __attribute__((ext_vector_type(4))) float f32x4;

__device__ __forceinline__ float sigm(float x) { return 1.0f / (1.0f + expf(-x)); }

__device__ __forceinline__ unsigned short bf16_rn(float x) {
    unsigned int u = __float_as_uint(x);
    return (unsigned short)((u + 0x7FFFu + ((u >> 16) & 1u)) >> 16);
}
__device__ __forceinline__ float bf16f(unsigned short h) {
    return __uint_as_float(((unsigned int)h) << 16);
}

// Canonical fragment layout (16x16x32 MFMA operand):
//   canon[((tile*NKT + kt)*64 + lane)*8 + e] = M[tile*16 + (lane&15)][kt*32 + (lane>>4)*8 + e]
// -> a wave's fragment load/list is one contiguous 1KB short8 load.
__device__ __forceinline__ size_t canon_off(int row, int k, int NKT) {
    return ((((size_t)(row >> 4) * NKT + (k >> 5)) * 64) +
            ((row & 15) + (((k >> 3) & 3) << 4))) * 8 + (k & 7);
}

// ---------------------------------------------------------------------------
// merged setup (block ranges):
//   [0,2048)      : W_proj -> canonical hi/lo (8192 x 512)
//   [2048,4096)   : emb    -> linear hi/lo planes
//   [4096,5376)   : Wg (gate-interleaved) -> canonical hi/lo (2048 x 1280)
//   [5376,5504)   : W_attn -> canonical hi/lo (512 x 512)
//   [5504,6016)   : init h0 (canonical) = c0 = mean, tok0 = 1
//   [6016,10112)  : zero out slab 0 (16 MB)
// ---------------------------------------------------------------------------
__global__ __launch_bounds__(256) void k_setup(const float* __restrict__ W_proj,
                                               const float* __restrict__ emb,
                                               const float* __restrict__ W_ih,
                                               const float* __restrict__ W_hh,
                                               const float* __restrict__ W_attn,
                                               const float* __restrict__ ctx,
                                               const int* __restrict__ counts,
                                               unsigned short* __restrict__ WpC_hi,
                                               unsigned short* __restrict__ WpC_lo,
                                               unsigned short* __restrict__ Eb_hi,
                                               unsigned short* __restrict__ Eb_lo,
                                               unsigned short* __restrict__ WgC_hi,
                                               unsigned short* __restrict__ WgC_lo,
                                               unsigned short* __restrict__ WaC_hi,
                                               unsigned short* __restrict__ WaC_lo,
                                               unsigned short* __restrict__ h_hi,
                                               unsigned short* __restrict__ h_lo,
                                               float* __restrict__ c,
                                               int* __restrict__ tok,
                                               float* __restrict__ out0) {
    int bb = blockIdx.x;
    int t = threadIdx.x;
    if (bb < 2048) {
        int i = bb * 256 + t;
        int n = i >> 6;
        int koff = (i & 63) * 8;
        float4 v0 = *(const float4*)&W_proj[(size_t)n * 512 + koff];
        float4 v1 = *(const float4*)&W_proj[(size_t)n * 512 + koff + 4];
        float vv[8] = {v0.x, v0.y, v0.z, v0.w, v1.x, v1.y, v1.z, v1.w};
        short8 h8, l8;
#pragma unroll
        for (int e = 0; e < 8; ++e) {
            unsigned short hh = bf16_rn(vv[e]);
            h8[e] = (short)hh;
            l8[e] = (short)bf16_rn(vv[e] - bf16f(hh));
        }
        size_t off = canon_off(n, koff, 16);
        *(short8*)&WpC_hi[off] = h8;
        *(short8*)&WpC_lo[off] = l8;
    } else if (bb < 4096) {
        int i = (bb - 2048) * 256 + t;
        float4 v = ((const float4*)emb)[i];
        ushort4 h, l;
        h.x = bf16_rn(v.x); l.x = bf16_rn(v.x - bf16f(h.x));
        h.y = bf16_rn(v.y); l.y = bf16_rn(v.y - bf16f(h.y));
        h.z = bf16_rn(v.z); l.z = bf16_rn(v.z - bf16f(h.z));
        h.w = bf16_rn(v.w); l.w = bf16_rn(v.w - bf16f(h.w));
        ((ushort4*)Eb_hi)[i] = h;
        ((ushort4*)Eb_lo)[i] = l;
    } else if (bb < 5376) {
        int i = (bb - 4096) * 256 + t;
        if (i < 327680) {
            int r = i / 160;
            int koff = (i - r * 160) * 8;
            int go = ((r & 3) << 9) + (r >> 2);
            float4 v0, v1;
            if (koff < 768) {
                v0 = *(const float4*)&W_ih[(size_t)go * 768 + koff];
                v1 = *(const float4*)&W_ih[(size_t)go * 768 + koff + 4];
            } else {
                v0 = *(const float4*)&W_hh[(size_t)go * 512 + (koff - 768)];
                v1 = *(const float4*)&W_hh[(size_t)go * 512 + (koff - 768) + 4];
            }
            float vv[8] = {v0.x, v0.y, v0.z, v0.w, v1.x, v1.y, v1.z, v1.w};
            short8 h8, l8;
#pragma unroll
            for (int e = 0; e < 8; ++e) {
                unsigned short hh = bf16_rn(vv[e]);
                h8[e] = (short)hh;
                l8[e] = (short)bf16_rn(vv[e] - bf16f(hh));
            }
            size_t off = canon_off(r, koff, 40);
            *(short8*)&WgC_hi[off] = h8;
            *(short8*)&WgC_lo[off] = l8;
        }
    } else if (bb < 5504) {
        int i = (bb - 5376) * 256 + t;
        int n = i >> 6;
        int koff = (i & 63) * 8;
        float4 v0 = *(const float4*)&W_attn[(size_t)n * 512 + koff];
        float4 v1 = *(const float4*)&W_attn[(size_t)n * 512 + koff + 4];
        float vv[8] = {v0.x, v0.y, v0.z, v0.w, v1.x, v1.y, v1.z, v1.w};
        short8 h8, l8;
#pragma unroll
        for (int e = 0; e < 8; ++e) {
            unsigned short hh = bf16_rn(vv[e]);
            h8[e] = (short)hh;
            l8[e] = (short)bf16_rn(vv[e] - bf16f(hh));
        }
        size_t off = canon_off(n, koff, 16);
        *(short8*)&WaC_hi[off] = h8;
        *(short8*)&WaC_lo[off] = l8;
    } else if (bb < 6016) {
        int b = bb - 5504;
        int cnt = counts[b];
        const float* base = ctx + (size_t)b * C_ * D_;
        float s0 = 0.f, s1 = 0.f;
        for (int cc = 0; cc < cnt; ++cc) {
            s0 += base[(size_t)cc * D_ + t];
            s1 += base[(size_t)cc * D_ + t + 256];
        }
        float inv = 1.0f / (float)cnt;
        float v0 = s0 * inv, v1 = s1 * inv;
        c[b * D_ + t] = v0;       c[b * D_ + t + 256] = v1;
        unsigned short p0 = bf16_rn(v0), p1 = bf16_rn(v1);
        size_t o0 = canon_off(b, t, 16);
        size_t o1 = canon_off(b, t + 256, 16);
        h_hi[o0] = p0;            h_hi[o1] = p1;
        h_lo[o0] = bf16_rn(v0 - bf16f(p0));
        h_lo[o1] = bf16_rn(v1 - bf16f(p1));
        if (t == 0) tok[b] = 1;
    } else {
        int i = (bb - 6016) * 256 + t;   // 4096 blocks * 256 = 1M float4
        ((float4*)out0)[i] = make_float4(0.f, 0.f, 0.f, 0.f);
    }
}

// ---------------------------------------------------------------------------
// All-direct split-bf16 GEMM body: C[64m x 128n], K=512 (16 ktiles), 4 waves.
// A: canonical direct loads (h). B: canonical direct loads (weights).
// No LDS staging, no per-ktile barriers.
// PART=1: +bias + per-block argmax partials (1 barrier). PART=0: plain store.
// ---------------------------------------------------------------------------
template<int PART>
__device__ __forceinline__ void gemm_body(int nb, int mb,
                                          const unsigned short* __restrict__ Ah,
                                          const unsigned short* __restrict__ Al,
                                          const unsigned short* __restrict__ BhC,
                                          const unsigned short* __restrict__ BlC,
                                          const float* __restrict__ bias,
                                          float* __restrict__ C, int ldc,
                                          float* __restrict__ pvO,
                                          int* __restrict__ piO,
                                          float (*pvS)[2], int (*piS)[2]) {
    int t = threadIdx.x;
    int l = t & 63;
    int w = t >> 6;
    int wm = w >> 1, wn = w & 1;
    int m0 = mb * 64;
    int n0 = nb * 128;
    int tA0 = mb * 4 + wm * 2;
    const unsigned short* Ah0 = Ah + ((size_t)tA0 * 16) * 512 + l * 8;
    const unsigned short* Al0 = Al + ((size_t)tA0 * 16) * 512 + l * 8;
    int ntbase = nb * 8 + wn * 4;
    const unsigned short* Bh0 = BhC + ((size_t)ntbase * 16) * 512 + l * 8;
    const unsigned short* Bl0 = BlC + ((size_t)ntbase * 16) * 512 + l * 8;

    f32x4 z = {0.f, 0.f, 0.f, 0.f};
    f32x4 acc[2][4];
#pragma unroll
    for (int i = 0; i < 2; ++i)
#pragma unroll
        for (int j = 0; j < 4; ++j) acc[i][j] = z;

    for (int kt = 0; kt < 16; ++kt) {
        short8 ah[2], al[2], bh[4], bl[4];
#pragma unroll
        for (int i = 0; i < 2; ++i) {
            size_t o = ((size_t)i * 16 + kt) * 512;
            ah[i] = *(const short8*)(Ah0 + o);
            al[i] = *(const short8*)(Al0 + o);
        }
#pragma unroll
        for (int j = 0; j < 4; ++j) {
            size_t o = ((size_t)j * 16 + kt) * 512;
            bh[j] = *(const short8*)(Bh0 + o);
            bl[j] = *(const short8*)(Bl0 + o);
        }
#pragma unroll
        for (int i = 0; i < 2; ++i)
#pragma unroll
            for (int j = 0; j < 4; ++j) {
                acc[i][j] = __builtin_amdgcn_mfma_f32_16x16x32_bf16(ah[i], bh[j], acc[i][j], 0, 0, 0);
                acc[i][j] = __builtin_amdgcn_mfma_f32_16x16x32_bf16(ah[i], bl[j], acc[i][j], 0, 0, 0);
                acc[i][j] = __builtin_amdgcn_mfma_f32_16x16x32_bf16(al[i], bh[j], acc[i][j], 0, 0, 0);
            }
    }
    int r0 = (l >> 4) * 4;
    int cl = l & 15;
    if (PART) {
        float bj_[4];
#pragma unroll
        for (int j = 0; j < 4; ++j) bj_[j] = bias[n0 + wn * 64 + j * 16 + cl];
#pragma unroll
        for (int i = 0; i < 2; ++i) {
#pragma unroll
            for (int r = 0; r < 4; ++r) {
                int row = m0 + wm * 32 + i * 16 + r0 + r;
                float bv = -INFINITY;
                int bidx = 0x7fffffff;
#pragma unroll
                for (int j = 0; j < 4; ++j) {
                    int col = n0 + wn * 64 + j * 16 + cl;
                    float v = acc[i][j][r] + bj_[j];
                    C[(size_t)row * ldc + col] = v;
                    if (v > bv) { bv = v; bidx = col; }
                }
#pragma unroll
                for (int off = 1; off < 16; off <<= 1) {
                    float ov = __shfl_xor(bv, off);
                    int oi = __shfl_xor(bidx, off);
                    if (ov > bv || (ov == bv && oi < bidx)) { bv = ov; bidx = oi; }
                }
                if (cl == 0) {
                    pvS[wm * 32 + i * 16 + r0 + r][wn] = bv;
                    piS[wm * 32 + i * 16 + r0 + r][wn] = bidx;
                }
            }
        }
        __syncthreads();
        if (t < 64) {
            float v0 = pvS[t][0], v1 = pvS[t][1];
            int i0 = piS[t][0], i1 = piS[t][1];
            bool take1 = (v1 > v0);
            pvO[(size_t)(m0 + t) * 64 + nb] = take1 ? v1 : v0;
            piO[(size_t)(m0 + t) * 64 + nb] = take1 ? i1 : i0;
        }
    } else {
#pragma unroll
        for (int i = 0; i < 2; ++i)
#pragma unroll
            for (int j = 0; j < 4; ++j) {
                int col = n0 + wn * 64 + j * 16 + cl;
                int rowb = m0 + wm * 32 + i * 16 + r0;
#pragma unroll
                for (int r = 0; r < 4; ++r)
                    C[(size_t)(rowb + r) * ldc + col] = acc[i][j][r];
            }
    }
}

// ---------------------------------------------------------------------------
// mega: blocks [0,512) = logits (XCD swizzle, argmax partials);
//       blocks [512,544) = qproj -> qbuf (next step's q).
// ---------------------------------------------------------------------------
__global__ __launch_bounds__(256, 2) void k_mega(const unsigned short* __restrict__ Ah,
                                                 const unsigned short* __restrict__ Al,
                                                 const unsigned short* __restrict__ WpCh,
                                                 const unsigned short* __restrict__ WpCl,
                                                 const float* __restrict__ bias,
                                                 float* __restrict__ Cl_,
                                                 float* __restrict__ pvO,
                                                 int* __restrict__ piO,
                                                 const unsigned short* __restrict__ WaCh,
                                                 const unsigned short* __restrict__ WaCl,
                                                 float* __restrict__ qbuf) {
    __shared__ float pvS[64][2];
    __shared__ int piS[64][2];
    int bb = blockIdx.x;
    if (bb < 512) {
        int xcd = bb & 7, lid = bb >> 3;
        int nb = xcd * 8 + (lid & 7);
        int mb = lid >> 3;
        gemm_body<1>(nb, mb, Ah, Al, WpCh, WpCl, bias, Cl_, V_, pvO, piO, pvS, piS);
    } else {
        int idx = bb - 512;
        int nb = idx & 3, mb = idx >> 2;
        gemm_body<0>(nb, mb, Ah, Al, WaCh, WaCl, nullptr, qbuf, D_, nullptr, nullptr, pvS, piS);
    }
}

// standalone qproj for the first step (h0)
__global__ __launch_bounds__(256, 2) void k_qproj(const unsigned short* __restrict__ Ah,
                                                  const unsigned short* __restrict__ Al,
                                                  const unsigned short* __restrict__ WaCh,
                                                  const unsigned short* __restrict__ WaCl,
                                                  float* __restrict__ qbuf) {
    __shared__ float pvS[64][2];
    __shared__ int piS[64][2];
    int nb = blockIdx.x & 3, mb = blockIdx.x >> 2;
    gemm_body<0>(nb, mb, Ah, Al, WaCh, WaCl, nullptr, qbuf, D_, nullptr, nullptr, pvS, piS);
}

// ---------------------------------------------------------------------------
// attention: single-pass online softmax. One block per batch row, 4 waves.
// cv written in canonical fragment layout.
// ---------------------------------------------------------------------------
__global__ __launch_bounds__(256) void k_attn(const float* __restrict__ ctx,
                                              const int* __restrict__ counts,
                                              const float* __restrict__ q,
                                              unsigned short* __restrict__ cv_hi,
                                              unsigned short* __restrict__ cv_lo) {
    __shared__ float accw[4][512];
    __shared__ float mw_s[4], sw_s[4];
    int b = blockIdx.x;
    int t = threadIdx.x;
    int lane = t & 63;
    int wv = t >> 6;
    int cnt = counts[b];
    const float* cb = ctx + (size_t)b * C_ * D_;

    float4 q0 = *(const float4*)&q[(size_t)b * D_ + lane * 4];
    float4 q1 = *(const float4*)&q[(size_t)b * D_ + lane * 4 + 256];

    float m_w = -INFINITY, s_w = 0.f;
    float4 a0 = make_float4(0.f, 0.f, 0.f, 0.f);
    float4 a1 = make_float4(0.f, 0.f, 0.f, 0.f);

#define ATT_DOT(x0, x1) (x0.x * q0.x + x0.y * q0.y + x0.z * q0.z + x0.w * q0.w + \
                         x1.x * q1.x + x1.y * q1.y + x1.z * q1.z + x1.w * q1.w)
#define ATT_UPD(s, x0, x1)                                                     \
    {                                                                          \
        float e;                                                               \
        if (s > m_w) {                                                         \
            float sc = expf(m_w - s);                                          \
            s_w = s_w * sc + 1.f;                                              \
            a0.x *= sc; a0.y *= sc; a0.z *= sc; a0.w *= sc;                    \
            a1.x *= sc; a1.y *= sc; a1.z *= sc; a1.w *= sc;                    \
            m_w = s; e = 1.f;                                                  \
        } else {                                                               \
            e = expf(s - m_w);                                                 \
            s_w += e;                                                          \
        }                                                                      \
        a0.x += e * x0.x; a0.y += e * x0.y; a0.z += e * x0.z; a0.w += e * x0.w;\
        a1.x += e * x1.x; a1.y += e * x1.y; a1.z += e * x1.z; a1.w += e * x1.w;\
    }

    int cc = wv;
    for (; cc + 4 < cnt; cc += 8) {
        const float* rA = cb + (size_t)cc * D_;
        const float* rB = cb + (size_t)(cc + 4) * D_;
        float4 xa0 = *(const float4*)&rA[lane * 4];
        float4 xa1 = *(const float4*)&rA[lane * 4 + 256];
        float4 xb0 = *(const float4*)&rB[lane * 4];
        float4 xb1 = *(const float4*)&rB[lane * 4 + 256];
        float sa = ATT_DOT(xa0, xa1);
        float sb = ATT_DOT(xb0, xb1);
#pragma unroll
        for (int off = 32; off; off >>= 1) {
            sa += __shfl_xor(sa, off);
            sb += __shfl_xor(sb, off);
        }
        ATT_UPD(sa, xa0, xa1);
        ATT_UPD(sb, xb0, xb1);
    }
    if (cc < cnt) {
        const float* rA = cb + (size_t)cc * D_;
        float4 xa0 = *(const float4*)&rA[lane * 4];
        float4 xa1 = *(const float4*)&rA[lane * 4 + 256];
        float sa = ATT_DOT(xa0, xa1);
#pragma unroll
        for (int off = 32; off; off >>= 1) sa += __shfl_xor(sa, off);
        ATT_UPD(sa, xa0, xa1);
    }

    accw[wv][lane * 4 + 0] = a0.x; accw[wv][lane * 4 + 1] = a0.y;
    accw[wv][lane * 4 + 2] = a0.z; accw[wv][lane * 4 + 3] = a0.w;
    accw[wv][256 + lane * 4 + 0] = a1.x; accw[wv][256 + lane * 4 + 1] = a1.y;
    accw[wv][256 + lane * 4 + 2] = a1.z; accw[wv][256 + lane * 4 + 3] = a1.w;
    if (lane == 0) { mw_s[wv] = m_w; sw_s[wv] = s_w; }
    __syncthreads();

    float m_g = fmaxf(fmaxf(mw_s[0], mw_s[1]), fmaxf(mw_s[2], mw_s[3]));
    float e0 = expf(mw_s[0] - m_g), e1 = expf(mw_s[1] - m_g);
    float e2 = expf(mw_s[2] - m_g), e3 = expf(mw_s[3] - m_g);
    float inv = 1.0f / (sw_s[0] * e0 + sw_s[1] * e1 + sw_s[2] * e2 + sw_s[3] * e3);
    float v0 = (accw[0][t] * e0 + accw[1][t] * e1 + accw[2][t] * e2 + accw[3][t] * e3) * inv;
    float v1 = (accw[0][t + 256] * e0 + accw[1][t + 256] * e1 +
                accw[2][t + 256] * e2 + accw[3][t + 256] * e3) * inv;
    unsigned short p0 = bf16_rn(v0), p1 = bf16_rn(v1);
    size_t o0 = canon_off(b, t, 16);
    size_t o1 = canon_off(b, t + 256, 16);
    cv_hi[o0] = p0;
    cv_hi[o1] = p1;
    cv_lo[o0] = bf16_rn(v0 - bf16f(p0));
    cv_lo[o1] = bf16_rn(v1 - bf16f(p1));
}

// ---------------------------------------------------------------------------
// gates GEMM (split-bf16 MFMA, K=1280) + fused LSTM epilogue. ALL-DIRECT:
// A fragments loaded straight from emb (gather) / cv,h (canonical), B from
// canonical Wg. No LDS staging, no per-ktile barriers.
// 64m x 32n tiles, 512 blocks (2/CU), XCD swizzle.
// RED=1: prologue reduces argmax partials for this block's 64 rows -> toks.
// ---------------------------------------------------------------------------
template<int RED>
__global__ __launch_bounds__(256, 2) void k_gatesm(const int* __restrict__ tok,
                                                   const float* __restrict__ pvO,
                                                   const int* __restrict__ piO,
                                                   const unsigned short* __restrict__ Eh,
                                                   const unsigned short* __restrict__ El,
                                                   const unsigned short* __restrict__ Ch,
                                                   const unsigned short* __restrict__ Cl,
                                                   const unsigned short* __restrict__ Hh,
                                                   const unsigned short* __restrict__ Hl,
                                                   const unsigned short* __restrict__ WgCh,
                                                   const unsigned short* __restrict__ WgCl,
                                                   const float* __restrict__ b_ih,
                                                   const float* __restrict__ b_hh,
                                                   float* __restrict__ cbuf,
                                                   unsigned short* __restrict__ Hoh,
                                                   unsigned short* __restrict__ Hol) {
    __shared__ int toks[64];
    int bid = blockIdx.x;
    int t = threadIdx.x;
    int l = t & 63;
    int w = t >> 6;
    int wm = w >> 1, wn = w & 1;
    int xcd = bid & 7, lid = bid >> 3;
    int nb = xcd * 8 + (lid & 7);        // 0..63
    int mb = lid >> 3;                   // 0..7
    int m0 = mb * 64;
    int n0 = nb * 32;
    int koct = 8 * (l >> 4);

    if (RED) {
        int ri = t >> 2, qq = t & 3;
        const float* pv = pvO + (size_t)(m0 + ri) * 64 + qq * 16;
        const int* pi = piO + (size_t)(m0 + ri) * 64 + qq * 16;
        float bv = -INFINITY;
        int bix = 0x7fffffff;
#pragma unroll
        for (int j = 0; j < 16; ++j) {
            float v = pv[j];
            int ii = pi[j];
            if (v > bv || (v == bv && ii < bix)) { bv = v; bix = ii; }
        }
#pragma unroll
        for (int off = 1; off < 4; off <<= 1) {
            float ov = __shfl_xor(bv, off);
            int oi = __shfl_xor(bix, off);
            if (ov > bv || (ov == bv && oi < bix)) { bv = ov; bix = oi; }
        }
        if (qq == 0) toks[ri] = bix;
        __syncthreads();
    }

    // this wave consumes tiles {wm*2, wm*2+1} (local), global tiles mb*4 + ...
    int lr0 = wm * 32 + (l & 15);        // local row of tile wm*2
    int tk0 = RED ? toks[lr0] : tok[m0 + lr0];
    int tk1 = RED ? toks[lr0 + 16] : tok[m0 + lr0 + 16];
    int tg0 = mb * 4 + wm * 2;           // global tile of i=0
    const unsigned short* Ch0 = Ch + ((size_t)tg0 * 16) * 512 + l * 8;
    const unsigned short* Cl0 = Cl + ((size_t)tg0 * 16) * 512 + l * 8;
    const unsigned short* Hh0 = Hh + ((size_t)tg0 * 16) * 512 + l * 8;
    const unsigned short* Hl0 = Hl + ((size_t)tg0 * 16) * 512 + l * 8;
    int ntg = nb * 2 + wn;
    const unsigned short* Bh0 = WgCh + ((size_t)ntg * 40) * 512 + l * 8;
    const unsigned short* Bl0 = WgCl + ((size_t)ntg * 40) * 512 + l * 8;

    f32x4 z = {0.f, 0.f, 0.f, 0.f};
    f32x4 acc[2];
    acc[0] = z; acc[1] = z;

#define GATES_MFMA(a0h, a0l, a1h, a1l, bh, bl)                                   \
    acc[0] = __builtin_amdgcn_mfma_f32_16x16x32_bf16(a0h, bh, acc[0], 0, 0, 0);  \
    acc[0] = __builtin_amdgcn_mfma_f32_16x16x32_bf16(a0h, bl, acc[0], 0, 0, 0);  \
    acc[0] = __builtin_amdgcn_mfma_f32_16x16x32_bf16(a0l, bh, acc[0], 0, 0, 0);  \
    acc[1] = __builtin_amdgcn_mfma_f32_16x16x32_bf16(a1h, bh, acc[1], 0, 0, 0);  \
    acc[1] = __builtin_amdgcn_mfma_f32_16x16x32_bf16(a1h, bl, acc[1], 0, 0, 0);  \
    acc[1] = __builtin_amdgcn_mfma_f32_16x16x32_bf16(a1l, bh, acc[1], 0, 0, 0);

    // k in [0,256): emb gather
    for (int kt = 0; kt < 8; ++kt) {
        int ko = kt * 32 + koct;
        short8 a0h = *(const short8*)&Eh[(size_t)tk0 * 256 + ko];
        short8 a0l = *(const short8*)&El[(size_t)tk0 * 256 + ko];
        short8 a1h = *(const short8*)&Eh[(size_t)tk1 * 256 + ko];
        short8 a1l = *(const short8*)&El[(size_t)tk1 * 256 + ko];
        short8 bh = *(const short8*)(Bh0 + (size_t)kt * 512);
        short8 bl = *(const short8*)(Bl0 + (size_t)kt * 512);
        GATES_MFMA(a0h, a0l, a1h, a1l, bh, bl)
    }
    // k in [256,768): cv canonical
    for (int kt = 8; kt < 24; ++kt) {
        size_t oc = ((size_t)(kt - 8)) * 512;
        short8 a0h = *(const short8*)(Ch0 + oc);
        short8 a0l = *(const short8*)(Cl0 + oc);
        short8 a1h = *(const short8*)(Ch0 + 16 * 512 + oc);
        short8 a1l = *(const short8*)(Cl0 + 16 * 512 + oc);
        short8 bh = *(const short8*)(Bh0 + (size_t)kt * 512);
        short8 bl = *(const short8*)(Bl0 + (size_t)kt * 512);
        GATES_MFMA(a0h, a0l, a1h, a1l, bh, bl)
    }
    // k in [768,1280): h canonical
    for (int kt = 24; kt < 40; ++kt) {
        size_t oh = ((size_t)(kt - 24)) * 512;
        short8 a0h = *(const short8*)(Hh0 + oh);
        short8 a0l = *(const short8*)(Hl0 + oh);
        short8 a1h = *(const short8*)(Hh0 + 16 * 512 + oh);
        short8 a1l = *(const short8*)(Hl0 + 16 * 512 + oh);
        short8 bh = *(const short8*)(Bh0 + (size_t)kt * 512);
        short8 bl = *(const short8*)(Bl0 + (size_t)kt * 512);
        GATES_MFMA(a0h, a0l, a1h, a1l, bh, bl)
    }

    int r0 = (l >> 4) * 4;
    int cl = l & 15;
    bool act = (cl & 3) == 0;
    int gc = n0 + wn * 16 + cl;
    int d = gc >> 2;
    float bi_ = b_ih[d] + b_hh[d];
    float bf_ = b_ih[512 + d] + b_hh[512 + d];
    float bg_ = b_ih[1024 + d] + b_hh[1024 + d];
    float bo_ = b_ih[1536 + d] + b_hh[1536 + d];
#pragma unroll
    for (int i = 0; i < 2; ++i) {
#pragma unroll
        for (int r = 0; r < 4; ++r) {
            float x = acc[i][r];
            float x1 = __shfl_xor(x, 1);
            float x2 = __shfl_xor(x, 2);
            float x3 = __shfl_xor(x, 3);
            if (act) {
                int row = m0 + wm * 32 + i * 16 + r0 + r;
                float ig = sigm(x + bi_);
                float fg = sigm(x1 + bf_);
                float gg = tanhf(x2 + bg_);
                float og = sigm(x3 + bo_);
                float cn = fg * cbuf[(size_t)row * D_ + d] + ig * gg;
                cbuf[(size_t)row * D_ + d] = cn;
                float hv = og * tanhf(cn);
                unsigned short hh = bf16_rn(hv);
                size_t oo = canon_off(row, d, 16);
                Hoh[oo] = hh;
                Hol[oo] = bf16_rn(hv - bf16f(hh));
            }
        }
    }
}

// ---------------------------------------------------------------------------
extern "C" void kernel_launch(void* const* d_in, const int* in_sizes, int n_in,
                              void* d_out, int out_size, void* d_ws, size_t ws_size,
                              hipStream_t stream) {
    const float* ctx    = (const float*)d_in[0];
    const int*   counts = (const int*)d_in[1];
    const float* emb    = (const float*)d_in[3];
    const float* W_attn = (const float*)d_in[4];
    const float* W_ih   = (const float*)d_in[5];
    const float* b_ih   = (const float*)d_in[6];
    const float* W_hh   = (const float*)d_in[7];
    const float* b_hh   = (const float*)d_in[8];
    const float* W_proj = (const float*)d_in[9];
    const float* b_proj = (const float*)d_in[10];
    float* out = (float*)d_out;

    float* qbuf = (float*)d_ws;                 // [512][512]
    float* cbuf = qbuf + B_ * D_;               // [512][512]
    unsigned short* p = (unsigned short*)(cbuf + B_ * D_);
    unsigned short* Wa_hi = p; p += D_ * D_;
    unsigned short* Wa_lo = p; p += D_ * D_;
    unsigned short* Wp_hi = p; p += (size_t)V_ * D_;
    unsigned short* Wp_lo = p; p += (size_t)V_ * D_;
    unsigned short* Eb_hi = p; p += (size_t)V_ * E_;
    unsigned short* Eb_lo = p; p += (size_t)V_ * E_;
    unsigned short* Wg_hi = p; p += (size_t)G_ * 1280;
    unsigned short* Wg_lo = p; p += (size_t)G_ * 1280;
    unsigned short* hA_hi = p; p += B_ * D_;
    unsigned short* hA_lo = p; p += B_ * D_;
    unsigned short* hB_hi = p; p += B_ * D_;
    unsigned short* hB_lo = p; p += B_ * D_;
    unsigned short* cv_hi = p; p += B_ * D_;
    unsigned short* cv_lo = p; p += B_ * D_;
    int* tok = (int*)p;                         // [512]
    float* pvO = (float*)(tok + B_);            // [512][64]
    int* piO = (int*)(pvO + B_ * 64);           // [512][64]

    k_setup<<<10112, 256, 0, stream>>>(W_proj, emb, W_ih, W_hh, W_attn, ctx, counts,
                                       Wp_hi, Wp_lo, Eb_hi, Eb_lo, Wg_hi, Wg_lo,
                                       Wa_hi, Wa_lo, hA_hi, hA_lo, cbuf, tok, out);

    // q for step 1 from h0
    k_qproj<<<32, 256, 0, stream>>>(hA_hi, hA_lo, Wa_hi, Wa_lo, qbuf);

    unsigned short *hin_hi = hA_hi, *hin_lo = hA_lo;
    unsigned short *hout_hi = hB_hi, *hout_lo = hB_lo;
    for (int t = 1; t < L_; ++t) {
        k_attn<<<B_, 256, 0, stream>>>(ctx, counts, qbuf, cv_hi, cv_lo);
        if (t == 1) {
            k_gatesm<0><<<512, 256, 0, stream>>>(
                tok, pvO, piO, Eb_hi, Eb_lo, cv_hi, cv_lo, hin_hi, hin_lo,
                Wg_hi, Wg_lo, b_ih, b_hh, cbuf, hout_hi, hout_lo);
        } else {
            k_gatesm<1><<<512, 256, 0, stream>>>(
                tok, pvO, piO, Eb_hi, Eb_lo, cv_hi, cv_lo, hin_hi, hin_lo,
                Wg_hi, Wg_lo, b_ih, b_hh, cbuf, hout_hi, hout_lo);
        }
        float* slab = out + (size_t)t * B_ * V_;
        k_mega<<<544, 256, 0, stream>>>(hout_hi, hout_lo, Wp_hi, Wp_lo, b_proj,
                                        slab, pvO, piO, Wa_hi, Wa_lo, qbuf);
        unsigned short* tmp;
        tmp = hin_hi; hin_hi = hout_hi; hout_hi = tmp;
        tmp = hin_lo; hin_lo = hout_lo; hout_lo = tmp;
    }
}

// Round 12
// 1375.728 us; speedup vs baseline: 5.3805x; 1.0632x over previous
//
#include <hip/hip_runtime.h>
#include <math.h>

#define B_ 512
#define C_ 200
#define D_ 512
#define E_ 256
#define V_ 8192
#define G_ 2048
#define L_ 16

typedef __attribute__((ext_vector_type(8))) short short8;
typedef __attribute__((ext_vector_type(4))) float f32x4;

__device__ __forceinline__ float sigm(float x) { return 1.0f / (1.0f + expf(-x)); }

__device__ __forceinline__ unsigned short bf16_rn(float x) {
    unsigned int u = __float_as_uint(x);
    return (unsigned short)((u + 0x7FFFu + ((u >> 16) & 1u)) >> 16);
}
__device__ __forceinline__ float bf16f(unsigned short h) {
    return __uint_as_float(((unsigned int)h) << 16);
}

// Canonical fragment layout (16x16x32 MFMA operand):
//   canon[((tile*NKT + kt)*64 + lane)*8 + e] = M[tile*16 + (lane&15)][kt*32 + (lane>>4)*8 + e]
__device__ __forceinline__ size_t canon_off(int row, int k, int NKT) {
    return ((((size_t)(row >> 4) * NKT + (k >> 5)) * 64) +
            ((row & 15) + (((k >> 3) & 3) << 4))) * 8 + (k & 7);
}

// ---------------------------------------------------------------------------
// merged setup (block ranges):
//   [0,2048) W_proj->canon  [2048,4096) emb  [4096,5376) Wg->canon
//   [5376,5504) W_attn->canon  [5504,6016) init  [6016,10112) zero out slab 0
// ---------------------------------------------------------------------------
__global__ __launch_bounds__(256) void k_setup(const float* __restrict__ W_proj,
                                               const float* __restrict__ emb,
                                               const float* __restrict__ W_ih,
                                               const float* __restrict__ W_hh,
                                               const float* __restrict__ W_attn,
                                               const float* __restrict__ ctx,
                                               const int* __restrict__ counts,
                                               unsigned short* __restrict__ WpC_hi,
                                               unsigned short* __restrict__ WpC_lo,
                                               unsigned short* __restrict__ Eb_hi,
                                               unsigned short* __restrict__ Eb_lo,
                                               unsigned short* __restrict__ WgC_hi,
                                               unsigned short* __restrict__ WgC_lo,
                                               unsigned short* __restrict__ WaC_hi,
                                               unsigned short* __restrict__ WaC_lo,
                                               unsigned short* __restrict__ h_hi,
                                               unsigned short* __restrict__ h_lo,
                                               float* __restrict__ c,
                                               int* __restrict__ tok,
                                               float* __restrict__ out0) {
    int bb = blockIdx.x;
    int t = threadIdx.x;
    if (bb < 2048) {
        int i = bb * 256 + t;
        int n = i >> 6;
        int koff = (i & 63) * 8;
        float4 v0 = *(const float4*)&W_proj[(size_t)n * 512 + koff];
        float4 v1 = *(const float4*)&W_proj[(size_t)n * 512 + koff + 4];
        float vv[8] = {v0.x, v0.y, v0.z, v0.w, v1.x, v1.y, v1.z, v1.w};
        short8 h8, l8;
#pragma unroll
        for (int e = 0; e < 8; ++e) {
            unsigned short hh = bf16_rn(vv[e]);
            h8[e] = (short)hh;
            l8[e] = (short)bf16_rn(vv[e] - bf16f(hh));
        }
        size_t off = canon_off(n, koff, 16);
        *(short8*)&WpC_hi[off] = h8;
        *(short8*)&WpC_lo[off] = l8;
    } else if (bb < 4096) {
        int i = (bb - 2048) * 256 + t;
        float4 v = ((const float4*)emb)[i];
        ushort4 h, l;
        h.x = bf16_rn(v.x); l.x = bf16_rn(v.x - bf16f(h.x));
        h.y = bf16_rn(v.y); l.y = bf16_rn(v.y - bf16f(h.y));
        h.z = bf16_rn(v.z); l.z = bf16_rn(v.z - bf16f(h.z));
        h.w = bf16_rn(v.w); l.w = bf16_rn(v.w - bf16f(h.w));
        ((ushort4*)Eb_hi)[i] = h;
        ((ushort4*)Eb_lo)[i] = l;
    } else if (bb < 5376) {
        int i = (bb - 4096) * 256 + t;
        if (i < 327680) {
            int r = i / 160;
            int koff = (i - r * 160) * 8;
            int go = ((r & 3) << 9) + (r >> 2);
            float4 v0, v1;
            if (koff < 768) {
                v0 = *(const float4*)&W_ih[(size_t)go * 768 + koff];
                v1 = *(const float4*)&W_ih[(size_t)go * 768 + koff + 4];
            } else {
                v0 = *(const float4*)&W_hh[(size_t)go * 512 + (koff - 768)];
                v1 = *(const float4*)&W_hh[(size_t)go * 512 + (koff - 768) + 4];
            }
            float vv[8] = {v0.x, v0.y, v0.z, v0.w, v1.x, v1.y, v1.z, v1.w};
            short8 h8, l8;
#pragma unroll
            for (int e = 0; e < 8; ++e) {
                unsigned short hh = bf16_rn(vv[e]);
                h8[e] = (short)hh;
                l8[e] = (short)bf16_rn(vv[e] - bf16f(hh));
            }
            size_t off = canon_off(r, koff, 40);
            *(short8*)&WgC_hi[off] = h8;
            *(short8*)&WgC_lo[off] = l8;
        }
    } else if (bb < 5504) {
        int i = (bb - 5376) * 256 + t;
        int n = i >> 6;
        int koff = (i & 63) * 8;
        float4 v0 = *(const float4*)&W_attn[(size_t)n * 512 + koff];
        float4 v1 = *(const float4*)&W_attn[(size_t)n * 512 + koff + 4];
        float vv[8] = {v0.x, v0.y, v0.z, v0.w, v1.x, v1.y, v1.z, v1.w};
        short8 h8, l8;
#pragma unroll
        for (int e = 0; e < 8; ++e) {
            unsigned short hh = bf16_rn(vv[e]);
            h8[e] = (short)hh;
            l8[e] = (short)bf16_rn(vv[e] - bf16f(hh));
        }
        size_t off = canon_off(n, koff, 16);
        *(short8*)&WaC_hi[off] = h8;
        *(short8*)&WaC_lo[off] = l8;
    } else if (bb < 6016) {
        int b = bb - 5504;
        int cnt = counts[b];
        const float* base = ctx + (size_t)b * C_ * D_;
        float s0 = 0.f, s1 = 0.f;
        for (int cc = 0; cc < cnt; ++cc) {
            s0 += base[(size_t)cc * D_ + t];
            s1 += base[(size_t)cc * D_ + t + 256];
        }
        float inv = 1.0f / (float)cnt;
        float v0 = s0 * inv, v1 = s1 * inv;
        c[b * D_ + t] = v0;       c[b * D_ + t + 256] = v1;
        unsigned short p0 = bf16_rn(v0), p1 = bf16_rn(v1);
        size_t o0 = canon_off(b, t, 16);
        size_t o1 = canon_off(b, t + 256, 16);
        h_hi[o0] = p0;            h_hi[o1] = p1;
        h_lo[o0] = bf16_rn(v0 - bf16f(p0));
        h_lo[o1] = bf16_rn(v1 - bf16f(p1));
        if (t == 0) tok[b] = 1;
    } else {
        int i = (bb - 6016) * 256 + t;
        ((float4*)out0)[i] = make_float4(0.f, 0.f, 0.f, 0.f);
    }
}

// ---------------------------------------------------------------------------
// All-direct split-bf16 GEMM body: C[64m x 128n], K=512 (16 ktiles), 4 waves.
// ---------------------------------------------------------------------------
template<int PART>
__device__ __forceinline__ void gemm_body(int nb, int mb,
                                          const unsigned short* __restrict__ Ah,
                                          const unsigned short* __restrict__ Al,
                                          const unsigned short* __restrict__ BhC,
                                          const unsigned short* __restrict__ BlC,
                                          const float* __restrict__ bias,
                                          float* __restrict__ C, int ldc,
                                          float* __restrict__ pvO,
                                          int* __restrict__ piO,
                                          float (*pvS)[2], int (*piS)[2]) {
    int t = threadIdx.x;
    int l = t & 63;
    int w = t >> 6;
    int wm = w >> 1, wn = w & 1;
    int m0 = mb * 64;
    int n0 = nb * 128;
    int tA0 = mb * 4 + wm * 2;
    const unsigned short* Ah0 = Ah + ((size_t)tA0 * 16) * 512 + l * 8;
    const unsigned short* Al0 = Al + ((size_t)tA0 * 16) * 512 + l * 8;
    int ntbase = nb * 8 + wn * 4;
    const unsigned short* Bh0 = BhC + ((size_t)ntbase * 16) * 512 + l * 8;
    const unsigned short* Bl0 = BlC + ((size_t)ntbase * 16) * 512 + l * 8;

    f32x4 z = {0.f, 0.f, 0.f, 0.f};
    f32x4 acc[2][4];
#pragma unroll
    for (int i = 0; i < 2; ++i)
#pragma unroll
        for (int j = 0; j < 4; ++j) acc[i][j] = z;

    for (int kt = 0; kt < 16; ++kt) {
        short8 ah[2], al[2], bh[4], bl[4];
#pragma unroll
        for (int i = 0; i < 2; ++i) {
            size_t o = ((size_t)i * 16 + kt) * 512;
            ah[i] = *(const short8*)(Ah0 + o);
            al[i] = *(const short8*)(Al0 + o);
        }
#pragma unroll
        for (int j = 0; j < 4; ++j) {
            size_t o = ((size_t)j * 16 + kt) * 512;
            bh[j] = *(const short8*)(Bh0 + o);
            bl[j] = *(const short8*)(Bl0 + o);
        }
#pragma unroll
        for (int i = 0; i < 2; ++i)
#pragma unroll
            for (int j = 0; j < 4; ++j) {
                acc[i][j] = __builtin_amdgcn_mfma_f32_16x16x32_bf16(ah[i], bh[j], acc[i][j], 0, 0, 0);
                acc[i][j] = __builtin_amdgcn_mfma_f32_16x16x32_bf16(ah[i], bl[j], acc[i][j], 0, 0, 0);
                acc[i][j] = __builtin_amdgcn_mfma_f32_16x16x32_bf16(al[i], bh[j], acc[i][j], 0, 0, 0);
            }
    }
    int r0 = (l >> 4) * 4;
    int cl = l & 15;
    if (PART) {
        float bj_[4];
#pragma unroll
        for (int j = 0; j < 4; ++j) bj_[j] = bias[n0 + wn * 64 + j * 16 + cl];
#pragma unroll
        for (int i = 0; i < 2; ++i) {
#pragma unroll
            for (int r = 0; r < 4; ++r) {
                int row = m0 + wm * 32 + i * 16 + r0 + r;
                float bv = -INFINITY;
                int bidx = 0x7fffffff;
#pragma unroll
                for (int j = 0; j < 4; ++j) {
                    int col = n0 + wn * 64 + j * 16 + cl;
                    float v = acc[i][j][r] + bj_[j];
                    C[(size_t)row * ldc + col] = v;
                    if (v > bv) { bv = v; bidx = col; }
                }
#pragma unroll
                for (int off = 1; off < 16; off <<= 1) {
                    float ov = __shfl_xor(bv, off);
                    int oi = __shfl_xor(bidx, off);
                    if (ov > bv || (ov == bv && oi < bidx)) { bv = ov; bidx = oi; }
                }
                if (cl == 0) {
                    pvS[wm * 32 + i * 16 + r0 + r][wn] = bv;
                    piS[wm * 32 + i * 16 + r0 + r][wn] = bidx;
                }
            }
        }
        __syncthreads();
        if (t < 64) {
            float v0 = pvS[t][0], v1 = pvS[t][1];
            int i0 = piS[t][0], i1 = piS[t][1];
            bool take1 = (v1 > v0);
            pvO[(size_t)(m0 + t) * 64 + nb] = take1 ? v1 : v0;
            piO[(size_t)(m0 + t) * 64 + nb] = take1 ? i1 : i0;
        }
    } else {
#pragma unroll
        for (int i = 0; i < 2; ++i)
#pragma unroll
            for (int j = 0; j < 4; ++j) {
                int col = n0 + wn * 64 + j * 16 + cl;
                int rowb = m0 + wm * 32 + i * 16 + r0;
#pragma unroll
                for (int r = 0; r < 4; ++r)
                    C[(size_t)(rowb + r) * ldc + col] = acc[i][j][r];
            }
    }
}

// ---------------------------------------------------------------------------
// mega: blocks [0,512) = logits (XCD swizzle, argmax partials);
//       blocks [512,544) = qproj -> qbuf (next step's q).
// ---------------------------------------------------------------------------
__global__ __launch_bounds__(256, 2) void k_mega(const unsigned short* __restrict__ Ah,
                                                 const unsigned short* __restrict__ Al,
                                                 const unsigned short* __restrict__ WpCh,
                                                 const unsigned short* __restrict__ WpCl,
                                                 const float* __restrict__ bias,
                                                 float* __restrict__ Cl_,
                                                 float* __restrict__ pvO,
                                                 int* __restrict__ piO,
                                                 const unsigned short* __restrict__ WaCh,
                                                 const unsigned short* __restrict__ WaCl,
                                                 float* __restrict__ qbuf) {
    __shared__ float pvS[64][2];
    __shared__ int piS[64][2];
    int bb = blockIdx.x;
    if (bb < 512) {
        int xcd = bb & 7, lid = bb >> 3;
        int nb = xcd * 8 + (lid & 7);
        int mb = lid >> 3;
        gemm_body<1>(nb, mb, Ah, Al, WpCh, WpCl, bias, Cl_, V_, pvO, piO, pvS, piS);
    } else {
        int idx = bb - 512;
        int nb = idx & 3, mb = idx >> 2;
        gemm_body<0>(nb, mb, Ah, Al, WaCh, WaCl, nullptr, qbuf, D_, nullptr, nullptr, pvS, piS);
    }
}

// standalone qproj for the first step (h0)
__global__ __launch_bounds__(256, 2) void k_qproj(const unsigned short* __restrict__ Ah,
                                                  const unsigned short* __restrict__ Al,
                                                  const unsigned short* __restrict__ WaCh,
                                                  const unsigned short* __restrict__ WaCl,
                                                  float* __restrict__ qbuf) {
    __shared__ float pvS[64][2];
    __shared__ int piS[64][2];
    int nb = blockIdx.x & 3, mb = blockIdx.x >> 2;
    gemm_body<0>(nb, mb, Ah, Al, WaCh, WaCl, nullptr, qbuf, D_, nullptr, nullptr, pvS, piS);
}

// ---------------------------------------------------------------------------
// attention: single-pass online softmax. One block per batch row, 8 waves
// (512 threads) for latency hiding; wave wv handles rows wv, wv+8, ...
// cv written in canonical fragment layout.
// ---------------------------------------------------------------------------
__global__ __launch_bounds__(512) void k_attn(const float* __restrict__ ctx,
                                              const int* __restrict__ counts,
                                              const float* __restrict__ q,
                                              unsigned short* __restrict__ cv_hi,
                                              unsigned short* __restrict__ cv_lo) {
    __shared__ float accw[8][512];
    __shared__ float mw_s[8], sw_s[8];
    int b = blockIdx.x;
    int t = threadIdx.x;
    int lane = t & 63;
    int wv = t >> 6;
    int cnt = counts[b];
    const float* cb = ctx + (size_t)b * C_ * D_;

    float4 q0 = *(const float4*)&q[(size_t)b * D_ + lane * 4];
    float4 q1 = *(const float4*)&q[(size_t)b * D_ + lane * 4 + 256];

    float m_w = -INFINITY, s_w = 0.f;
    float4 a0 = make_float4(0.f, 0.f, 0.f, 0.f);
    float4 a1 = make_float4(0.f, 0.f, 0.f, 0.f);

#define ATT_DOT(x0, x1) (x0.x * q0.x + x0.y * q0.y + x0.z * q0.z + x0.w * q0.w + \
                         x1.x * q1.x + x1.y * q1.y + x1.z * q1.z + x1.w * q1.w)
#define ATT_UPD(s, x0, x1)                                                     \
    {                                                                          \
        float e;                                                               \
        if (s > m_w) {                                                         \
            float sc = expf(m_w - s);                                          \
            s_w = s_w * sc + 1.f;                                              \
            a0.x *= sc; a0.y *= sc; a0.z *= sc; a0.w *= sc;                    \
            a1.x *= sc; a1.y *= sc; a1.z *= sc; a1.w *= sc;                    \
            m_w = s; e = 1.f;                                                  \
        } else {                                                               \
            e = expf(s - m_w);                                                 \
            s_w += e;                                                          \
        }                                                                      \
        a0.x += e * x0.x; a0.y += e * x0.y; a0.z += e * x0.z; a0.w += e * x0.w;\
        a1.x += e * x1.x; a1.y += e * x1.y; a1.z += e * x1.z; a1.w += e * x1.w;\
    }

    int cc = wv;
    for (; cc + 8 < cnt; cc += 16) {
        const float* rA = cb + (size_t)cc * D_;
        const float* rB = cb + (size_t)(cc + 8) * D_;
        float4 xa0 = *(const float4*)&rA[lane * 4];
        float4 xa1 = *(const float4*)&rA[lane * 4 + 256];
        float4 xb0 = *(const float4*)&rB[lane * 4];
        float4 xb1 = *(const float4*)&rB[lane * 4 + 256];
        float sa = ATT_DOT(xa0, xa1);
        float sb = ATT_DOT(xb0, xb1);
#pragma unroll
        for (int off = 32; off; off >>= 1) {
            sa += __shfl_xor(sa, off);
            sb += __shfl_xor(sb, off);
        }
        ATT_UPD(sa, xa0, xa1);
        ATT_UPD(sb, xb0, xb1);
    }
    if (cc < cnt) {
        const float* rA = cb + (size_t)cc * D_;
        float4 xa0 = *(const float4*)&rA[lane * 4];
        float4 xa1 = *(const float4*)&rA[lane * 4 + 256];
        float sa = ATT_DOT(xa0, xa1);
#pragma unroll
        for (int off = 32; off; off >>= 1) sa += __shfl_xor(sa, off);
        ATT_UPD(sa, xa0, xa1);
    }

    accw[wv][lane * 4 + 0] = a0.x; accw[wv][lane * 4 + 1] = a0.y;
    accw[wv][lane * 4 + 2] = a0.z; accw[wv][lane * 4 + 3] = a0.w;
    accw[wv][256 + lane * 4 + 0] = a1.x; accw[wv][256 + lane * 4 + 1] = a1.y;
    accw[wv][256 + lane * 4 + 2] = a1.z; accw[wv][256 + lane * 4 + 3] = a1.w;
    if (lane == 0) { mw_s[wv] = m_w; sw_s[wv] = s_w; }
    __syncthreads();

    // combine 8 wave partials; thread t owns dim t
    float m_g = mw_s[0];
#pragma unroll
    for (int ww = 1; ww < 8; ++ww) m_g = fmaxf(m_g, mw_s[ww]);
    float den = 0.f, num = 0.f;
#pragma unroll
    for (int ww = 0; ww < 8; ++ww) {
        float e = expf(mw_s[ww] - m_g);
        den += sw_s[ww] * e;
        num += accw[ww][t] * e;
    }
    float v0 = num / den;
    unsigned short p0 = bf16_rn(v0);
    size_t o0 = canon_off(b, t, 16);
    cv_hi[o0] = p0;
    cv_lo[o0] = bf16_rn(v0 - bf16f(p0));
}

// ---------------------------------------------------------------------------
// gates GEMM (split-bf16 MFMA, K=1280) + fused LSTM epilogue. ALL-DIRECT.
// 64m x 32n tiles, 512 blocks (2/CU), XCD swizzle.
// RED=1: prologue reduces argmax partials for this block's 64 rows -> toks.
// ---------------------------------------------------------------------------
template<int RED>
__global__ __launch_bounds__(256, 2) void k_gatesm(const int* __restrict__ tok,
                                                   const float* __restrict__ pvO,
                                                   const int* __restrict__ piO,
                                                   const unsigned short* __restrict__ Eh,
                                                   const unsigned short* __restrict__ El,
                                                   const unsigned short* __restrict__ Ch,
                                                   const unsigned short* __restrict__ Cl,
                                                   const unsigned short* __restrict__ Hh,
                                                   const unsigned short* __restrict__ Hl,
                                                   const unsigned short* __restrict__ WgCh,
                                                   const unsigned short* __restrict__ WgCl,
                                                   const float* __restrict__ b_ih,
                                                   const float* __restrict__ b_hh,
                                                   float* __restrict__ cbuf,
                                                   unsigned short* __restrict__ Hoh,
                                                   unsigned short* __restrict__ Hol) {
    __shared__ int toks[64];
    int bid = blockIdx.x;
    int t = threadIdx.x;
    int l = t & 63;
    int w = t >> 6;
    int wm = w >> 1, wn = w & 1;
    int xcd = bid & 7, lid = bid >> 3;
    int nb = xcd * 8 + (lid & 7);
    int mb = lid >> 3;
    int m0 = mb * 64;
    int n0 = nb * 32;
    int koct = 8 * (l >> 4);

    if (RED) {
        int ri = t >> 2, qq = t & 3;
        const float* pv = pvO + (size_t)(m0 + ri) * 64 + qq * 16;
        const int* pi = piO + (size_t)(m0 + ri) * 64 + qq * 16;
        float bv = -INFINITY;
        int bix = 0x7fffffff;
#pragma unroll
        for (int j = 0; j < 16; ++j) {
            float v = pv[j];
            int ii = pi[j];
            if (v > bv || (v == bv && ii < bix)) { bv = v; bix = ii; }
        }
#pragma unroll
        for (int off = 1; off < 4; off <<= 1) {
            float ov = __shfl_xor(bv, off);
            int oi = __shfl_xor(bix, off);
            if (ov > bv || (ov == bv && oi < bix)) { bv = ov; bix = oi; }
        }
        if (qq == 0) toks[ri] = bix;
        __syncthreads();
    }

    int lr0 = wm * 32 + (l & 15);
    int tk0 = RED ? toks[lr0] : tok[m0 + lr0];
    int tk1 = RED ? toks[lr0 + 16] : tok[m0 + lr0 + 16];
    int tg0 = mb * 4 + wm * 2;
    const unsigned short* Ch0 = Ch + ((size_t)tg0 * 16) * 512 + l * 8;
    const unsigned short* Cl0 = Cl + ((size_t)tg0 * 16) * 512 + l * 8;
    const unsigned short* Hh0 = Hh + ((size_t)tg0 * 16) * 512 + l * 8;
    const unsigned short* Hl0 = Hl + ((size_t)tg0 * 16) * 512 + l * 8;
    int ntg = nb * 2 + wn;
    const unsigned short* Bh0 = WgCh + ((size_t)ntg * 40) * 512 + l * 8;
    const unsigned short* Bl0 = WgCl + ((size_t)ntg * 40) * 512 + l * 8;

    f32x4 z = {0.f, 0.f, 0.f, 0.f};
    f32x4 acc[2];
    acc[0] = z; acc[1] = z;

#define GATES_MFMA(a0h, a0l, a1h, a1l, bh, bl)                                   \
    acc[0] = __builtin_amdgcn_mfma_f32_16x16x32_bf16(a0h, bh, acc[0], 0, 0, 0);  \
    acc[0] = __builtin_amdgcn_mfma_f32_16x16x32_bf16(a0h, bl, acc[0], 0, 0, 0);  \
    acc[0] = __builtin_amdgcn_mfma_f32_16x16x32_bf16(a0l, bh, acc[0], 0, 0, 0);  \
    acc[1] = __builtin_amdgcn_mfma_f32_16x16x32_bf16(a1h, bh, acc[1], 0, 0, 0);  \
    acc[1] = __builtin_amdgcn_mfma_f32_16x16x32_bf16(a1h, bl, acc[1], 0, 0, 0);  \
    acc[1] = __builtin_amdgcn_mfma_f32_16x16x32_bf16(a1l, bh, acc[1], 0, 0, 0);

    for (int kt = 0; kt < 8; ++kt) {
        int ko = kt * 32 + koct;
        short8 a0h = *(const short8*)&Eh[(size_t)tk0 * 256 + ko];
        short8 a0l = *(const short8*)&El[(size_t)tk0 * 256 + ko];
        short8 a1h = *(const short8*)&Eh[(size_t)tk1 * 256 + ko];
        short8 a1l = *(const short8*)&El[(size_t)tk1 * 256 + ko];
        short8 bh = *(const short8*)(Bh0 + (size_t)kt * 512);
        short8 bl = *(const short8*)(Bl0 + (size_t)kt * 512);
        GATES_MFMA(a0h, a0l, a1h, a1l, bh, bl)
    }
    for (int kt = 8; kt < 24; ++kt) {
        size_t oc = ((size_t)(kt - 8)) * 512;
        short8 a0h = *(const short8*)(Ch0 + oc);
        short8 a0l = *(const short8*)(Cl0 + oc);
        short8 a1h = *(const short8*)(Ch0 + 16 * 512 + oc);
        short8 a1l = *(const short8*)(Cl0 + 16 * 512 + oc);
        short8 bh = *(const short8*)(Bh0 + (size_t)kt * 512);
        short8 bl = *(const short8*)(Bl0 + (size_t)kt * 512);
        GATES_MFMA(a0h, a0l, a1h, a1l, bh, bl)
    }
    for (int kt = 24; kt < 40; ++kt) {
        size_t oh = ((size_t)(kt - 24)) * 512;
        short8 a0h = *(const short8*)(Hh0 + oh);
        short8 a0l = *(const short8*)(Hl0 + oh);
        short8 a1h = *(const short8*)(Hh0 + 16 * 512 + oh);
        short8 a1l = *(const short8*)(Hl0 + 16 * 512 + oh);
        short8 bh = *(const short8*)(Bh0 + (size_t)kt * 512);
        short8 bl = *(const short8*)(Bl0 + (size_t)kt * 512);
        GATES_MFMA(a0h, a0l, a1h, a1l, bh, bl)
    }

    int r0 = (l >> 4) * 4;
    int cl = l & 15;
    bool act = (cl & 3) == 0;
    int gc = n0 + wn * 16 + cl;
    int d = gc >> 2;
    float bi_ = b_ih[d] + b_hh[d];
    float bf_ = b_ih[512 + d] + b_hh[512 + d];
    float bg_ = b_ih[1024 + d] + b_hh[1024 + d];
    float bo_ = b_ih[1536 + d] + b_hh[1536 + d];
#pragma unroll
    for (int i = 0; i < 2; ++i) {
#pragma unroll
        for (int r = 0; r < 4; ++r) {
            float x = acc[i][r];
            float x1 = __shfl_xor(x, 1);
            float x2 = __shfl_xor(x, 2);
            float x3 = __shfl_xor(x, 3);
            if (act) {
                int row = m0 + wm * 32 + i * 16 + r0 + r;
                float ig = sigm(x + bi_);
                float fg = sigm(x1 + bf_);
                float gg = tanhf(x2 + bg_);
                float og = sigm(x3 + bo_);
                float cn = fg * cbuf[(size_t)row * D_ + d] + ig * gg;
                cbuf[(size_t)row * D_ + d] = cn;
                float hv = og * tanhf(cn);
                unsigned short hh = bf16_rn(hv);
                size_t oo = canon_off(row, d, 16);
                Hoh[oo] = hh;
                Hol[oo] = bf16_rn(hv - bf16f(hh));
            }
        }
    }
}

// ---------------------------------------------------------------------------
extern "C" void kernel_launch(void* const* d_in, const int* in_sizes, int n_in,
                              void* d_out, int out_size, void* d_ws, size_t ws_size,
                              hipStream_t stream) {
    const float* ctx    = (const float*)d_in[0];
    const int*   counts = (const int*)d_in[1];
    const float* emb    = (const float*)d_in[3];
    const float* W_attn = (const float*)d_in[4];
    const float* W_ih   = (const float*)d_in[5];
    const float* b_ih   = (const float*)d_in[6];
    const float* W_hh   = (const float*)d_in[7];
    const float* b_hh   = (const float*)d_in[8];
    const float* W_proj = (const float*)d_in[9];
    const float* b_proj = (const float*)d_in[10];
    float* out = (float*)d_out;

    float* qbuf = (float*)d_ws;                 // [512][512]
    float* cbuf = qbuf + B_ * D_;               // [512][512]
    unsigned short* p = (unsigned short*)(cbuf + B_ * D_);
    unsigned short* Wa_hi = p; p += D_ * D_;
    unsigned short* Wa_lo = p; p += D_ * D_;
    unsigned short* Wp_hi = p; p += (size_t)V_ * D_;
    unsigned short* Wp_lo = p; p += (size_t)V_ * D_;
    unsigned short* Eb_hi = p; p += (size_t)V_ * E_;
    unsigned short* Eb_lo = p; p += (size_t)V_ * E_;
    unsigned short* Wg_hi = p; p += (size_t)G_ * 1280;
    unsigned short* Wg_lo = p; p += (size_t)G_ * 1280;
    unsigned short* hA_hi = p; p += B_ * D_;
    unsigned short* hA_lo = p; p += B_ * D_;
    unsigned short* hB_hi = p; p += B_ * D_;
    unsigned short* hB_lo = p; p += B_ * D_;
    unsigned short* cv_hi = p; p += B_ * D_;
    unsigned short* cv_lo = p; p += B_ * D_;
    int* tok = (int*)p;                         // [512]
    float* pvO = (float*)(tok + B_);            // [512][64]
    int* piO = (int*)(pvO + B_ * 64);           // [512][64]

    k_setup<<<10112, 256, 0, stream>>>(W_proj, emb, W_ih, W_hh, W_attn, ctx, counts,
                                       Wp_hi, Wp_lo, Eb_hi, Eb_lo, Wg_hi, Wg_lo,
                                       Wa_hi, Wa_lo, hA_hi, hA_lo, cbuf, tok, out);

    k_qproj<<<32, 256, 0, stream>>>(hA_hi, hA_lo, Wa_hi, Wa_lo, qbuf);

    unsigned short *hin_hi = hA_hi, *hin_lo = hA_lo;
    unsigned short *hout_hi = hB_hi, *hout_lo = hB_lo;
    for (int t = 1; t < L_; ++t) {
        k_attn<<<B_, 512, 0, stream>>>(ctx, counts, qbuf, cv_hi, cv_lo);
        if (t == 1) {
            k_gatesm<0><<<512, 256, 0, stream>>>(
                tok, pvO, piO, Eb_hi, Eb_lo, cv_hi, cv_lo, hin_hi, hin_lo,
                Wg_hi, Wg_lo, b_ih, b_hh, cbuf, hout_hi, hout_lo);
        } else {
            k_gatesm<1><<<512, 256, 0, stream>>>(
                tok, pvO, piO, Eb_hi, Eb_lo, cv_hi, cv_lo, hin_hi, hin_lo,
                Wg_hi, Wg_lo, b_ih, b_hh, cbuf, hout_hi, hout_lo);
        }
        float* slab = out + (size_t)t * B_ * V_;
        k_mega<<<544, 256, 0, stream>>>(hout_hi, hout_lo, Wp_hi, Wp_lo, b_proj,
                                        slab, pvO, piO, Wa_hi, Wa_lo, qbuf);
        unsigned short* tmp;
        tmp = hin_hi; hin_hi = hout_hi; hout_hi = tmp;
        tmp = hin_lo; hin_lo = hout_lo; hout_lo = tmp;
    }
}

// Round 14
// 1337.208 us; speedup vs baseline: 5.5355x; 1.0288x over previous
//
#include <hip/hip_runtime.h>
#include <math.h>

#define B_ 512
#define C_ 200
#define D_ 512
#define E_ 256
#define V_ 8192
#define G_ 2048
#define L_ 16

typedef __attribute__((ext_vector_type(8))) short short8;
typedef __attribute__((ext_vector_type(4))) float f32x4;

__device__ __forceinline__ float sigm(float x) { return 1.0f / (1.0f + expf(-x)); }

__device__ __forceinline__ unsigned short bf16_rn(float x) {
    unsigned int u = __float_as_uint(x);
    return (unsigned short)((u + 0x7FFFu + ((u >> 16) & 1u)) >> 16);
}
__device__ __forceinline__ float bf16f(unsigned short h) {
    return __uint_as_float(((unsigned int)h) << 16);
}

// Canonical fragment layout (16x16x32 MFMA operand):
//   canon[((tile*NKT + kt)*64 + lane)*8 + e] = M[tile*16 + (lane&15)][kt*32 + (lane>>4)*8 + e]
__device__ __forceinline__ size_t canon_off(int row, int k, int NKT) {
    return ((((size_t)(row >> 4) * NKT + (k >> 5)) * 64) +
            ((row & 15) + (((k >> 3) & 3) << 4))) * 8 + (k & 7);
}

// ---------------------------------------------------------------------------
// merged setup (block ranges):
//   [0,2048) W_proj->canon  [2048,4096) emb  [4096,5376) Wg->canon
//   [5376,5504) W_attn->canon  [5504,6016) init  [6016,10112) zero out slab 0
// ---------------------------------------------------------------------------
__global__ __launch_bounds__(256) void k_setup(const float* __restrict__ W_proj,
                                               const float* __restrict__ emb,
                                               const float* __restrict__ W_ih,
                                               const float* __restrict__ W_hh,
                                               const float* __restrict__ W_attn,
                                               const float* __restrict__ ctx,
                                               const int* __restrict__ counts,
                                               unsigned short* __restrict__ WpC_hi,
                                               unsigned short* __restrict__ WpC_lo,
                                               unsigned short* __restrict__ Eb_hi,
                                               unsigned short* __restrict__ Eb_lo,
                                               unsigned short* __restrict__ WgC_hi,
                                               unsigned short* __restrict__ WgC_lo,
                                               unsigned short* __restrict__ WaC_hi,
                                               unsigned short* __restrict__ WaC_lo,
                                               unsigned short* __restrict__ h_hi,
                                               unsigned short* __restrict__ h_lo,
                                               float* __restrict__ c,
                                               int* __restrict__ tok,
                                               float* __restrict__ out0) {
    int bb = blockIdx.x;
    int t = threadIdx.x;
    if (bb < 2048) {
        int i = bb * 256 + t;
        int n = i >> 6;
        int koff = (i & 63) * 8;
        float4 v0 = *(const float4*)&W_proj[(size_t)n * 512 + koff];
        float4 v1 = *(const float4*)&W_proj[(size_t)n * 512 + koff + 4];
        float vv[8] = {v0.x, v0.y, v0.z, v0.w, v1.x, v1.y, v1.z, v1.w};
        short8 h8, l8;
#pragma unroll
        for (int e = 0; e < 8; ++e) {
            unsigned short hh = bf16_rn(vv[e]);
            h8[e] = (short)hh;
            l8[e] = (short)bf16_rn(vv[e] - bf16f(hh));
        }
        size_t off = canon_off(n, koff, 16);
        *(short8*)&WpC_hi[off] = h8;
        *(short8*)&WpC_lo[off] = l8;
    } else if (bb < 4096) {
        int i = (bb - 2048) * 256 + t;
        float4 v = ((const float4*)emb)[i];
        ushort4 h, l;
        h.x = bf16_rn(v.x); l.x = bf16_rn(v.x - bf16f(h.x));
        h.y = bf16_rn(v.y); l.y = bf16_rn(v.y - bf16f(h.y));
        h.z = bf16_rn(v.z); l.z = bf16_rn(v.z - bf16f(h.z));
        h.w = bf16_rn(v.w); l.w = bf16_rn(v.w - bf16f(h.w));
        ((ushort4*)Eb_hi)[i] = h;
        ((ushort4*)Eb_lo)[i] = l;
    } else if (bb < 5376) {
        int i = (bb - 4096) * 256 + t;
        if (i < 327680) {
            int r = i / 160;
            int koff = (i - r * 160) * 8;
            int go = ((r & 3) << 9) + (r >> 2);
            float4 v0, v1;
            if (koff < 768) {
                v0 = *(const float4*)&W_ih[(size_t)go * 768 + koff];
                v1 = *(const float4*)&W_ih[(size_t)go * 768 + koff + 4];
            } else {
                v0 = *(const float4*)&W_hh[(size_t)go * 512 + (koff - 768)];
                v1 = *(const float4*)&W_hh[(size_t)go * 512 + (koff - 768) + 4];
            }
            float vv[8] = {v0.x, v0.y, v0.z, v0.w, v1.x, v1.y, v1.z, v1.w};
            short8 h8, l8;
#pragma unroll
            for (int e = 0; e < 8; ++e) {
                unsigned short hh = bf16_rn(vv[e]);
                h8[e] = (short)hh;
                l8[e] = (short)bf16_rn(vv[e] - bf16f(hh));
            }
            size_t off = canon_off(r, koff, 40);
            *(short8*)&WgC_hi[off] = h8;
            *(short8*)&WgC_lo[off] = l8;
        }
    } else if (bb < 5504) {
        int i = (bb - 5376) * 256 + t;
        int n = i >> 6;
        int koff = (i & 63) * 8;
        float4 v0 = *(const float4*)&W_attn[(size_t)n * 512 + koff];
        float4 v1 = *(const float4*)&W_attn[(size_t)n * 512 + koff + 4];
        float vv[8] = {v0.x, v0.y, v0.z, v0.w, v1.x, v1.y, v1.z, v1.w};
        short8 h8, l8;
#pragma unroll
        for (int e = 0; e < 8; ++e) {
            unsigned short hh = bf16_rn(vv[e]);
            h8[e] = (short)hh;
            l8[e] = (short)bf16_rn(vv[e] - bf16f(hh));
        }
        size_t off = canon_off(n, koff, 16);
        *(short8*)&WaC_hi[off] = h8;
        *(short8*)&WaC_lo[off] = l8;
    } else if (bb < 6016) {
        int b = bb - 5504;
        int cnt = counts[b];
        const float* base = ctx + (size_t)b * C_ * D_;
        float s0 = 0.f, s1 = 0.f;
        for (int cc = 0; cc < cnt; ++cc) {
            s0 += base[(size_t)cc * D_ + t];
            s1 += base[(size_t)cc * D_ + t + 256];
        }
        float inv = 1.0f / (float)cnt;
        float v0 = s0 * inv, v1 = s1 * inv;
        c[b * D_ + t] = v0;       c[b * D_ + t + 256] = v1;
        unsigned short p0 = bf16_rn(v0), p1 = bf16_rn(v1);
        size_t o0 = canon_off(b, t, 16);
        size_t o1 = canon_off(b, t + 256, 16);
        h_hi[o0] = p0;            h_hi[o1] = p1;
        h_lo[o0] = bf16_rn(v0 - bf16f(p0));
        h_lo[o1] = bf16_rn(v1 - bf16f(p1));
        if (t == 0) tok[b] = 1;
    } else {
        int i = (bb - 6016) * 256 + t;
        f32x4 zz = {0.f, 0.f, 0.f, 0.f};
        __builtin_nontemporal_store(zz, &((f32x4*)out0)[i]);
    }
}

// ---------------------------------------------------------------------------
// All-direct split-bf16 GEMM body: C[64m x 128n], K=512 (16 ktiles), 4 waves.
// PART=1: logits -> nontemporal C stores (don't pollute L2) + argmax partials.
// ---------------------------------------------------------------------------
template<int PART>
__device__ __forceinline__ void gemm_body(int nb, int mb,
                                          const unsigned short* __restrict__ Ah,
                                          const unsigned short* __restrict__ Al,
                                          const unsigned short* __restrict__ BhC,
                                          const unsigned short* __restrict__ BlC,
                                          const float* __restrict__ bias,
                                          float* __restrict__ C, int ldc,
                                          float* __restrict__ pvO,
                                          int* __restrict__ piO,
                                          float (*pvS)[2], int (*piS)[2]) {
    int t = threadIdx.x;
    int l = t & 63;
    int w = t >> 6;
    int wm = w >> 1, wn = w & 1;
    int m0 = mb * 64;
    int n0 = nb * 128;
    int tA0 = mb * 4 + wm * 2;
    const unsigned short* Ah0 = Ah + ((size_t)tA0 * 16) * 512 + l * 8;
    const unsigned short* Al0 = Al + ((size_t)tA0 * 16) * 512 + l * 8;
    int ntbase = nb * 8 + wn * 4;
    const unsigned short* Bh0 = BhC + ((size_t)ntbase * 16) * 512 + l * 8;
    const unsigned short* Bl0 = BlC + ((size_t)ntbase * 16) * 512 + l * 8;

    f32x4 z = {0.f, 0.f, 0.f, 0.f};
    f32x4 acc[2][4];
#pragma unroll
    for (int i = 0; i < 2; ++i)
#pragma unroll
        for (int j = 0; j < 4; ++j) acc[i][j] = z;

    for (int kt = 0; kt < 16; ++kt) {
        short8 ah[2], al[2], bh[4], bl[4];
#pragma unroll
        for (int i = 0; i < 2; ++i) {
            size_t o = ((size_t)i * 16 + kt) * 512;
            ah[i] = *(const short8*)(Ah0 + o);
            al[i] = *(const short8*)(Al0 + o);
        }
#pragma unroll
        for (int j = 0; j < 4; ++j) {
            size_t o = ((size_t)j * 16 + kt) * 512;
            bh[j] = *(const short8*)(Bh0 + o);
            bl[j] = *(const short8*)(Bl0 + o);
        }
#pragma unroll
        for (int i = 0; i < 2; ++i)
#pragma unroll
            for (int j = 0; j < 4; ++j) {
                acc[i][j] = __builtin_amdgcn_mfma_f32_16x16x32_bf16(ah[i], bh[j], acc[i][j], 0, 0, 0);
                acc[i][j] = __builtin_amdgcn_mfma_f32_16x16x32_bf16(ah[i], bl[j], acc[i][j], 0, 0, 0);
                acc[i][j] = __builtin_amdgcn_mfma_f32_16x16x32_bf16(al[i], bh[j], acc[i][j], 0, 0, 0);
            }
    }
    int r0 = (l >> 4) * 4;
    int cl = l & 15;
    if (PART) {
        float bj_[4];
#pragma unroll
        for (int j = 0; j < 4; ++j) bj_[j] = bias[n0 + wn * 64 + j * 16 + cl];
#pragma unroll
        for (int i = 0; i < 2; ++i) {
#pragma unroll
            for (int r = 0; r < 4; ++r) {
                int row = m0 + wm * 32 + i * 16 + r0 + r;
                float bv = -INFINITY;
                int bidx = 0x7fffffff;
#pragma unroll
                for (int j = 0; j < 4; ++j) {
                    int col = n0 + wn * 64 + j * 16 + cl;
                    float v = acc[i][j][r] + bj_[j];
                    __builtin_nontemporal_store(v, &C[(size_t)row * ldc + col]);
                    if (v > bv) { bv = v; bidx = col; }
                }
#pragma unroll
                for (int off = 1; off < 16; off <<= 1) {
                    float ov = __shfl_xor(bv, off);
                    int oi = __shfl_xor(bidx, off);
                    if (ov > bv || (ov == bv && oi < bidx)) { bv = ov; bidx = oi; }
                }
                if (cl == 0) {
                    pvS[wm * 32 + i * 16 + r0 + r][wn] = bv;
                    piS[wm * 32 + i * 16 + r0 + r][wn] = bidx;
                }
            }
        }
        __syncthreads();
        if (t < 64) {
            float v0 = pvS[t][0], v1 = pvS[t][1];
            int i0 = piS[t][0], i1 = piS[t][1];
            bool take1 = (v1 > v0);
            pvO[(size_t)(m0 + t) * 64 + nb] = take1 ? v1 : v0;
            piO[(size_t)(m0 + t) * 64 + nb] = take1 ? i1 : i0;
        }
    } else {
#pragma unroll
        for (int i = 0; i < 2; ++i)
#pragma unroll
            for (int j = 0; j < 4; ++j) {
                int col = n0 + wn * 64 + j * 16 + cl;
                int rowb = m0 + wm * 32 + i * 16 + r0;
#pragma unroll
                for (int r = 0; r < 4; ++r)
                    C[(size_t)(rowb + r) * ldc + col] = acc[i][j][r];
            }
    }
}

// ---------------------------------------------------------------------------
// mega: blocks [0,512) = logits (XCD swizzle, argmax partials);
//       blocks [512,544) = qproj -> qbuf (next step's q).
// (256,3): 3 blocks/CU -> all 544 blocks co-resident in one round.
// ---------------------------------------------------------------------------
__global__ __launch_bounds__(256, 3) void k_mega(const unsigned short* __restrict__ Ah,
                                                 const unsigned short* __restrict__ Al,
                                                 const unsigned short* __restrict__ WpCh,
                                                 const unsigned short* __restrict__ WpCl,
                                                 const float* __restrict__ bias,
                                                 float* __restrict__ Cl_,
                                                 float* __restrict__ pvO,
                                                 int* __restrict__ piO,
                                                 const unsigned short* __restrict__ WaCh,
                                                 const unsigned short* __restrict__ WaCl,
                                                 float* __restrict__ qbuf) {
    __shared__ float pvS[64][2];
    __shared__ int piS[64][2];
    int bb = blockIdx.x;
    if (bb < 512) {
        int xcd = bb & 7, lid = bb >> 3;
        int nb = xcd * 8 + (lid & 7);
        int mb = lid >> 3;
        gemm_body<1>(nb, mb, Ah, Al, WpCh, WpCl, bias, Cl_, V_, pvO, piO, pvS, piS);
    } else {
        int idx = bb - 512;
        int nb = idx & 3, mb = idx >> 2;
        gemm_body<0>(nb, mb, Ah, Al, WaCh, WaCl, nullptr, qbuf, D_, nullptr, nullptr, pvS, piS);
    }
}

// standalone qproj for the first step (h0)
__global__ __launch_bounds__(256, 3) void k_qproj(const unsigned short* __restrict__ Ah,
                                                  const unsigned short* __restrict__ Al,
                                                  const unsigned short* __restrict__ WaCh,
                                                  const unsigned short* __restrict__ WaCl,
                                                  float* __restrict__ qbuf) {
    __shared__ float pvS[64][2];
    __shared__ int piS[64][2];
    int nb = blockIdx.x & 3, mb = blockIdx.x >> 2;
    gemm_body<0>(nb, mb, Ah, Al, WaCh, WaCl, nullptr, qbuf, D_, nullptr, nullptr, pvS, piS);
}

// ---------------------------------------------------------------------------
// attention: single-pass online softmax. One block per batch row, 8 waves.
// cv written in canonical fragment layout.
// ---------------------------------------------------------------------------
__global__ __launch_bounds__(512) void k_attn(const float* __restrict__ ctx,
                                              const int* __restrict__ counts,
                                              const float* __restrict__ q,
                                              unsigned short* __restrict__ cv_hi,
                                              unsigned short* __restrict__ cv_lo) {
    __shared__ float accw[8][512];
    __shared__ float mw_s[8], sw_s[8];
    int b = blockIdx.x;
    int t = threadIdx.x;
    int lane = t & 63;
    int wv = t >> 6;
    int cnt = counts[b];
    const float* cb = ctx + (size_t)b * C_ * D_;

    float4 q0 = *(const float4*)&q[(size_t)b * D_ + lane * 4];
    float4 q1 = *(const float4*)&q[(size_t)b * D_ + lane * 4 + 256];

    float m_w = -INFINITY, s_w = 0.f;
    float4 a0 = make_float4(0.f, 0.f, 0.f, 0.f);
    float4 a1 = make_float4(0.f, 0.f, 0.f, 0.f);

#define ATT_DOT(x0, x1) (x0.x * q0.x + x0.y * q0.y + x0.z * q0.z + x0.w * q0.w + \
                         x1.x * q1.x + x1.y * q1.y + x1.z * q1.z + x1.w * q1.w)
#define ATT_UPD(s, x0, x1)                                                     \
    {                                                                          \
        float e;                                                               \
        if (s > m_w) {                                                         \
            float sc = expf(m_w - s);                                          \
            s_w = s_w * sc + 1.f;                                              \
            a0.x *= sc; a0.y *= sc; a0.z *= sc; a0.w *= sc;                    \
            a1.x *= sc; a1.y *= sc; a1.z *= sc; a1.w *= sc;                    \
            m_w = s; e = 1.f;                                                  \
        } else {                                                               \
            e = expf(s - m_w);                                                 \
            s_w += e;                                                          \
        }                                                                      \
        a0.x += e * x0.x; a0.y += e * x0.y; a0.z += e * x0.z; a0.w += e * x0.w;\
        a1.x += e * x1.x; a1.y += e * x1.y; a1.z += e * x1.z; a1.w += e * x1.w;\
    }

    int cc = wv;
    for (; cc + 8 < cnt; cc += 16) {
        const float* rA = cb + (size_t)cc * D_;
        const float* rB = cb + (size_t)(cc + 8) * D_;
        float4 xa0 = *(const float4*)&rA[lane * 4];
        float4 xa1 = *(const float4*)&rA[lane * 4 + 256];
        float4 xb0 = *(const float4*)&rB[lane * 4];
        float4 xb1 = *(const float4*)&rB[lane * 4 + 256];
        float sa = ATT_DOT(xa0, xa1);
        float sb = ATT_DOT(xb0, xb1);
#pragma unroll
        for (int off = 32; off; off >>= 1) {
            sa += __shfl_xor(sa, off);
            sb += __shfl_xor(sb, off);
        }
        ATT_UPD(sa, xa0, xa1);
        ATT_UPD(sb, xb0, xb1);
    }
    if (cc < cnt) {
        const float* rA = cb + (size_t)cc * D_;
        float4 xa0 = *(const float4*)&rA[lane * 4];
        float4 xa1 = *(const float4*)&rA[lane * 4 + 256];
        float sa = ATT_DOT(xa0, xa1);
#pragma unroll
        for (int off = 32; off; off >>= 1) sa += __shfl_xor(sa, off);
        ATT_UPD(sa, xa0, xa1);
    }

    accw[wv][lane * 4 + 0] = a0.x; accw[wv][lane * 4 + 1] = a0.y;
    accw[wv][lane * 4 + 2] = a0.z; accw[wv][lane * 4 + 3] = a0.w;
    accw[wv][256 + lane * 4 + 0] = a1.x; accw[wv][256 + lane * 4 + 1] = a1.y;
    accw[wv][256 + lane * 4 + 2] = a1.z; accw[wv][256 + lane * 4 + 3] = a1.w;
    if (lane == 0) { mw_s[wv] = m_w; sw_s[wv] = s_w; }
    __syncthreads();

    float m_g = mw_s[0];
#pragma unroll
    for (int ww = 1; ww < 8; ++ww) m_g = fmaxf(m_g, mw_s[ww]);
    float den = 0.f, num = 0.f;
#pragma unroll
    for (int ww = 0; ww < 8; ++ww) {
        float e = expf(mw_s[ww] - m_g);
        den += sw_s[ww] * e;
        num += accw[ww][t] * e;
    }
    float v0 = num / den;
    unsigned short p0 = bf16_rn(v0);
    size_t o0 = canon_off(b, t, 16);
    cv_hi[o0] = p0;
    cv_lo[o0] = bf16_rn(v0 - bf16f(p0));
}

// ---------------------------------------------------------------------------
// gates GEMM (split-bf16 MFMA, K=1280) + fused LSTM epilogue. ALL-DIRECT.
// 64m x 32n tiles, 512 blocks, XCD swizzle.
// RED=1: prologue reduces argmax partials for this block's 64 rows -> toks.
// ---------------------------------------------------------------------------
template<int RED>
__global__ __launch_bounds__(256, 3) void k_gatesm(const int* __restrict__ tok,
                                                   const float* __restrict__ pvO,
                                                   const int* __restrict__ piO,
                                                   const unsigned short* __restrict__ Eh,
                                                   const unsigned short* __restrict__ El,
                                                   const unsigned short* __restrict__ Ch,
                                                   const unsigned short* __restrict__ Cl,
                                                   const unsigned short* __restrict__ Hh,
                                                   const unsigned short* __restrict__ Hl,
                                                   const unsigned short* __restrict__ WgCh,
                                                   const unsigned short* __restrict__ WgCl,
                                                   const float* __restrict__ b_ih,
                                                   const float* __restrict__ b_hh,
                                                   float* __restrict__ cbuf,
                                                   unsigned short* __restrict__ Hoh,
                                                   unsigned short* __restrict__ Hol) {
    __shared__ int toks[64];
    int bid = blockIdx.x;
    int t = threadIdx.x;
    int l = t & 63;
    int w = t >> 6;
    int wm = w >> 1, wn = w & 1;
    int xcd = bid & 7, lid = bid >> 3;
    int nb = xcd * 8 + (lid & 7);
    int mb = lid >> 3;
    int m0 = mb * 64;
    int n0 = nb * 32;
    int koct = 8 * (l >> 4);

    if (RED) {
        int ri = t >> 2, qq = t & 3;
        const float* pv = pvO + (size_t)(m0 + ri) * 64 + qq * 16;
        const int* pi = piO + (size_t)(m0 + ri) * 64 + qq * 16;
        float bv = -INFINITY;
        int bix = 0x7fffffff;
#pragma unroll
        for (int j = 0; j < 16; ++j) {
            float v = pv[j];
            int ii = pi[j];
            if (v > bv || (v == bv && ii < bix)) { bv = v; bix = ii; }
        }
#pragma unroll
        for (int off = 1; off < 4; off <<= 1) {
            float ov = __shfl_xor(bv, off);
            int oi = __shfl_xor(bix, off);
            if (ov > bv || (ov == bv && oi < bix)) { bv = ov; bix = oi; }
        }
        if (qq == 0) toks[ri] = bix;
        __syncthreads();
    }

    int lr0 = wm * 32 + (l & 15);
    int tk0 = RED ? toks[lr0] : tok[m0 + lr0];
    int tk1 = RED ? toks[lr0 + 16] : tok[m0 + lr0 + 16];
    int tg0 = mb * 4 + wm * 2;
    const unsigned short* Ch0 = Ch + ((size_t)tg0 * 16) * 512 + l * 8;
    const unsigned short* Cl0 = Cl + ((size_t)tg0 * 16) * 512 + l * 8;
    const unsigned short* Hh0 = Hh + ((size_t)tg0 * 16) * 512 + l * 8;
    const unsigned short* Hl0 = Hl + ((size_t)tg0 * 16) * 512 + l * 8;
    int ntg = nb * 2 + wn;
    const unsigned short* Bh0 = WgCh + ((size_t)ntg * 40) * 512 + l * 8;
    const unsigned short* Bl0 = WgCl + ((size_t)ntg * 40) * 512 + l * 8;

    f32x4 z = {0.f, 0.f, 0.f, 0.f};
    f32x4 acc[2];
    acc[0] = z; acc[1] = z;

#define GATES_MFMA(a0h, a0l, a1h, a1l, bh, bl)                                   \
    acc[0] = __builtin_amdgcn_mfma_f32_16x16x32_bf16(a0h, bh, acc[0], 0, 0, 0);  \
    acc[0] = __builtin_amdgcn_mfma_f32_16x16x32_bf16(a0h, bl, acc[0], 0, 0, 0);  \
    acc[0] = __builtin_amdgcn_mfma_f32_16x16x32_bf16(a0l, bh, acc[0], 0, 0, 0);  \
    acc[1] = __builtin_amdgcn_mfma_f32_16x16x32_bf16(a1h, bh, acc[1], 0, 0, 0);  \
    acc[1] = __builtin_amdgcn_mfma_f32_16x16x32_bf16(a1h, bl, acc[1], 0, 0, 0);  \
    acc[1] = __builtin_amdgcn_mfma_f32_16x16x32_bf16(a1l, bh, acc[1], 0, 0, 0);

    for (int kt = 0; kt < 8; ++kt) {
        int ko = kt * 32 + koct;
        short8 a0h = *(const short8*)&Eh[(size_t)tk0 * 256 + ko];
        short8 a0l = *(const short8*)&El[(size_t)tk0 * 256 + ko];
        short8 a1h = *(const short8*)&Eh[(size_t)tk1 * 256 + ko];
        short8 a1l = *(const short8*)&El[(size_t)tk1 * 256 + ko];
        short8 bh = *(const short8*)(Bh0 + (size_t)kt * 512);
        short8 bl = *(const short8*)(Bl0 + (size_t)kt * 512);
        GATES_MFMA(a0h, a0l, a1h, a1l, bh, bl)
    }
    for (int kt = 8; kt < 24; ++kt) {
        size_t oc = ((size_t)(kt - 8)) * 512;
        short8 a0h = *(const short8*)(Ch0 + oc);
        short8 a0l = *(const short8*)(Cl0 + oc);
        short8 a1h = *(const short8*)(Ch0 + 16 * 512 + oc);
        short8 a1l = *(const short8*)(Cl0 + 16 * 512 + oc);
        short8 bh = *(const short8*)(Bh0 + (size_t)kt * 512);
        short8 bl = *(const short8*)(Bl0 + (size_t)kt * 512);
        GATES_MFMA(a0h, a0l, a1h, a1l, bh, bl)
    }
    for (int kt = 24; kt < 40; ++kt) {
        size_t oh = ((size_t)(kt - 24)) * 512;
        short8 a0h = *(const short8*)(Hh0 + oh);
        short8 a0l = *(const short8*)(Hl0 + oh);
        short8 a1h = *(const short8*)(Hh0 + 16 * 512 + oh);
        short8 a1l = *(const short8*)(Hl0 + 16 * 512 + oh);
        short8 bh = *(const short8*)(Bh0 + (size_t)kt * 512);
        short8 bl = *(const short8*)(Bl0 + (size_t)kt * 512);
        GATES_MFMA(a0h, a0l, a1h, a1l, bh, bl)
    }

    int r0 = (l >> 4) * 4;
    int cl = l & 15;
    bool act = (cl & 3) == 0;
    int gc = n0 + wn * 16 + cl;
    int d = gc >> 2;
    float bi_ = b_ih[d] + b_hh[d];
    float bf_ = b_ih[512 + d] + b_hh[512 + d];
    float bg_ = b_ih[1024 + d] + b_hh[1024 + d];
    float bo_ = b_ih[1536 + d] + b_hh[1536 + d];
#pragma unroll
    for (int i = 0; i < 2; ++i) {
#pragma unroll
        for (int r = 0; r < 4; ++r) {
            float x = acc[i][r];
            float x1 = __shfl_xor(x, 1);
            float x2 = __shfl_xor(x, 2);
            float x3 = __shfl_xor(x, 3);
            if (act) {
                int row = m0 + wm * 32 + i * 16 + r0 + r;
                float ig = sigm(x + bi_);
                float fg = sigm(x1 + bf_);
                float gg = tanhf(x2 + bg_);
                float og = sigm(x3 + bo_);
                float cn = fg * cbuf[(size_t)row * D_ + d] + ig * gg;
                cbuf[(size_t)row * D_ + d] = cn;
                float hv = og * tanhf(cn);
                unsigned short hh = bf16_rn(hv);
                size_t oo = canon_off(row, d, 16);
                Hoh[oo] = hh;
                Hol[oo] = bf16_rn(hv - bf16f(hh));
            }
        }
    }
}

// ---------------------------------------------------------------------------
extern "C" void kernel_launch(void* const* d_in, const int* in_sizes, int n_in,
                              void* d_out, int out_size, void* d_ws, size_t ws_size,
                              hipStream_t stream) {
    const float* ctx    = (const float*)d_in[0];
    const int*   counts = (const int*)d_in[1];
    const float* emb    = (const float*)d_in[3];
    const float* W_attn = (const float*)d_in[4];
    const float* W_ih   = (const float*)d_in[5];
    const float* b_ih   = (const float*)d_in[6];
    const float* W_hh   = (const float*)d_in[7];
    const float* b_hh   = (const float*)d_in[8];
    const float* W_proj = (const float*)d_in[9];
    const float* b_proj = (const float*)d_in[10];
    float* out = (float*)d_out;

    float* qbuf = (float*)d_ws;                 // [512][512]
    float* cbuf = qbuf + B_ * D_;               // [512][512]
    unsigned short* p = (unsigned short*)(cbuf + B_ * D_);
    unsigned short* Wa_hi = p; p += D_ * D_;
    unsigned short* Wa_lo = p; p += D_ * D_;
    unsigned short* Wp_hi = p; p += (size_t)V_ * D_;
    unsigned short* Wp_lo = p; p += (size_t)V_ * D_;
    unsigned short* Eb_hi = p; p += (size_t)V_ * E_;
    unsigned short* Eb_lo = p; p += (size_t)V_ * E_;
    unsigned short* Wg_hi = p; p += (size_t)G_ * 1280;
    unsigned short* Wg_lo = p; p += (size_t)G_ * 1280;
    unsigned short* hA_hi = p; p += B_ * D_;
    unsigned short* hA_lo = p; p += B_ * D_;
    unsigned short* hB_hi = p; p += B_ * D_;
    unsigned short* hB_lo = p; p += B_ * D_;
    unsigned short* cv_hi = p; p += B_ * D_;
    unsigned short* cv_lo = p; p += B_ * D_;
    int* tok = (int*)p;                         // [512]
    float* pvO = (float*)(tok + B_);            // [512][64]
    int* piO = (int*)(pvO + B_ * 64);           // [512][64]

    k_setup<<<10112, 256, 0, stream>>>(W_proj, emb, W_ih, W_hh, W_attn, ctx, counts,
                                       Wp_hi, Wp_lo, Eb_hi, Eb_lo, Wg_hi, Wg_lo,
                                       Wa_hi, Wa_lo, hA_hi, hA_lo, cbuf, tok, out);

    k_qproj<<<32, 256, 0, stream>>>(hA_hi, hA_lo, Wa_hi, Wa_lo, qbuf);

    unsigned short *hin_hi = hA_hi, *hin_lo = hA_lo;
    unsigned short *hout_hi = hB_hi, *hout_lo = hB_lo;
    for (int t = 1; t < L_; ++t) {
        k_attn<<<B_, 512, 0, stream>>>(ctx, counts, qbuf, cv_hi, cv_lo);
        if (t == 1) {
            k_gatesm<0><<<512, 256, 0, stream>>>(
                tok, pvO, piO, Eb_hi, Eb_lo, cv_hi, cv_lo, hin_hi, hin_lo,
                Wg_hi, Wg_lo, b_ih, b_hh, cbuf, hout_hi, hout_lo);
        } else {
            k_gatesm<1><<<512, 256, 0, stream>>>(
                tok, pvO, piO, Eb_hi, Eb_lo, cv_hi, cv_lo, hin_hi, hin_lo,
                Wg_hi, Wg_lo, b_ih, b_hh, cbuf, hout_hi, hout_lo);
        }
        float* slab = out + (size_t)t * B_ * V_;
        k_mega<<<544, 256, 0, stream>>>(hout_hi, hout_lo, Wp_hi, Wp_lo, b_proj,
                                        slab, pvO, piO, Wa_hi, Wa_lo, qbuf);
        unsigned short* tmp;
        tmp = hin_hi; hin_hi = hout_hi; hout_hi = tmp;
        tmp = hin_lo; hin_lo = hout_lo; hout_lo = tmp;
    }
}

// Round 15
// 1332.079 us; speedup vs baseline: 5.5568x; 1.0038x over previous
//
#include <hip/hip_runtime.h>
#include <math.h>

#define B_ 512
#define C_ 200
#define D_ 512
#define E_ 256
#define V_ 8192
#define G_ 2048
#define L_ 16

typedef __attribute__((ext_vector_type(8))) short short8;
typedef __attribute__((ext_vector_type(4))) float f32x4;

__device__ __forceinline__ float sigm(float x) { return 1.0f / (1.0f + expf(-x)); }

__device__ __forceinline__ unsigned short bf16_rn(float x) {
    unsigned int u = __float_as_uint(x);
    return (unsigned short)((u + 0x7FFFu + ((u >> 16) & 1u)) >> 16);
}
__device__ __forceinline__ float bf16f(unsigned short h) {
    return __uint_as_float(((unsigned int)h) << 16);
}

// Canonical fragment layout (16x16x32 MFMA operand):
//   canon[((tile*NKT + kt)*64 + lane)*8 + e] = M[tile*16 + (lane&15)][kt*32 + (lane>>4)*8 + e]
__device__ __forceinline__ size_t canon_off(int row, int k, int NKT) {
    return ((((size_t)(row >> 4) * NKT + (k >> 5)) * 64) +
            ((row & 15) + (((k >> 3) & 3) << 4))) * 8 + (k & 7);
}

// ---------------------------------------------------------------------------
// merged setup (block ranges):
//   [0,2048) W_proj->canon  [2048,4096) emb  [4096,5376) Wg->canon
//   [5376,5504) W_attn->canon  [5504,6016) init  [6016,10112) zero out slab 0
// ---------------------------------------------------------------------------
__global__ __launch_bounds__(256) void k_setup(const float* __restrict__ W_proj,
                                               const float* __restrict__ emb,
                                               const float* __restrict__ W_ih,
                                               const float* __restrict__ W_hh,
                                               const float* __restrict__ W_attn,
                                               const float* __restrict__ ctx,
                                               const int* __restrict__ counts,
                                               unsigned short* __restrict__ WpC_hi,
                                               unsigned short* __restrict__ WpC_lo,
                                               unsigned short* __restrict__ Eb_hi,
                                               unsigned short* __restrict__ Eb_lo,
                                               unsigned short* __restrict__ WgC_hi,
                                               unsigned short* __restrict__ WgC_lo,
                                               unsigned short* __restrict__ WaC_hi,
                                               unsigned short* __restrict__ WaC_lo,
                                               unsigned short* __restrict__ h_hi,
                                               unsigned short* __restrict__ h_lo,
                                               float* __restrict__ c,
                                               int* __restrict__ tok,
                                               float* __restrict__ out0) {
    int bb = blockIdx.x;
    int t = threadIdx.x;
    if (bb < 2048) {
        int i = bb * 256 + t;
        int n = i >> 6;
        int koff = (i & 63) * 8;
        float4 v0 = *(const float4*)&W_proj[(size_t)n * 512 + koff];
        float4 v1 = *(const float4*)&W_proj[(size_t)n * 512 + koff + 4];
        float vv[8] = {v0.x, v0.y, v0.z, v0.w, v1.x, v1.y, v1.z, v1.w};
        short8 h8, l8;
#pragma unroll
        for (int e = 0; e < 8; ++e) {
            unsigned short hh = bf16_rn(vv[e]);
            h8[e] = (short)hh;
            l8[e] = (short)bf16_rn(vv[e] - bf16f(hh));
        }
        size_t off = canon_off(n, koff, 16);
        *(short8*)&WpC_hi[off] = h8;
        *(short8*)&WpC_lo[off] = l8;
    } else if (bb < 4096) {
        int i = (bb - 2048) * 256 + t;
        float4 v = ((const float4*)emb)[i];
        ushort4 h, l;
        h.x = bf16_rn(v.x); l.x = bf16_rn(v.x - bf16f(h.x));
        h.y = bf16_rn(v.y); l.y = bf16_rn(v.y - bf16f(h.y));
        h.z = bf16_rn(v.z); l.z = bf16_rn(v.z - bf16f(h.z));
        h.w = bf16_rn(v.w); l.w = bf16_rn(v.w - bf16f(h.w));
        ((ushort4*)Eb_hi)[i] = h;
        ((ushort4*)Eb_lo)[i] = l;
    } else if (bb < 5376) {
        int i = (bb - 4096) * 256 + t;
        if (i < 327680) {
            int r = i / 160;
            int koff = (i - r * 160) * 8;
            int go = ((r & 3) << 9) + (r >> 2);
            float4 v0, v1;
            if (koff < 768) {
                v0 = *(const float4*)&W_ih[(size_t)go * 768 + koff];
                v1 = *(const float4*)&W_ih[(size_t)go * 768 + koff + 4];
            } else {
                v0 = *(const float4*)&W_hh[(size_t)go * 512 + (koff - 768)];
                v1 = *(const float4*)&W_hh[(size_t)go * 512 + (koff - 768) + 4];
            }
            float vv[8] = {v0.x, v0.y, v0.z, v0.w, v1.x, v1.y, v1.z, v1.w};
            short8 h8, l8;
#pragma unroll
            for (int e = 0; e < 8; ++e) {
                unsigned short hh = bf16_rn(vv[e]);
                h8[e] = (short)hh;
                l8[e] = (short)bf16_rn(vv[e] - bf16f(hh));
            }
            size_t off = canon_off(r, koff, 40);
            *(short8*)&WgC_hi[off] = h8;
            *(short8*)&WgC_lo[off] = l8;
        }
    } else if (bb < 5504) {
        int i = (bb - 5376) * 256 + t;
        int n = i >> 6;
        int koff = (i & 63) * 8;
        float4 v0 = *(const float4*)&W_attn[(size_t)n * 512 + koff];
        float4 v1 = *(const float4*)&W_attn[(size_t)n * 512 + koff + 4];
        float vv[8] = {v0.x, v0.y, v0.z, v0.w, v1.x, v1.y, v1.z, v1.w};
        short8 h8, l8;
#pragma unroll
        for (int e = 0; e < 8; ++e) {
            unsigned short hh = bf16_rn(vv[e]);
            h8[e] = (short)hh;
            l8[e] = (short)bf16_rn(vv[e] - bf16f(hh));
        }
        size_t off = canon_off(n, koff, 16);
        *(short8*)&WaC_hi[off] = h8;
        *(short8*)&WaC_lo[off] = l8;
    } else if (bb < 6016) {
        int b = bb - 5504;
        int cnt = counts[b];
        const float* base = ctx + (size_t)b * C_ * D_;
        float s0 = 0.f, s1 = 0.f;
        for (int cc = 0; cc < cnt; ++cc) {
            s0 += base[(size_t)cc * D_ + t];
            s1 += base[(size_t)cc * D_ + t + 256];
        }
        float inv = 1.0f / (float)cnt;
        float v0 = s0 * inv, v1 = s1 * inv;
        c[b * D_ + t] = v0;       c[b * D_ + t + 256] = v1;
        unsigned short p0 = bf16_rn(v0), p1 = bf16_rn(v1);
        size_t o0 = canon_off(b, t, 16);
        size_t o1 = canon_off(b, t + 256, 16);
        h_hi[o0] = p0;            h_hi[o1] = p1;
        h_lo[o0] = bf16_rn(v0 - bf16f(p0));
        h_lo[o1] = bf16_rn(v1 - bf16f(p1));
        if (t == 0) tok[b] = 1;
    } else {
        int i = (bb - 6016) * 256 + t;
        f32x4 zz = {0.f, 0.f, 0.f, 0.f};
        __builtin_nontemporal_store(zz, &((f32x4*)out0)[i]);
    }
}

// ---------------------------------------------------------------------------
// All-direct split-bf16 GEMM body: C[64m x 128n], K=512 (16 ktiles), 4 waves.
// PART=1: logits -> nontemporal C stores (don't pollute L2) + argmax partials.
// ---------------------------------------------------------------------------
template<int PART>
__device__ __forceinline__ void gemm_body(int nb, int mb,
                                          const unsigned short* __restrict__ Ah,
                                          const unsigned short* __restrict__ Al,
                                          const unsigned short* __restrict__ BhC,
                                          const unsigned short* __restrict__ BlC,
                                          const float* __restrict__ bias,
                                          float* __restrict__ C, int ldc,
                                          float* __restrict__ pvO,
                                          int* __restrict__ piO,
                                          float (*pvS)[2], int (*piS)[2]) {
    int t = threadIdx.x;
    int l = t & 63;
    int w = t >> 6;
    int wm = w >> 1, wn = w & 1;
    int m0 = mb * 64;
    int n0 = nb * 128;
    int tA0 = mb * 4 + wm * 2;
    const unsigned short* Ah0 = Ah + ((size_t)tA0 * 16) * 512 + l * 8;
    const unsigned short* Al0 = Al + ((size_t)tA0 * 16) * 512 + l * 8;
    int ntbase = nb * 8 + wn * 4;
    const unsigned short* Bh0 = BhC + ((size_t)ntbase * 16) * 512 + l * 8;
    const unsigned short* Bl0 = BlC + ((size_t)ntbase * 16) * 512 + l * 8;

    f32x4 z = {0.f, 0.f, 0.f, 0.f};
    f32x4 acc[2][4];
#pragma unroll
    for (int i = 0; i < 2; ++i)
#pragma unroll
        for (int j = 0; j < 4; ++j) acc[i][j] = z;

    for (int kt = 0; kt < 16; ++kt) {
        short8 ah[2], al[2], bh[4], bl[4];
#pragma unroll
        for (int i = 0; i < 2; ++i) {
            size_t o = ((size_t)i * 16 + kt) * 512;
            ah[i] = *(const short8*)(Ah0 + o);
            al[i] = *(const short8*)(Al0 + o);
        }
#pragma unroll
        for (int j = 0; j < 4; ++j) {
            size_t o = ((size_t)j * 16 + kt) * 512;
            bh[j] = *(const short8*)(Bh0 + o);
            bl[j] = *(const short8*)(Bl0 + o);
        }
#pragma unroll
        for (int i = 0; i < 2; ++i)
#pragma unroll
            for (int j = 0; j < 4; ++j) {
                acc[i][j] = __builtin_amdgcn_mfma_f32_16x16x32_bf16(ah[i], bh[j], acc[i][j], 0, 0, 0);
                acc[i][j] = __builtin_amdgcn_mfma_f32_16x16x32_bf16(ah[i], bl[j], acc[i][j], 0, 0, 0);
                acc[i][j] = __builtin_amdgcn_mfma_f32_16x16x32_bf16(al[i], bh[j], acc[i][j], 0, 0, 0);
            }
    }
    int r0 = (l >> 4) * 4;
    int cl = l & 15;
    if (PART) {
        float bj_[4];
#pragma unroll
        for (int j = 0; j < 4; ++j) bj_[j] = bias[n0 + wn * 64 + j * 16 + cl];
#pragma unroll
        for (int i = 0; i < 2; ++i) {
#pragma unroll
            for (int r = 0; r < 4; ++r) {
                int row = m0 + wm * 32 + i * 16 + r0 + r;
                float bv = -INFINITY;
                int bidx = 0x7fffffff;
#pragma unroll
                for (int j = 0; j < 4; ++j) {
                    int col = n0 + wn * 64 + j * 16 + cl;
                    float v = acc[i][j][r] + bj_[j];
                    __builtin_nontemporal_store(v, &C[(size_t)row * ldc + col]);
                    if (v > bv) { bv = v; bidx = col; }
                }
#pragma unroll
                for (int off = 1; off < 16; off <<= 1) {
                    float ov = __shfl_xor(bv, off);
                    int oi = __shfl_xor(bidx, off);
                    if (ov > bv || (ov == bv && oi < bidx)) { bv = ov; bidx = oi; }
                }
                if (cl == 0) {
                    pvS[wm * 32 + i * 16 + r0 + r][wn] = bv;
                    piS[wm * 32 + i * 16 + r0 + r][wn] = bidx;
                }
            }
        }
        __syncthreads();
        if (t < 64) {
            float v0 = pvS[t][0], v1 = pvS[t][1];
            int i0 = piS[t][0], i1 = piS[t][1];
            bool take1 = (v1 > v0);
            pvO[(size_t)(m0 + t) * 64 + nb] = take1 ? v1 : v0;
            piO[(size_t)(m0 + t) * 64 + nb] = take1 ? i1 : i0;
        }
    } else {
#pragma unroll
        for (int i = 0; i < 2; ++i)
#pragma unroll
            for (int j = 0; j < 4; ++j) {
                int col = n0 + wn * 64 + j * 16 + cl;
                int rowb = m0 + wm * 32 + i * 16 + r0;
#pragma unroll
                for (int r = 0; r < 4; ++r)
                    C[(size_t)(rowb + r) * ldc + col] = acc[i][j][r];
            }
    }
}

// ---------------------------------------------------------------------------
// mega: blocks [0,512) = logits (XCD swizzle, argmax partials);
//       blocks [512,544) = qproj -> qbuf (next step's q).
// ---------------------------------------------------------------------------
__global__ __launch_bounds__(256, 3) void k_mega(const unsigned short* __restrict__ Ah,
                                                 const unsigned short* __restrict__ Al,
                                                 const unsigned short* __restrict__ WpCh,
                                                 const unsigned short* __restrict__ WpCl,
                                                 const float* __restrict__ bias,
                                                 float* __restrict__ Cl_,
                                                 float* __restrict__ pvO,
                                                 int* __restrict__ piO,
                                                 const unsigned short* __restrict__ WaCh,
                                                 const unsigned short* __restrict__ WaCl,
                                                 float* __restrict__ qbuf) {
    __shared__ float pvS[64][2];
    __shared__ int piS[64][2];
    int bb = blockIdx.x;
    if (bb < 512) {
        int xcd = bb & 7, lid = bb >> 3;
        int nb = xcd * 8 + (lid & 7);
        int mb = lid >> 3;
        gemm_body<1>(nb, mb, Ah, Al, WpCh, WpCl, bias, Cl_, V_, pvO, piO, pvS, piS);
    } else {
        int idx = bb - 512;
        int nb = idx & 3, mb = idx >> 2;
        gemm_body<0>(nb, mb, Ah, Al, WaCh, WaCl, nullptr, qbuf, D_, nullptr, nullptr, pvS, piS);
    }
}

// standalone qproj for the first step (h0)
__global__ __launch_bounds__(256, 3) void k_qproj(const unsigned short* __restrict__ Ah,
                                                  const unsigned short* __restrict__ Al,
                                                  const unsigned short* __restrict__ WaCh,
                                                  const unsigned short* __restrict__ WaCl,
                                                  float* __restrict__ qbuf) {
    __shared__ float pvS[64][2];
    __shared__ int piS[64][2];
    int nb = blockIdx.x & 3, mb = blockIdx.x >> 2;
    gemm_body<0>(nb, mb, Ah, Al, WaCh, WaCl, nullptr, qbuf, D_, nullptr, nullptr, pvS, piS);
}

// ---------------------------------------------------------------------------
// attention: single-pass online softmax. One block per batch row, 16 waves
// (1024 threads); wave wv handles rows wv, wv+16, ... (2-row ILP, stride 32).
// cv written in canonical fragment layout.
// ---------------------------------------------------------------------------
__global__ __launch_bounds__(1024) void k_attn(const float* __restrict__ ctx,
                                               const int* __restrict__ counts,
                                               const float* __restrict__ q,
                                               unsigned short* __restrict__ cv_hi,
                                               unsigned short* __restrict__ cv_lo) {
    __shared__ float accw[16][512];
    __shared__ float mw_s[16], sw_s[16];
    int b = blockIdx.x;
    int t = threadIdx.x;
    int lane = t & 63;
    int wv = t >> 6;
    int cnt = counts[b];
    const float* cb = ctx + (size_t)b * C_ * D_;

    float4 q0 = *(const float4*)&q[(size_t)b * D_ + lane * 4];
    float4 q1 = *(const float4*)&q[(size_t)b * D_ + lane * 4 + 256];

    float m_w = -INFINITY, s_w = 0.f;
    float4 a0 = make_float4(0.f, 0.f, 0.f, 0.f);
    float4 a1 = make_float4(0.f, 0.f, 0.f, 0.f);

#define ATT_DOT(x0, x1) (x0.x * q0.x + x0.y * q0.y + x0.z * q0.z + x0.w * q0.w + \
                         x1.x * q1.x + x1.y * q1.y + x1.z * q1.z + x1.w * q1.w)
#define ATT_UPD(s, x0, x1)                                                     \
    {                                                                          \
        float e;                                                               \
        if (s > m_w) {                                                         \
            float sc = expf(m_w - s);                                          \
            s_w = s_w * sc + 1.f;                                              \
            a0.x *= sc; a0.y *= sc; a0.z *= sc; a0.w *= sc;                    \
            a1.x *= sc; a1.y *= sc; a1.z *= sc; a1.w *= sc;                    \
            m_w = s; e = 1.f;                                                  \
        } else {                                                               \
            e = expf(s - m_w);                                                 \
            s_w += e;                                                          \
        }                                                                      \
        a0.x += e * x0.x; a0.y += e * x0.y; a0.z += e * x0.z; a0.w += e * x0.w;\
        a1.x += e * x1.x; a1.y += e * x1.y; a1.z += e * x1.z; a1.w += e * x1.w;\
    }

    int cc = wv;
    for (; cc + 16 < cnt; cc += 32) {
        const float* rA = cb + (size_t)cc * D_;
        const float* rB = cb + (size_t)(cc + 16) * D_;
        float4 xa0 = *(const float4*)&rA[lane * 4];
        float4 xa1 = *(const float4*)&rA[lane * 4 + 256];
        float4 xb0 = *(const float4*)&rB[lane * 4];
        float4 xb1 = *(const float4*)&rB[lane * 4 + 256];
        float sa = ATT_DOT(xa0, xa1);
        float sb = ATT_DOT(xb0, xb1);
#pragma unroll
        for (int off = 32; off; off >>= 1) {
            sa += __shfl_xor(sa, off);
            sb += __shfl_xor(sb, off);
        }
        ATT_UPD(sa, xa0, xa1);
        ATT_UPD(sb, xb0, xb1);
    }
    if (cc < cnt) {
        const float* rA = cb + (size_t)cc * D_;
        float4 xa0 = *(const float4*)&rA[lane * 4];
        float4 xa1 = *(const float4*)&rA[lane * 4 + 256];
        float sa = ATT_DOT(xa0, xa1);
#pragma unroll
        for (int off = 32; off; off >>= 1) sa += __shfl_xor(sa, off);
        ATT_UPD(sa, xa0, xa1);
    }

    accw[wv][lane * 4 + 0] = a0.x; accw[wv][lane * 4 + 1] = a0.y;
    accw[wv][lane * 4 + 2] = a0.z; accw[wv][lane * 4 + 3] = a0.w;
    accw[wv][256 + lane * 4 + 0] = a1.x; accw[wv][256 + lane * 4 + 1] = a1.y;
    accw[wv][256 + lane * 4 + 2] = a1.z; accw[wv][256 + lane * 4 + 3] = a1.w;
    if (lane == 0) { mw_s[wv] = m_w; sw_s[wv] = s_w; }
    __syncthreads();

    if (t < 512) {
        float m_g = mw_s[0];
#pragma unroll
        for (int ww = 1; ww < 16; ++ww) m_g = fmaxf(m_g, mw_s[ww]);
        float den = 0.f, num = 0.f;
#pragma unroll
        for (int ww = 0; ww < 16; ++ww) {
            float e = expf(mw_s[ww] - m_g);
            den += sw_s[ww] * e;
            num += accw[ww][t] * e;
        }
        float v0 = num / den;
        unsigned short p0 = bf16_rn(v0);
        size_t o0 = canon_off(b, t, 16);
        cv_hi[o0] = p0;
        cv_lo[o0] = bf16_rn(v0 - bf16f(p0));
    }
}

// ---------------------------------------------------------------------------
// gates GEMM (split-bf16 MFMA, K=1280) + fused LSTM epilogue. ALL-DIRECT.
// 64m x 32n tiles, 512 blocks, XCD swizzle.
// RED=1: prologue reduces argmax partials for this block's 64 rows -> toks.
// ---------------------------------------------------------------------------
template<int RED>
__global__ __launch_bounds__(256, 3) void k_gatesm(const int* __restrict__ tok,
                                                   const float* __restrict__ pvO,
                                                   const int* __restrict__ piO,
                                                   const unsigned short* __restrict__ Eh,
                                                   const unsigned short* __restrict__ El,
                                                   const unsigned short* __restrict__ Ch,
                                                   const unsigned short* __restrict__ Cl,
                                                   const unsigned short* __restrict__ Hh,
                                                   const unsigned short* __restrict__ Hl,
                                                   const unsigned short* __restrict__ WgCh,
                                                   const unsigned short* __restrict__ WgCl,
                                                   const float* __restrict__ b_ih,
                                                   const float* __restrict__ b_hh,
                                                   float* __restrict__ cbuf,
                                                   unsigned short* __restrict__ Hoh,
                                                   unsigned short* __restrict__ Hol) {
    __shared__ int toks[64];
    int bid = blockIdx.x;
    int t = threadIdx.x;
    int l = t & 63;
    int w = t >> 6;
    int wm = w >> 1, wn = w & 1;
    int xcd = bid & 7, lid = bid >> 3;
    int nb = xcd * 8 + (lid & 7);
    int mb = lid >> 3;
    int m0 = mb * 64;
    int n0 = nb * 32;
    int koct = 8 * (l >> 4);

    if (RED) {
        int ri = t >> 2, qq = t & 3;
        const float* pv = pvO + (size_t)(m0 + ri) * 64 + qq * 16;
        const int* pi = piO + (size_t)(m0 + ri) * 64 + qq * 16;
        float bv = -INFINITY;
        int bix = 0x7fffffff;
#pragma unroll
        for (int j = 0; j < 16; ++j) {
            float v = pv[j];
            int ii = pi[j];
            if (v > bv || (v == bv && ii < bix)) { bv = v; bix = ii; }
        }
#pragma unroll
        for (int off = 1; off < 4; off <<= 1) {
            float ov = __shfl_xor(bv, off);
            int oi = __shfl_xor(bix, off);
            if (ov > bv || (ov == bv && oi < bix)) { bv = ov; bix = oi; }
        }
        if (qq == 0) toks[ri] = bix;
        __syncthreads();
    }

    int lr0 = wm * 32 + (l & 15);
    int tk0 = RED ? toks[lr0] : tok[m0 + lr0];
    int tk1 = RED ? toks[lr0 + 16] : tok[m0 + lr0 + 16];
    int tg0 = mb * 4 + wm * 2;
    const unsigned short* Ch0 = Ch + ((size_t)tg0 * 16) * 512 + l * 8;
    const unsigned short* Cl0 = Cl + ((size_t)tg0 * 16) * 512 + l * 8;
    const unsigned short* Hh0 = Hh + ((size_t)tg0 * 16) * 512 + l * 8;
    const unsigned short* Hl0 = Hl + ((size_t)tg0 * 16) * 512 + l * 8;
    int ntg = nb * 2 + wn;
    const unsigned short* Bh0 = WgCh + ((size_t)ntg * 40) * 512 + l * 8;
    const unsigned short* Bl0 = WgCl + ((size_t)ntg * 40) * 512 + l * 8;

    f32x4 z = {0.f, 0.f, 0.f, 0.f};
    f32x4 acc[2];
    acc[0] = z; acc[1] = z;

#define GATES_MFMA(a0h, a0l, a1h, a1l, bh, bl)                                   \
    acc[0] = __builtin_amdgcn_mfma_f32_16x16x32_bf16(a0h, bh, acc[0], 0, 0, 0);  \
    acc[0] = __builtin_amdgcn_mfma_f32_16x16x32_bf16(a0h, bl, acc[0], 0, 0, 0);  \
    acc[0] = __builtin_amdgcn_mfma_f32_16x16x32_bf16(a0l, bh, acc[0], 0, 0, 0);  \
    acc[1] = __builtin_amdgcn_mfma_f32_16x16x32_bf16(a1h, bh, acc[1], 0, 0, 0);  \
    acc[1] = __builtin_amdgcn_mfma_f32_16x16x32_bf16(a1h, bl, acc[1], 0, 0, 0);  \
    acc[1] = __builtin_amdgcn_mfma_f32_16x16x32_bf16(a1l, bh, acc[1], 0, 0, 0);

    for (int kt = 0; kt < 8; ++kt) {
        int ko = kt * 32 + koct;
        short8 a0h = *(const short8*)&Eh[(size_t)tk0 * 256 + ko];
        short8 a0l = *(const short8*)&El[(size_t)tk0 * 256 + ko];
        short8 a1h = *(const short8*)&Eh[(size_t)tk1 * 256 + ko];
        short8 a1l = *(const short8*)&El[(size_t)tk1 * 256 + ko];
        short8 bh = *(const short8*)(Bh0 + (size_t)kt * 512);
        short8 bl = *(const short8*)(Bl0 + (size_t)kt * 512);
        GATES_MFMA(a0h, a0l, a1h, a1l, bh, bl)
    }
    for (int kt = 8; kt < 24; ++kt) {
        size_t oc = ((size_t)(kt - 8)) * 512;
        short8 a0h = *(const short8*)(Ch0 + oc);
        short8 a0l = *(const short8*)(Cl0 + oc);
        short8 a1h = *(const short8*)(Ch0 + 16 * 512 + oc);
        short8 a1l = *(const short8*)(Cl0 + 16 * 512 + oc);
        short8 bh = *(const short8*)(Bh0 + (size_t)kt * 512);
        short8 bl = *(const short8*)(Bl0 + (size_t)kt * 512);
        GATES_MFMA(a0h, a0l, a1h, a1l, bh, bl)
    }
    for (int kt = 24; kt < 40; ++kt) {
        size_t oh = ((size_t)(kt - 24)) * 512;
        short8 a0h = *(const short8*)(Hh0 + oh);
        short8 a0l = *(const short8*)(Hl0 + oh);
        short8 a1h = *(const short8*)(Hh0 + 16 * 512 + oh);
        short8 a1l = *(const short8*)(Hl0 + 16 * 512 + oh);
        short8 bh = *(const short8*)(Bh0 + (size_t)kt * 512);
        short8 bl = *(const short8*)(Bl0 + (size_t)kt * 512);
        GATES_MFMA(a0h, a0l, a1h, a1l, bh, bl)
    }

    int r0 = (l >> 4) * 4;
    int cl = l & 15;
    bool act = (cl & 3) == 0;
    int gc = n0 + wn * 16 + cl;
    int d = gc >> 2;
    float bi_ = b_ih[d] + b_hh[d];
    float bf_ = b_ih[512 + d] + b_hh[512 + d];
    float bg_ = b_ih[1024 + d] + b_hh[1024 + d];
    float bo_ = b_ih[1536 + d] + b_hh[1536 + d];
#pragma unroll
    for (int i = 0; i < 2; ++i) {
#pragma unroll
        for (int r = 0; r < 4; ++r) {
            float x = acc[i][r];
            float x1 = __shfl_xor(x, 1);
            float x2 = __shfl_xor(x, 2);
            float x3 = __shfl_xor(x, 3);
            if (act) {
                int row = m0 + wm * 32 + i * 16 + r0 + r;
                float ig = sigm(x + bi_);
                float fg = sigm(x1 + bf_);
                float gg = tanhf(x2 + bg_);
                float og = sigm(x3 + bo_);
                float cn = fg * cbuf[(size_t)row * D_ + d] + ig * gg;
                cbuf[(size_t)row * D_ + d] = cn;
                float hv = og * tanhf(cn);
                unsigned short hh = bf16_rn(hv);
                size_t oo = canon_off(row, d, 16);
                Hoh[oo] = hh;
                Hol[oo] = bf16_rn(hv - bf16f(hh));
            }
        }
    }
}

// ---------------------------------------------------------------------------
extern "C" void kernel_launch(void* const* d_in, const int* in_sizes, int n_in,
                              void* d_out, int out_size, void* d_ws, size_t ws_size,
                              hipStream_t stream) {
    const float* ctx    = (const float*)d_in[0];
    const int*   counts = (const int*)d_in[1];
    const float* emb    = (const float*)d_in[3];
    const float* W_attn = (const float*)d_in[4];
    const float* W_ih   = (const float*)d_in[5];
    const float* b_ih   = (const float*)d_in[6];
    const float* W_hh   = (const float*)d_in[7];
    const float* b_hh   = (const float*)d_in[8];
    const float* W_proj = (const float*)d_in[9];
    const float* b_proj = (const float*)d_in[10];
    float* out = (float*)d_out;

    float* qbuf = (float*)d_ws;                 // [512][512]
    float* cbuf = qbuf + B_ * D_;               // [512][512]
    unsigned short* p = (unsigned short*)(cbuf + B_ * D_);
    unsigned short* Wa_hi = p; p += D_ * D_;
    unsigned short* Wa_lo = p; p += D_ * D_;
    unsigned short* Wp_hi = p; p += (size_t)V_ * D_;
    unsigned short* Wp_lo = p; p += (size_t)V_ * D_;
    unsigned short* Eb_hi = p; p += (size_t)V_ * E_;
    unsigned short* Eb_lo = p; p += (size_t)V_ * E_;
    unsigned short* Wg_hi = p; p += (size_t)G_ * 1280;
    unsigned short* Wg_lo = p; p += (size_t)G_ * 1280;
    unsigned short* hA_hi = p; p += B_ * D_;
    unsigned short* hA_lo = p; p += B_ * D_;
    unsigned short* hB_hi = p; p += B_ * D_;
    unsigned short* hB_lo = p; p += B_ * D_;
    unsigned short* cv_hi = p; p += B_ * D_;
    unsigned short* cv_lo = p; p += B_ * D_;
    int* tok = (int*)p;                         // [512]
    float* pvO = (float*)(tok + B_);            // [512][64]
    int* piO = (int*)(pvO + B_ * 64);           // [512][64]

    k_setup<<<10112, 256, 0, stream>>>(W_proj, emb, W_ih, W_hh, W_attn, ctx, counts,
                                       Wp_hi, Wp_lo, Eb_hi, Eb_lo, Wg_hi, Wg_lo,
                                       Wa_hi, Wa_lo, hA_hi, hA_lo, cbuf, tok, out);

    k_qproj<<<32, 256, 0, stream>>>(hA_hi, hA_lo, Wa_hi, Wa_lo, qbuf);

    unsigned short *hin_hi = hA_hi, *hin_lo = hA_lo;
    unsigned short *hout_hi = hB_hi, *hout_lo = hB_lo;
    for (int t = 1; t < L_; ++t) {
        k_attn<<<B_, 1024, 0, stream>>>(ctx, counts, qbuf, cv_hi, cv_lo);
        if (t == 1) {
            k_gatesm<0><<<512, 256, 0, stream>>>(
                tok, pvO, piO, Eb_hi, Eb_lo, cv_hi, cv_lo, hin_hi, hin_lo,
                Wg_hi, Wg_lo, b_ih, b_hh, cbuf, hout_hi, hout_lo);
        } else {
            k_gatesm<1><<<512, 256, 0, stream>>>(
                tok, pvO, piO, Eb_hi, Eb_lo, cv_hi, cv_lo, hin_hi, hin_lo,
                Wg_hi, Wg_lo, b_ih, b_hh, cbuf, hout_hi, hout_lo);
        }
        float* slab = out + (size_t)t * B_ * V_;
        k_mega<<<544, 256, 0, stream>>>(hout_hi, hout_lo, Wp_hi, Wp_lo, b_proj,
                                        slab, pvO, piO, Wa_hi, Wa_lo, qbuf);
        unsigned short* tmp;
        tmp = hin_hi; hin_hi = hout_hi; hout_hi = tmp;
        tmp = hin_lo; hin_lo = hout_lo; hout_lo = tmp;
    }
}